// Round 7
// baseline (958.782 us; speedup 1.0000x reference)
//
#include <hip/hip_runtime.h>

typedef __attribute__((ext_vector_type(8))) short short8v;
typedef __attribute__((ext_vector_type(8))) unsigned short ushort8v;
typedef __attribute__((ext_vector_type(4))) float float4v;

__device__ __constant__ float c_LO[8] = {
    -0.010597401784997278f, 0.032883011666982945f, 0.030841381835986965f,
    -0.18703481171888114f, -0.02798376941698385f, 0.6308807679295904f,
    0.7148465705525415f, 0.23037781330885523f};
__device__ __constant__ float c_HI[8] = {
    -0.23037781330885523f, 0.7148465705525415f, -0.6308807679295904f,
    -0.02798376941698385f, 0.18703481171888114f, 0.030841381835986965f,
    -0.032883011666982945f, -0.010597401784997278f};

__device__ __forceinline__ unsigned short f2bf(float f) {
    unsigned u = __builtin_bit_cast(unsigned, f);
    unsigned r = u + 0x7fffu + ((u >> 16) & 1u);
    return (unsigned short)(r >> 16);
}
__device__ __forceinline__ float bf2f(unsigned short u) {
    return __builtin_bit_cast(float, (unsigned)u << 16);
}

// tanh-form GELU: one exp2 + rcp
__device__ __forceinline__ float gelu_fast(float x) {
    float x3 = x * x * x;
    float y = fmaf(0.044715f, x3, x) * 0.7978845608028654f;
    float t = fminf(fmaxf(y * 2.8853900817779268f, -30.f), 30.f);
    float e = exp2f(t);
    return x * e * __builtin_amdgcn_rcpf(e + 1.0f);
}

__device__ __forceinline__ void gload_lds16(const void* g, void* l) {
    __builtin_amdgcn_global_load_lds(g, l, 16, 0, 0);
}

// ---------------- x -> bf16 cast ----------------
__global__ void cast_bf16_kernel(const float* __restrict__ in, unsigned short* __restrict__ out, int n4) {
    int i = blockIdx.x * blockDim.x + threadIdx.x;
    if (i >= n4) return;
    float4 v = ((const float4*)in)[i];
    ushort4 o;
    o.x = f2bf(v.x); o.y = f2bf(v.y); o.z = f2bf(v.z); o.w = f2bf(v.w);
    ((ushort4*)out)[i] = o;
}

// ---------------- CSR build: histogram ----------------
__global__ void hist_kernel(const int* __restrict__ rows, int* __restrict__ cnt, int E) {
    int i = blockIdx.x * blockDim.x + threadIdx.x;
    if (i < E) atomicAdd(&cnt[rows[i]], 1);
}

// ---------------- CSR build: single-block scan ----------------
__global__ __launch_bounds__(1024) void scan_kernel(const int* __restrict__ cnt, int* __restrict__ offs,
                                                    int* __restrict__ cursor, int Nrows, int E) {
    __shared__ int part[1024];
    int tid = threadIdx.x;
    const int per = Nrows / 1024;  // 16
    int base = tid * per;
    int local[16];
    int s = 0;
    for (int i = 0; i < per; ++i) { local[i] = s; s += cnt[base + i]; }
    part[tid] = s;
    __syncthreads();
    for (int off = 1; off < 1024; off <<= 1) {
        int v = part[tid];
        int w = (tid >= off) ? part[tid - off] : 0;
        __syncthreads();
        part[tid] = v + w;
        __syncthreads();
    }
    int pre = (tid == 0) ? 0 : part[tid - 1];
    for (int i = 0; i < per; ++i) {
        int o = pre + local[i];
        offs[base + i] = o;
        cursor[base + i] = o;
    }
    if (tid == 0) offs[Nrows] = E;
}

// ---------------- CSR build: scatter ----------------
__global__ void scatter_kernel(const int* __restrict__ rows, const int* __restrict__ cols,
                               const float* __restrict__ vals, int* __restrict__ cursor,
                               int* __restrict__ ccol, float* __restrict__ cval, int E) {
    int i = blockIdx.x * blockDim.x + threadIdx.x;
    if (i >= E) return;
    int r = rows[i];
    int p = atomicAdd(&cursor[r], 1);
    ccol[p] = cols[i];
    cval[p] = vals[i];
}

// ---------------- SpMM CSR: one wave per row, bf16 gather ----------------
__global__ __launch_bounds__(256) void spmm_csr(const unsigned short* __restrict__ xb, const int* __restrict__ offs,
                                                const int* __restrict__ ccol, const float* __restrict__ cval,
                                                float* __restrict__ xa) {
    int r = blockIdx.x * 4 + (threadIdx.x >> 6);
    int lane = threadIdx.x & 63;
    int s = offs[r], e = offs[r + 1];
    float acc[12] = {};
    for (int j = s; j < e; ++j) {
        int c = ccol[j];
        float v = cval[j];
        const unsigned short* xr = xb + (size_t)c * 768;
#pragma unroll
        for (int seg = 0; seg < 3; ++seg) {
            ushort4 u = *(const ushort4*)(xr + seg * 256 + lane * 4);
            acc[seg * 4 + 0] = fmaf(v, bf2f(u.x), acc[seg * 4 + 0]);
            acc[seg * 4 + 1] = fmaf(v, bf2f(u.y), acc[seg * 4 + 1]);
            acc[seg * 4 + 2] = fmaf(v, bf2f(u.z), acc[seg * 4 + 2]);
            acc[seg * 4 + 3] = fmaf(v, bf2f(u.w), acc[seg * 4 + 3]);
        }
    }
    float* o = xa + (size_t)r * 768;
#pragma unroll
    for (int seg = 0; seg < 3; ++seg) {
        float4 w = make_float4(acc[seg * 4], acc[seg * 4 + 1], acc[seg * 4 + 2], acc[seg * 4 + 3]);
        *(float4*)(o + seg * 256 + lane * 4) = w;
    }
}

// ---------------- one DWT level (pywt symmetric) ----------------
template <bool IN_BF16, bool A_BF16>
__global__ void dwt_kernel(const void* __restrict__ in, int n, int in_stride,
                           void* __restrict__ outA, int a_stride,
                           unsigned short* __restrict__ outD, int d_stride, int m) {
    extern __shared__ float srow[];
    int row = blockIdx.x;
    if (IN_BF16) {
        const unsigned short* ip = (const unsigned short*)in + (size_t)row * in_stride;
        for (int i = threadIdx.x; i < n; i += blockDim.x) srow[i] = bf2f(ip[i]);
    } else {
        const float* ip = (const float*)in + (size_t)row * in_stride;
        for (int i = threadIdx.x; i < n; i += blockDim.x) srow[i] = ip[i];
    }
    __syncthreads();
    for (int j = threadIdx.x; j < m; j += blockDim.x) {
        float a = 0.f, d = 0.f;
#pragma unroll
        for (int i = 0; i < 8; ++i) {
            int p = 2 * j + 7 - i;
            int q = (p < 6) ? (5 - p) : ((p < n + 6) ? (p - 6) : (2 * n + 5 - p));
            float xv = srow[q];
            a = fmaf(c_LO[i], xv, a);
            d = fmaf(c_HI[i], xv, d);
        }
        if (A_BF16)
            ((unsigned short*)outA)[(size_t)row * a_stride + j] = f2bf(a);
        else
            ((float*)outA)[(size_t)row * a_stride + j] = a;
        outD[(size_t)row * d_stride + j] = f2bf(d);
    }
}

// ---------------- pack basis stack -> transposed bf16 [N][Kpad] ----------------
struct Bounds { int b[6]; };

__global__ void pack_basis_T(const float* __restrict__ basis, unsigned short* __restrict__ BT,
                             Bounds bd, int brows, int N, int K, int Kpad) {
    int idx = blockIdx.x * blockDim.x + threadIdx.x;
    if (idx >= N * Kpad) return;
    int n = idx / Kpad, k = idx - n * Kpad;
    float v = 0.f;
    if (k < K) {
        int s = 0;
#pragma unroll
        for (int t = 1; t < 5; ++t)
            if (k >= bd.b[t]) s = t;
        int lr = k - bd.b[s];
        v = basis[((size_t)s * brows + lr) * N + n];
    }
    BT[idx] = f2bf(v);
}

// ---------------- pack weights [NB][K][N] -> transposed bf16 [NB][N][Kpad] ----------------
__global__ void pack_wT(const float* __restrict__ W, unsigned short* __restrict__ WT,
                        int NB, int K, int N, int Kpad) {
    int idx = blockIdx.x * blockDim.x + threadIdx.x;
    int tot = NB * N * Kpad;
    if (idx >= tot) return;
    int b = idx / (N * Kpad);
    int r = idx - b * (N * Kpad);
    int n = r / Kpad, k = r - n * Kpad;
    float v = (k < K) ? W[((size_t)b * K + k) * N + n] : 0.f;
    WT[idx] = f2bf(v);
}

// ---------------- bf16 MFMA GEMM (proven) ----------------
template <int OUT_BF16>
__global__ __launch_bounds__(256) void gemm_mfma(const unsigned short* __restrict__ A,
                                                 const unsigned short* __restrict__ BT,
                                                 const float* __restrict__ bias,
                                                 void* __restrict__ Cv,
                                                 int M, int N, int K, int lda, int ldb, int ldc) {
    __shared__ __align__(16) unsigned short As[128 * 32];
    __shared__ __align__(16) unsigned short Bs[128 * 32];
    const int tid = threadIdx.x;
    const int wave = tid >> 6, lane = tid & 63;
    const int m0 = blockIdx.y * 128, n0 = blockIdx.x * 128;
    const int wr = wave >> 1, wc = wave & 1;
    const int frow = lane & 15, fq = lane >> 4;

    const int off0 = tid * 16;
    const int r0 = off0 >> 6, c0 = off0 & 63;
    const int r1 = (off0 + 4096) >> 6, c1 = (off0 + 4096) & 63;
    const char* Ab = (const char*)A;
    const char* Bb = (const char*)BT;
    size_t gA0 = (size_t)(m0 + r0) * lda * 2 + c0;
    size_t gA1 = (size_t)(m0 + r1) * lda * 2 + c1;
    size_t gB0 = (size_t)(n0 + r0) * ldb * 2 + c0;
    size_t gB1 = (size_t)(n0 + r1) * ldb * 2 + c1;
    char* lA0 = (char*)As + wave * 1024;
    char* lB0 = (char*)Bs + wave * 1024;

    const int aoff = (wr * 64 + frow) * 32 + fq * 8;
    const int boff = (wc * 64 + frow) * 32 + fq * 8;

    float4v acc[4][4] = {};
    for (int k0 = 0; k0 < K; k0 += 32) {
        size_t kb2 = (size_t)k0 * 2;
        gload_lds16(Ab + gA0 + kb2, lA0);
        gload_lds16(Ab + gA1 + kb2, lA0 + 4096);
        gload_lds16(Bb + gB0 + kb2, lB0);
        gload_lds16(Bb + gB1 + kb2, lB0 + 4096);
        __syncthreads();
        short8v av[4], bv[4];
#pragma unroll
        for (int i = 0; i < 4; ++i) av[i] = *(const short8v*)(As + aoff + i * 512);
#pragma unroll
        for (int i = 0; i < 4; ++i) bv[i] = *(const short8v*)(Bs + boff + i * 512);
#pragma unroll
        for (int mi = 0; mi < 4; ++mi)
#pragma unroll
            for (int ni = 0; ni < 4; ++ni)
                acc[mi][ni] = __builtin_amdgcn_mfma_f32_16x16x32_bf16(av[mi], bv[ni], acc[mi][ni], 0, 0, 0);
        __syncthreads();
    }
#pragma unroll
    for (int ni = 0; ni < 4; ++ni) {
        int col = n0 + wc * 64 + ni * 16 + frow;
        float bval = bias ? bias[col] : 0.f;
#pragma unroll
        for (int mi = 0; mi < 4; ++mi) {
#pragma unroll
            for (int i = 0; i < 4; ++i) {
                int row = m0 + wr * 64 + mi * 16 + fq * 4 + i;
                float v = acc[mi][ni][i] + bval;
                if (OUT_BF16)
                    ((unsigned short*)Cv)[(size_t)row * ldc + col] = f2bf(v);
                else
                    ((float*)Cv)[(size_t)row * ldc + col] = v;
            }
        }
    }
}

// ---- dendritic partial v3: z-split branch groups, BK=64, 2-barrier loop, XOR-swizzled LDS ----
// A [M,K] bf16; WT [nb][Nc][K] bf16; bias [nb][Nc] f32; P [ngrp][M][Nc] bf16.
// grid (Nc/128, M/128, ngrp), block 256.
__global__ __launch_bounds__(256) void dendritic_part(const unsigned short* __restrict__ A,
                                                      const unsigned short* __restrict__ WT,
                                                      const float* __restrict__ bias,
                                                      unsigned short* __restrict__ Pout,
                                                      int M, int Nc, int K, int nb, int ngrp) {
    __shared__ __align__(16) unsigned short As[128 * 64];
    __shared__ __align__(16) unsigned short Bs[128 * 64];
    const int tid = threadIdx.x;
    const int wave = tid >> 6, lane = tid & 63;
    const int n0 = blockIdx.x * 128, m0 = blockIdx.y * 128;
    const int gz = blockIdx.z;
    const int q = nb / ngrp, rmd = nb - q * ngrp;
    const int kb0 = gz * q + (gz < rmd ? gz : rmd);
    const int kbn = q + (gz < rmd ? 1 : 0);
    unsigned short* P = Pout + (size_t)gz * M * Nc;
    const int wr = wave >> 1, wc = wave & 1;
    const int frow = lane & 15, fq = lane >> 4;

    // staging: chunk ch = i*256 + tid; LDS linear byte = ch*16 (row=ch>>3, slot=ch&7);
    // global source col pre-swizzled: slot_src = slot ^ (row&7)  (involution)
    int srow[4], scol[4];
#pragma unroll
    for (int i = 0; i < 4; ++i) {
        int ch = i * 256 + tid;
        srow[i] = ch >> 3;
        scol[i] = ((ch & 7) ^ (srow[i] & 7)) * 16;
    }
    const char* Ab = (const char*)A;
    const size_t K2 = (size_t)K * 2;
    const size_t branchBytes = (size_t)Nc * K2;
    char* lA = (char*)As + wave * 1024;
    char* lB = (char*)Bs + wave * 1024;

    float4v best[4][4];
#pragma unroll
    for (int mi = 0; mi < 4; ++mi)
#pragma unroll
        for (int ni = 0; ni < 4; ++ni) best[mi][ni] = (float4v)(-1e30f);

    for (int kb = kb0; kb < kb0 + kbn; ++kb) {
        const char* Bb = (const char*)WT + (size_t)kb * branchBytes;
        float4v acc[4][4] = {};
        for (int k0 = 0; k0 < K; k0 += 64) {
            const size_t kby = (size_t)k0 * 2;
#pragma unroll
            for (int i = 0; i < 4; ++i)
                gload_lds16(Ab + (size_t)(m0 + srow[i]) * K2 + kby + scol[i], lA + i * 4096);
#pragma unroll
            for (int i = 0; i < 4; ++i)
                gload_lds16(Bb + (size_t)(n0 + srow[i]) * K2 + kby + scol[i], lB + i * 4096);
            __syncthreads();
#pragma unroll
            for (int kk = 0; kk < 2; ++kk) {
                short8v av[4], bv[4];
                const int slot = kk * 4 + fq;
#pragma unroll
                for (int mi = 0; mi < 4; ++mi) {
                    int ra = wr * 64 + mi * 16 + frow;
                    av[mi] = *(const short8v*)((const char*)As + ra * 128 + ((slot ^ (ra & 7)) * 16));
                }
#pragma unroll
                for (int ni = 0; ni < 4; ++ni) {
                    int rb = wc * 64 + ni * 16 + frow;
                    bv[ni] = *(const short8v*)((const char*)Bs + rb * 128 + ((slot ^ (rb & 7)) * 16));
                }
#pragma unroll
                for (int mi = 0; mi < 4; ++mi)
#pragma unroll
                    for (int ni = 0; ni < 4; ++ni)
                        acc[mi][ni] = __builtin_amdgcn_mfma_f32_16x16x32_bf16(av[mi], bv[ni], acc[mi][ni], 0, 0, 0);
            }
            __syncthreads();
        }
#pragma unroll
        for (int ni = 0; ni < 4; ++ni) {
            int col = n0 + wc * 64 + ni * 16 + frow;
            float bval = bias[(size_t)kb * Nc + col];
#pragma unroll
            for (int mi = 0; mi < 4; ++mi) {
#pragma unroll
                for (int i = 0; i < 4; ++i) {
                    float v = acc[mi][ni][i] + bval;
                    best[mi][ni][i] = fmaxf(best[mi][ni][i], gelu_fast(v));
                }
            }
        }
    }

#pragma unroll
    for (int ni = 0; ni < 4; ++ni) {
        int col = n0 + wc * 64 + ni * 16 + frow;
#pragma unroll
        for (int mi = 0; mi < 4; ++mi) {
#pragma unroll
            for (int i = 0; i < 4; ++i) {
                int row = m0 + wr * 64 + mi * 16 + fq * 4 + i;
                P[(size_t)row * Nc + col] = f2bf(best[mi][ni][i]);
            }
        }
    }
}

// ---------------- combine: out[i] = max_s P[s][i] (bf16, 4/thread) ----------------
__global__ void combine_max(const unsigned short* __restrict__ P, unsigned short* __restrict__ out,
                            size_t tileElems, int S) {
    size_t i = ((size_t)blockIdx.x * blockDim.x + threadIdx.x) * 4;
    if (i >= tileElems) return;
    ushort4 best = *(const ushort4*)(P + i);
    for (int s = 1; s < S; ++s) {
        ushort4 c = *(const ushort4*)(P + (size_t)s * tileElems + i);
        if (bf2f(c.x) > bf2f(best.x)) best.x = c.x;
        if (bf2f(c.y) > bf2f(best.y)) best.y = c.y;
        if (bf2f(c.z) > bf2f(best.z)) best.z = c.z;
        if (bf2f(c.w) > bf2f(best.w)) best.w = c.w;
    }
    *(ushort4*)(out + i) = best;
}

// ---------------- LayerNorm over H=512: f32 in -> bf16 out ----------------
__global__ __launch_bounds__(256) void layernorm_bf16(const float* __restrict__ h,
                                                      unsigned short* __restrict__ o,
                                                      const float* __restrict__ g,
                                                      const float* __restrict__ b) {
    int row = blockIdx.x;
    const float* p = h + (size_t)row * 512;
    int tid = threadIdx.x;
    float v0 = p[tid], v1 = p[tid + 256];
    float s = v0 + v1, sq = v0 * v0 + v1 * v1;
#pragma unroll
    for (int off = 32; off >= 1; off >>= 1) {
        s += __shfl_xor(s, off);
        sq += __shfl_xor(sq, off);
    }
    __shared__ float ls[4], lq[4];
    int wid = tid >> 6, lane = tid & 63;
    if (lane == 0) { ls[wid] = s; lq[wid] = sq; }
    __syncthreads();
    float ts = ls[0] + ls[1] + ls[2] + ls[3];
    float tq = lq[0] + lq[1] + lq[2] + lq[3];
    float mean = ts / 512.f;
    float var = tq / 512.f - mean * mean;
    float inv = rsqrtf(var + 1e-5f);
    unsigned short* op = o + (size_t)row * 512;
    op[tid] = f2bf((v0 - mean) * inv * g[tid] + b[tid]);
    op[tid + 256] = f2bf((v1 - mean) * inv * g[tid + 256] + b[tid + 256]);
}

// ---------------- z = mu + eps * exp(0.5*logvar)  -> bf16 ----------------
__global__ void z_kernel(const float* __restrict__ mu, const float* __restrict__ lv,
                         const float* __restrict__ eps, unsigned short* __restrict__ z, int n4) {
    int i = blockIdx.x * blockDim.x + threadIdx.x;
    if (i >= n4) return;
    float4 m = ((const float4*)mu)[i];
    float4 l = ((const float4*)lv)[i];
    float4 e = ((const float4*)eps)[i];
    ushort4 o;
    o.x = f2bf(m.x + e.x * expf(0.5f * l.x));
    o.y = f2bf(m.y + e.y * expf(0.5f * l.y));
    o.z = f2bf(m.z + e.z * expf(0.5f * l.z));
    o.w = f2bf(m.w + e.w * expf(0.5f * l.w));
    ((ushort4*)z)[i] = o;
}

extern "C" void kernel_launch(void* const* d_in, const int* in_sizes, int n_in,
                              void* d_out, int out_size, void* d_ws, size_t ws_size,
                              hipStream_t stream) {
    const float* x        = (const float*)d_in[0];
    const int*   arows    = (const int*)d_in[1];
    const int*   acols    = (const int*)d_in[2];
    const float* avals    = (const float*)d_in[3];
    const float* basisenc = (const float*)d_in[4];
    const float* ln_g     = (const float*)d_in[5];
    const float* ln_b     = (const float*)d_in[6];
    const float* Wd_enc   = (const float*)d_in[7];
    const float* bd_enc   = (const float*)d_in[8];
    const float* W_mu     = (const float*)d_in[9];
    const float* b_mu     = (const float*)d_in[10];
    const float* W_lv     = (const float*)d_in[11];
    const float* b_lv     = (const float*)d_in[12];
    const float* Wd_dec   = (const float*)d_in[13];
    const float* bd_dec   = (const float*)d_in[14];
    const float* basisdec = (const float*)d_in[15];
    const float* epsin    = (const float*)d_in[16];

    const int N = 16384;
    const int E = in_sizes[1];

    float* ws = (float*)d_ws;
    const size_t A0 = 0;                               // f32 N*768: xa -> hF -> Penc(5xN*256 u16) -> Pdec(3xN*512 u16) -> b1
    const size_t B0 = A0 + (size_t)N * 768;            // u16 N*800: cenc -> [cdec | zb]
    const size_t C0 = B0 + (size_t)N * 400;            // f32 N*387: xbf -> a1 -> [hbf | encb] -> decb
    const size_t D0 = C0 + (size_t)N * 387;            // f32 N*197: a2 -> b2
    const size_t E0 = D0 + (size_t)N * 197;            // f32 N*102: a3 -> b3
    const size_t F0 = E0 + (size_t)N * 102;            // u16 weights
    const size_t G0 = F0 + 3100672;                    // CSR

    float* xa  = ws + A0;
    float* hF  = ws + A0;
    unsigned short* Penc = (unsigned short*)(ws + A0);  // 5 x N*256 u16 = N*640 f32
    unsigned short* Pdec = (unsigned short*)(ws + A0);  // 3 x N*512 u16 = N*768 f32
    float* b1  = ws + A0;
    unsigned short* cenc = (unsigned short*)(ws + B0);
    unsigned short* cdec = (unsigned short*)(ws + B0);
    unsigned short* zb   = cdec + (size_t)N * 544;
    unsigned short* xbf  = (unsigned short*)(ws + C0);
    float* a1 = ws + C0;
    unsigned short* hbf  = (unsigned short*)(ws + C0);
    unsigned short* encb = hbf + (size_t)N * 512;
    unsigned short* decb = (unsigned short*)(ws + C0);
    float* a2 = ws + D0;
    float* b2 = ws + D0;
    float* a3 = ws + E0;
    float* b3 = ws + E0;
    unsigned short* wF = (unsigned short*)(ws + F0);
    unsigned short* BceT   = wF;                       // 512*800
    unsigned short* BcdT   = BceT + 512 * 800;         // 768*544
    unsigned short* WdencT = BcdT + 768 * 544;         // 20*256*512
    unsigned short* WddecT = WdencT + 20 * 256 * 512;  // 20*512*256
    unsigned short* WmuT   = WddecT + 20 * 512 * 256;  // 256*256
    unsigned short* WlvT   = WmuT + 256 * 256;
    int*   csr_cnt  = (int*)(ws + G0);
    int*   csr_offs = csr_cnt + N;
    int*   csr_cur  = csr_offs + N + 1;
    int*   csr_col  = csr_cur + N;
    float* csr_val  = (float*)(csr_col + E);

    float* out_recon = (float*)d_out;
    float* out_mu    = out_recon + (size_t)N * 768;
    float* out_lv    = out_mu + (size_t)N * 256;

    // --- packs + cast (independent) ---
    {
        Bounds be = {{0, 54, 108, 210, 407, 794}};
        pack_basis_T<<<(512 * 800 + 255) / 256, 256, 0, stream>>>(basisenc, BceT, be, 768, 512, 794, 800);
        Bounds bdd = {{0, 38, 76, 146, 279, 538}};
        pack_basis_T<<<(768 * 544 + 255) / 256, 256, 0, stream>>>(basisdec, BcdT, bdd, 512, 768, 538, 544);
        pack_wT<<<(20 * 256 * 512 + 255) / 256, 256, 0, stream>>>(Wd_enc, WdencT, 20, 512, 256, 512);
        pack_wT<<<(20 * 512 * 256 + 255) / 256, 256, 0, stream>>>(Wd_dec, WddecT, 20, 256, 512, 256);
        pack_wT<<<(256 * 256 + 255) / 256, 256, 0, stream>>>(W_mu, WmuT, 1, 256, 256, 256);
        pack_wT<<<(256 * 256 + 255) / 256, 256, 0, stream>>>(W_lv, WlvT, 1, 256, 256, 256);
        cast_bf16_kernel<<<(N * 768 / 4 + 255) / 256, 256, 0, stream>>>(x, xbf, N * 768 / 4);
    }

    // 1) SpMM via device-built CSR (bf16 gather)
    hipMemsetAsync(csr_cnt, 0, N * sizeof(int), stream);
    hipMemsetAsync(cenc, 0, (size_t)N * 800 * sizeof(unsigned short), stream);
    hist_kernel<<<(E + 255) / 256, 256, 0, stream>>>(arows, csr_cnt, E);
    scan_kernel<<<1, 1024, 0, stream>>>(csr_cnt, csr_offs, csr_cur, N, E);
    scatter_kernel<<<(E + 255) / 256, 256, 0, stream>>>(arows, acols, avals, csr_cur, csr_col, csr_val, E);
    spmm_csr<<<N / 4, 256, 0, stream>>>(xbf, csr_offs, csr_col, csr_val, xa);

    // 2) wavedec enc: 768->387->197->102->54 ; cenc cols [cA4(0)|cD4(54)|cD3(108)|cD2(210)|cD1(407)]
    dwt_kernel<false, false><<<N, 128, 768 * 4, stream>>>(xa, 768, 768, a1, 387, cenc + 407, 800, 387);
    dwt_kernel<false, false><<<N, 128, 387 * 4, stream>>>(a1, 387, 387, a2, 197, cenc + 210, 800, 197);
    dwt_kernel<false, false><<<N, 128, 197 * 4, stream>>>(a2, 197, 197, a3, 102, cenc + 108, 800, 102);
    dwt_kernel<false, true><<<N, 128, 102 * 4, stream>>>(a3, 102, 102, cenc + 0, 800, cenc + 54, 800, 54);

    // 3) h = cenc @ BceT^T  [16384,512], K=800
    gemm_mfma<0><<<dim3(512 / 128, N / 128), 256, 0, stream>>>(cenc, BceT, nullptr, hF, N, 512, 800, 800, 800, 512);

    // 4) layernorm -> bf16
    layernorm_bf16<<<N, 256, 0, stream>>>(hF, hbf, ln_g, ln_b);

    // 5) enc: 5 branch-groups of 4 (hF dead -> Penc), combine -> encb
    dendritic_part<<<dim3(2, N / 128, 5), 256, 0, stream>>>(hbf, WdencT, bd_enc, Penc, N, 256, 512, 20, 5);
    combine_max<<<(int)(((size_t)N * 256 / 4 + 255) / 256), 256, 0, stream>>>(Penc, encb, (size_t)N * 256, 5);

    // 6) mu / logvar (f32 out to d_out), K=256
    gemm_mfma<0><<<dim3(256 / 128, N / 128), 256, 0, stream>>>(encb, WmuT, b_mu, out_mu, N, 256, 256, 256, 256, 256);
    gemm_mfma<0><<<dim3(256 / 128, N / 128), 256, 0, stream>>>(encb, WlvT, b_lv, out_lv, N, 256, 256, 256, 256, 256);

    // 7) z -> bf16
    z_kernel<<<(N * 256 / 4 + 255) / 256, 256, 0, stream>>>(out_mu, out_lv, epsin, zb, N * 256 / 4);

    // 8) dec: 3 branch-groups of 7/7/6 (Penc dead -> Pdec), combine -> decb
    dendritic_part<<<dim3(4, N / 128, 3), 256, 0, stream>>>(zb, WddecT, bd_dec, Pdec, N, 512, 256, 20, 3);
    combine_max<<<(int)(((size_t)N * 512 / 4 + 255) / 256), 256, 0, stream>>>(Pdec, decb, (size_t)N * 512, 3);

    // 9) memset cdec pad, then wavedec dec: 512->259->133->70->38 ; cols [0|38|76|146|279]
    hipMemsetAsync(cdec, 0, (size_t)N * 544 * sizeof(unsigned short), stream);
    dwt_kernel<true, false><<<N, 128, 512 * 4, stream>>>(decb, 512, 512, b1, 259, cdec + 279, 544, 259);
    dwt_kernel<false, false><<<N, 128, 259 * 4, stream>>>(b1, 259, 259, b2, 133, cdec + 146, 544, 133);
    dwt_kernel<false, false><<<N, 128, 133 * 4, stream>>>(b2, 133, 133, b3, 70, cdec + 76, 544, 70);
    dwt_kernel<false, true><<<N, 128, 70 * 4, stream>>>(b3, 70, 70, cdec + 0, 544, cdec + 38, 544, 38);

    // 10) recon = cdec @ BcdT^T [16384,768], K=544
    gemm_mfma<0><<<dim3(768 / 128, N / 128), 256, 0, stream>>>(cdec, BcdT, nullptr, out_recon, N, 768, 544, 544, 544, 768);

    (void)ws_size; (void)out_size; (void)n_in;
}

// Round 8
// 765.036 us; speedup vs baseline: 1.2532x; 1.2532x over previous
//
#include <hip/hip_runtime.h>

typedef __attribute__((ext_vector_type(8))) short short8v;
typedef __attribute__((ext_vector_type(8))) unsigned short ushort8v;
typedef __attribute__((ext_vector_type(4))) float float4v;

__device__ __constant__ float c_LO[8] = {
    -0.010597401784997278f, 0.032883011666982945f, 0.030841381835986965f,
    -0.18703481171888114f, -0.02798376941698385f, 0.6308807679295904f,
    0.7148465705525415f, 0.23037781330885523f};
__device__ __constant__ float c_HI[8] = {
    -0.23037781330885523f, 0.7148465705525415f, -0.6308807679295904f,
    -0.02798376941698385f, 0.18703481171888114f, 0.030841381835986965f,
    -0.032883011666982945f, -0.010597401784997278f};

__device__ __forceinline__ unsigned short f2bf(float f) {
    unsigned u = __builtin_bit_cast(unsigned, f);
    unsigned r = u + 0x7fffu + ((u >> 16) & 1u);
    return (unsigned short)(r >> 16);
}
__device__ __forceinline__ float bf2f(unsigned short u) {
    return __builtin_bit_cast(float, (unsigned)u << 16);
}

// tanh-form GELU: one exp2 + rcp
__device__ __forceinline__ float gelu_fast(float x) {
    float x3 = x * x * x;
    float y = fmaf(0.044715f, x3, x) * 0.7978845608028654f;
    float t = fminf(fmaxf(y * 2.8853900817779268f, -30.f), 30.f);
    float e = exp2f(t);
    return x * e * __builtin_amdgcn_rcpf(e + 1.0f);
}

__device__ __forceinline__ void gload_lds16(const void* g, void* l) {
    __builtin_amdgcn_global_load_lds(g, l, 16, 0, 0);
}

// ---------------- x -> bf16 cast ----------------
__global__ void cast_bf16_kernel(const float* __restrict__ in, unsigned short* __restrict__ out, int n4) {
    int i = blockIdx.x * blockDim.x + threadIdx.x;
    if (i >= n4) return;
    float4 v = ((const float4*)in)[i];
    ushort4 o;
    o.x = f2bf(v.x); o.y = f2bf(v.y); o.z = f2bf(v.z); o.w = f2bf(v.w);
    ((ushort4*)out)[i] = o;
}

// ---------------- CSR build: histogram ----------------
__global__ void hist_kernel(const int* __restrict__ rows, int* __restrict__ cnt, int E) {
    int i = blockIdx.x * blockDim.x + threadIdx.x;
    if (i < E) atomicAdd(&cnt[rows[i]], 1);
}

// ---------------- CSR build: single-block scan ----------------
__global__ __launch_bounds__(1024) void scan_kernel(const int* __restrict__ cnt, int* __restrict__ offs,
                                                    int* __restrict__ cursor, int Nrows, int E) {
    __shared__ int part[1024];
    int tid = threadIdx.x;
    const int per = Nrows / 1024;  // 16
    int base = tid * per;
    int local[16];
    int s = 0;
    for (int i = 0; i < per; ++i) { local[i] = s; s += cnt[base + i]; }
    part[tid] = s;
    __syncthreads();
    for (int off = 1; off < 1024; off <<= 1) {
        int v = part[tid];
        int w = (tid >= off) ? part[tid - off] : 0;
        __syncthreads();
        part[tid] = v + w;
        __syncthreads();
    }
    int pre = (tid == 0) ? 0 : part[tid - 1];
    for (int i = 0; i < per; ++i) {
        int o = pre + local[i];
        offs[base + i] = o;
        cursor[base + i] = o;
    }
    if (tid == 0) offs[Nrows] = E;
}

// ---------------- CSR build: scatter ----------------
__global__ void scatter_kernel(const int* __restrict__ rows, const int* __restrict__ cols,
                               const float* __restrict__ vals, int* __restrict__ cursor,
                               int* __restrict__ ccol, float* __restrict__ cval, int E) {
    int i = blockIdx.x * blockDim.x + threadIdx.x;
    if (i >= E) return;
    int r = rows[i];
    int p = atomicAdd(&cursor[r], 1);
    ccol[p] = cols[i];
    cval[p] = vals[i];
}

// ---------------- SpMM CSR: one wave per row, bf16 gather ----------------
__global__ __launch_bounds__(256) void spmm_csr(const unsigned short* __restrict__ xb, const int* __restrict__ offs,
                                                const int* __restrict__ ccol, const float* __restrict__ cval,
                                                float* __restrict__ xa) {
    int r = blockIdx.x * 4 + (threadIdx.x >> 6);
    int lane = threadIdx.x & 63;
    int s = offs[r], e = offs[r + 1];
    float acc[12] = {};
    for (int j = s; j < e; ++j) {
        int c = ccol[j];
        float v = cval[j];
        const unsigned short* xr = xb + (size_t)c * 768;
#pragma unroll
        for (int seg = 0; seg < 3; ++seg) {
            ushort4 u = *(const ushort4*)(xr + seg * 256 + lane * 4);
            acc[seg * 4 + 0] = fmaf(v, bf2f(u.x), acc[seg * 4 + 0]);
            acc[seg * 4 + 1] = fmaf(v, bf2f(u.y), acc[seg * 4 + 1]);
            acc[seg * 4 + 2] = fmaf(v, bf2f(u.z), acc[seg * 4 + 2]);
            acc[seg * 4 + 3] = fmaf(v, bf2f(u.w), acc[seg * 4 + 3]);
        }
    }
    float* o = xa + (size_t)r * 768;
#pragma unroll
    for (int seg = 0; seg < 3; ++seg) {
        float4 w = make_float4(acc[seg * 4], acc[seg * 4 + 1], acc[seg * 4 + 2], acc[seg * 4 + 3]);
        *(float4*)(o + seg * 256 + lane * 4) = w;
    }
}

// ---------------- one DWT level (pywt symmetric) ----------------
template <bool IN_BF16, bool A_BF16>
__global__ void dwt_kernel(const void* __restrict__ in, int n, int in_stride,
                           void* __restrict__ outA, int a_stride,
                           unsigned short* __restrict__ outD, int d_stride, int m) {
    extern __shared__ float srow[];
    int row = blockIdx.x;
    if (IN_BF16) {
        const unsigned short* ip = (const unsigned short*)in + (size_t)row * in_stride;
        for (int i = threadIdx.x; i < n; i += blockDim.x) srow[i] = bf2f(ip[i]);
    } else {
        const float* ip = (const float*)in + (size_t)row * in_stride;
        for (int i = threadIdx.x; i < n; i += blockDim.x) srow[i] = ip[i];
    }
    __syncthreads();
    for (int j = threadIdx.x; j < m; j += blockDim.x) {
        float a = 0.f, d = 0.f;
#pragma unroll
        for (int i = 0; i < 8; ++i) {
            int p = 2 * j + 7 - i;
            int q = (p < 6) ? (5 - p) : ((p < n + 6) ? (p - 6) : (2 * n + 5 - p));
            float xv = srow[q];
            a = fmaf(c_LO[i], xv, a);
            d = fmaf(c_HI[i], xv, d);
        }
        if (A_BF16)
            ((unsigned short*)outA)[(size_t)row * a_stride + j] = f2bf(a);
        else
            ((float*)outA)[(size_t)row * a_stride + j] = a;
        outD[(size_t)row * d_stride + j] = f2bf(d);
    }
}

// ---------------- pack basis stack -> transposed bf16 [N][Kpad] ----------------
struct Bounds { int b[6]; };

__global__ void pack_basis_T(const float* __restrict__ basis, unsigned short* __restrict__ BT,
                             Bounds bd, int brows, int N, int K, int Kpad) {
    int idx = blockIdx.x * blockDim.x + threadIdx.x;
    if (idx >= N * Kpad) return;
    int n = idx / Kpad, k = idx - n * Kpad;
    float v = 0.f;
    if (k < K) {
        int s = 0;
#pragma unroll
        for (int t = 1; t < 5; ++t)
            if (k >= bd.b[t]) s = t;
        int lr = k - bd.b[s];
        v = basis[((size_t)s * brows + lr) * N + n];
    }
    BT[idx] = f2bf(v);
}

// ---------------- pack weights [NB][K][N] -> transposed bf16 [NB][N][Kpad] ----------------
__global__ void pack_wT(const float* __restrict__ W, unsigned short* __restrict__ WT,
                        int NB, int K, int N, int Kpad) {
    int idx = blockIdx.x * blockDim.x + threadIdx.x;
    int tot = NB * N * Kpad;
    if (idx >= tot) return;
    int b = idx / (N * Kpad);
    int r = idx - b * (N * Kpad);
    int n = r / Kpad, k = r - n * Kpad;
    float v = (k < K) ? W[((size_t)b * K + k) * N + n] : 0.f;
    WT[idx] = f2bf(v);
}

// ---------------- bf16 MFMA GEMM (proven) ----------------
template <int OUT_BF16>
__global__ __launch_bounds__(256) void gemm_mfma(const unsigned short* __restrict__ A,
                                                 const unsigned short* __restrict__ BT,
                                                 const float* __restrict__ bias,
                                                 void* __restrict__ Cv,
                                                 int M, int N, int K, int lda, int ldb, int ldc) {
    __shared__ __align__(16) unsigned short As[128 * 32];
    __shared__ __align__(16) unsigned short Bs[128 * 32];
    const int tid = threadIdx.x;
    const int wave = tid >> 6, lane = tid & 63;
    const int m0 = blockIdx.y * 128, n0 = blockIdx.x * 128;
    const int wr = wave >> 1, wc = wave & 1;
    const int frow = lane & 15, fq = lane >> 4;

    const int off0 = tid * 16;
    const int r0 = off0 >> 6, c0 = off0 & 63;
    const int r1 = (off0 + 4096) >> 6, c1 = (off0 + 4096) & 63;
    const char* Ab = (const char*)A;
    const char* Bb = (const char*)BT;
    size_t gA0 = (size_t)(m0 + r0) * lda * 2 + c0;
    size_t gA1 = (size_t)(m0 + r1) * lda * 2 + c1;
    size_t gB0 = (size_t)(n0 + r0) * ldb * 2 + c0;
    size_t gB1 = (size_t)(n0 + r1) * ldb * 2 + c1;
    char* lA0 = (char*)As + wave * 1024;
    char* lB0 = (char*)Bs + wave * 1024;

    const int aoff = (wr * 64 + frow) * 32 + fq * 8;
    const int boff = (wc * 64 + frow) * 32 + fq * 8;

    float4v acc[4][4] = {};
    for (int k0 = 0; k0 < K; k0 += 32) {
        size_t kb2 = (size_t)k0 * 2;
        gload_lds16(Ab + gA0 + kb2, lA0);
        gload_lds16(Ab + gA1 + kb2, lA0 + 4096);
        gload_lds16(Bb + gB0 + kb2, lB0);
        gload_lds16(Bb + gB1 + kb2, lB0 + 4096);
        __syncthreads();
        short8v av[4], bv[4];
#pragma unroll
        for (int i = 0; i < 4; ++i) av[i] = *(const short8v*)(As + aoff + i * 512);
#pragma unroll
        for (int i = 0; i < 4; ++i) bv[i] = *(const short8v*)(Bs + boff + i * 512);
#pragma unroll
        for (int mi = 0; mi < 4; ++mi)
#pragma unroll
            for (int ni = 0; ni < 4; ++ni)
                acc[mi][ni] = __builtin_amdgcn_mfma_f32_16x16x32_bf16(av[mi], bv[ni], acc[mi][ni], 0, 0, 0);
        __syncthreads();
    }
#pragma unroll
    for (int ni = 0; ni < 4; ++ni) {
        int col = n0 + wc * 64 + ni * 16 + frow;
        float bval = bias ? bias[col] : 0.f;
#pragma unroll
        for (int mi = 0; mi < 4; ++mi) {
#pragma unroll
            for (int i = 0; i < 4; ++i) {
                int row = m0 + wr * 64 + mi * 16 + fq * 4 + i;
                float v = acc[mi][ni][i] + bval;
                if (OUT_BF16)
                    ((unsigned short*)Cv)[(size_t)row * ldc + col] = f2bf(v);
                else
                    ((float*)Cv)[(size_t)row * ldc + col] = v;
            }
        }
    }
}

// ---- dendritic partial v4: occupancy-first. Block tile 128x64, wave tile 64x32, BK=64. ----
// A [M,K] bf16; WT [nb][Nc][K] bf16; bias [nb][Nc] f32; P [ngrp][M][Nc] bf16.
// grid (Nc/64, M/128, ngrp), block 256 (4 waves, 2Mx2N). ~64 AGPR + ~90 VGPR -> >=3 waves/SIMD.
__global__ __launch_bounds__(256, 3) void dendritic_part(const unsigned short* __restrict__ A,
                                                         const unsigned short* __restrict__ WT,
                                                         const float* __restrict__ bias,
                                                         unsigned short* __restrict__ Pout,
                                                         int M, int Nc, int K, int nb, int ngrp) {
    __shared__ __align__(16) unsigned short As[128 * 64];  // 16 KB
    __shared__ __align__(16) unsigned short Bs[64 * 64];   // 8 KB
    const int tid = threadIdx.x;
    const int wave = tid >> 6;
    const int lane = tid & 63;
    const int n0 = blockIdx.x * 64, m0 = blockIdx.y * 128;
    const int gz = blockIdx.z;
    const int q = nb / ngrp, rmd = nb - q * ngrp;
    const int kb0 = gz * q + (gz < rmd ? gz : rmd);
    const int kbn = q + (gz < rmd ? 1 : 0);
    unsigned short* P = Pout + (size_t)gz * M * Nc;
    const int wr = wave >> 1, wc = wave & 1;
    const int frow = lane & 15, fq = lane >> 4;

    // staging: chunk ch -> LDS linear byte ch*16 (row=ch>>3, slot=ch&7);
    // global col pre-swizzled: slot_src = slot ^ (row&7)  (involution; read applies same XOR)
    int srA[4], scA[4];
#pragma unroll
    for (int i = 0; i < 4; ++i) {
        int ch = i * 256 + tid;
        srA[i] = ch >> 3;
        scA[i] = ((ch & 7) ^ (srA[i] & 7)) * 16;
    }
    int srB[2], scB[2];
#pragma unroll
    for (int i = 0; i < 2; ++i) {
        int ch = i * 256 + tid;
        srB[i] = ch >> 3;
        scB[i] = ((ch & 7) ^ (srB[i] & 7)) * 16;
    }
    const char* Ab = (const char*)A;
    const size_t K2 = (size_t)K * 2;
    const size_t branchBytes = (size_t)Nc * K2;
    char* lA = (char*)As + wave * 1024;
    char* lB = (char*)Bs + wave * 1024;

    float4v best[4][2];
#pragma unroll
    for (int mi = 0; mi < 4; ++mi)
#pragma unroll
        for (int ni = 0; ni < 2; ++ni) best[mi][ni] = (float4v)(-1e30f);

    for (int kb = kb0; kb < kb0 + kbn; ++kb) {
        const char* Bb = (const char*)WT + (size_t)kb * branchBytes;
        // bias folded into acc init (C/D col = n0 + wc*32 + ni*16 + frow, same for all 4 regs)
        float4v acc[4][2];
#pragma unroll
        for (int ni = 0; ni < 2; ++ni) {
            float bval = bias[(size_t)kb * Nc + n0 + wc * 32 + ni * 16 + frow];
#pragma unroll
            for (int mi = 0; mi < 4; ++mi) acc[mi][ni] = (float4v)(bval);
        }
        for (int k0 = 0; k0 < K; k0 += 64) {
            const size_t kby = (size_t)k0 * 2;
#pragma unroll
            for (int i = 0; i < 4; ++i)
                gload_lds16(Ab + (size_t)(m0 + srA[i]) * K2 + kby + scA[i], lA + i * 4096);
#pragma unroll
            for (int i = 0; i < 2; ++i)
                gload_lds16(Bb + (size_t)(n0 + srB[i]) * K2 + kby + scB[i], lB + i * 4096);
            __syncthreads();
#pragma unroll
            for (int kk = 0; kk < 2; ++kk) {
                short8v av[4], bv[2];
                const int slot = kk * 4 + fq;
#pragma unroll
                for (int mi = 0; mi < 4; ++mi) {
                    int ra = wr * 64 + mi * 16 + frow;
                    av[mi] = *(const short8v*)((const char*)As + ra * 128 + ((slot ^ (ra & 7)) * 16));
                }
#pragma unroll
                for (int ni = 0; ni < 2; ++ni) {
                    int rb = wc * 32 + ni * 16 + frow;
                    bv[ni] = *(const short8v*)((const char*)Bs + rb * 128 + ((slot ^ (rb & 7)) * 16));
                }
#pragma unroll
                for (int mi = 0; mi < 4; ++mi)
#pragma unroll
                    for (int ni = 0; ni < 2; ++ni)
                        acc[mi][ni] = __builtin_amdgcn_mfma_f32_16x16x32_bf16(av[mi], bv[ni], acc[mi][ni], 0, 0, 0);
            }
            __syncthreads();
        }
#pragma unroll
        for (int ni = 0; ni < 2; ++ni)
#pragma unroll
            for (int mi = 0; mi < 4; ++mi)
#pragma unroll
                for (int i = 0; i < 4; ++i)
                    best[mi][ni][i] = fmaxf(best[mi][ni][i], gelu_fast(acc[mi][ni][i]));
    }

#pragma unroll
    for (int ni = 0; ni < 2; ++ni) {
        int col = n0 + wc * 32 + ni * 16 + frow;
#pragma unroll
        for (int mi = 0; mi < 4; ++mi) {
#pragma unroll
            for (int i = 0; i < 4; ++i) {
                int row = m0 + wr * 64 + mi * 16 + fq * 4 + i;
                P[(size_t)row * Nc + col] = f2bf(best[mi][ni][i]);
            }
        }
    }
}

// ---------------- combine: out[i] = max_s P[s][i] (bf16, 4/thread) ----------------
__global__ void combine_max(const unsigned short* __restrict__ P, unsigned short* __restrict__ out,
                            size_t tileElems, int S) {
    size_t i = ((size_t)blockIdx.x * blockDim.x + threadIdx.x) * 4;
    if (i >= tileElems) return;
    ushort4 best = *(const ushort4*)(P + i);
    for (int s = 1; s < S; ++s) {
        ushort4 c = *(const ushort4*)(P + (size_t)s * tileElems + i);
        if (bf2f(c.x) > bf2f(best.x)) best.x = c.x;
        if (bf2f(c.y) > bf2f(best.y)) best.y = c.y;
        if (bf2f(c.z) > bf2f(best.z)) best.z = c.z;
        if (bf2f(c.w) > bf2f(best.w)) best.w = c.w;
    }
    *(ushort4*)(out + i) = best;
}

// ---------------- LayerNorm over H=512: f32 in -> bf16 out ----------------
__global__ __launch_bounds__(256) void layernorm_bf16(const float* __restrict__ h,
                                                      unsigned short* __restrict__ o,
                                                      const float* __restrict__ g,
                                                      const float* __restrict__ b) {
    int row = blockIdx.x;
    const float* p = h + (size_t)row * 512;
    int tid = threadIdx.x;
    float v0 = p[tid], v1 = p[tid + 256];
    float s = v0 + v1, sq = v0 * v0 + v1 * v1;
#pragma unroll
    for (int off = 32; off >= 1; off >>= 1) {
        s += __shfl_xor(s, off);
        sq += __shfl_xor(sq, off);
    }
    __shared__ float ls[4], lq[4];
    int wid = tid >> 6, lane = tid & 63;
    if (lane == 0) { ls[wid] = s; lq[wid] = sq; }
    __syncthreads();
    float ts = ls[0] + ls[1] + ls[2] + ls[3];
    float tq = lq[0] + lq[1] + lq[2] + lq[3];
    float mean = ts / 512.f;
    float var = tq / 512.f - mean * mean;
    float inv = rsqrtf(var + 1e-5f);
    unsigned short* op = o + (size_t)row * 512;
    op[tid] = f2bf((v0 - mean) * inv * g[tid] + b[tid]);
    op[tid + 256] = f2bf((v1 - mean) * inv * g[tid + 256] + b[tid + 256]);
}

// ---------------- z = mu + eps * exp(0.5*logvar)  -> bf16 ----------------
__global__ void z_kernel(const float* __restrict__ mu, const float* __restrict__ lv,
                         const float* __restrict__ eps, unsigned short* __restrict__ z, int n4) {
    int i = blockIdx.x * blockDim.x + threadIdx.x;
    if (i >= n4) return;
    float4 m = ((const float4*)mu)[i];
    float4 l = ((const float4*)lv)[i];
    float4 e = ((const float4*)eps)[i];
    ushort4 o;
    o.x = f2bf(m.x + e.x * expf(0.5f * l.x));
    o.y = f2bf(m.y + e.y * expf(0.5f * l.y));
    o.z = f2bf(m.z + e.z * expf(0.5f * l.z));
    o.w = f2bf(m.w + e.w * expf(0.5f * l.w));
    ((ushort4*)z)[i] = o;
}

extern "C" void kernel_launch(void* const* d_in, const int* in_sizes, int n_in,
                              void* d_out, int out_size, void* d_ws, size_t ws_size,
                              hipStream_t stream) {
    const float* x        = (const float*)d_in[0];
    const int*   arows    = (const int*)d_in[1];
    const int*   acols    = (const int*)d_in[2];
    const float* avals    = (const float*)d_in[3];
    const float* basisenc = (const float*)d_in[4];
    const float* ln_g     = (const float*)d_in[5];
    const float* ln_b     = (const float*)d_in[6];
    const float* Wd_enc   = (const float*)d_in[7];
    const float* bd_enc   = (const float*)d_in[8];
    const float* W_mu     = (const float*)d_in[9];
    const float* b_mu     = (const float*)d_in[10];
    const float* W_lv     = (const float*)d_in[11];
    const float* b_lv     = (const float*)d_in[12];
    const float* Wd_dec   = (const float*)d_in[13];
    const float* bd_dec   = (const float*)d_in[14];
    const float* basisdec = (const float*)d_in[15];
    const float* epsin    = (const float*)d_in[16];

    const int N = 16384;
    const int E = in_sizes[1];

    float* ws = (float*)d_ws;
    const size_t A0 = 0;                               // f32 N*768: xa -> hF -> Penc(5xN*256 u16) -> Pdec(3xN*512 u16) -> b1
    const size_t B0 = A0 + (size_t)N * 768;            // u16 N*800: cenc -> [cdec | zb]
    const size_t C0 = B0 + (size_t)N * 400;            // f32 N*387: xbf -> a1 -> [hbf | encb] -> decb
    const size_t D0 = C0 + (size_t)N * 387;            // f32 N*197: a2 -> b2
    const size_t E0 = D0 + (size_t)N * 197;            // f32 N*102: a3 -> b3
    const size_t F0 = E0 + (size_t)N * 102;            // u16 weights
    const size_t G0 = F0 + 3100672;                    // CSR

    float* xa  = ws + A0;
    float* hF  = ws + A0;
    unsigned short* Penc = (unsigned short*)(ws + A0);  // 5 x N*256 u16
    unsigned short* Pdec = (unsigned short*)(ws + A0);  // 3 x N*512 u16 (exact fit)
    float* b1  = ws + A0;
    unsigned short* cenc = (unsigned short*)(ws + B0);
    unsigned short* cdec = (unsigned short*)(ws + B0);
    unsigned short* zb   = cdec + (size_t)N * 544;
    unsigned short* xbf  = (unsigned short*)(ws + C0);
    float* a1 = ws + C0;
    unsigned short* hbf  = (unsigned short*)(ws + C0);
    unsigned short* encb = hbf + (size_t)N * 512;
    unsigned short* decb = (unsigned short*)(ws + C0);
    float* a2 = ws + D0;
    float* b2 = ws + D0;
    float* a3 = ws + E0;
    float* b3 = ws + E0;
    unsigned short* wF = (unsigned short*)(ws + F0);
    unsigned short* BceT   = wF;                       // 512*800
    unsigned short* BcdT   = BceT + 512 * 800;         // 768*544
    unsigned short* WdencT = BcdT + 768 * 544;         // 20*256*512
    unsigned short* WddecT = WdencT + 20 * 256 * 512;  // 20*512*256
    unsigned short* WmuT   = WddecT + 20 * 512 * 256;  // 256*256
    unsigned short* WlvT   = WmuT + 256 * 256;
    int*   csr_cnt  = (int*)(ws + G0);
    int*   csr_offs = csr_cnt + N;
    int*   csr_cur  = csr_offs + N + 1;
    int*   csr_col  = csr_cur + N;
    float* csr_val  = (float*)(csr_col + E);

    float* out_recon = (float*)d_out;
    float* out_mu    = out_recon + (size_t)N * 768;
    float* out_lv    = out_mu + (size_t)N * 256;

    // --- packs + cast (independent) ---
    {
        Bounds be = {{0, 54, 108, 210, 407, 794}};
        pack_basis_T<<<(512 * 800 + 255) / 256, 256, 0, stream>>>(basisenc, BceT, be, 768, 512, 794, 800);
        Bounds bdd = {{0, 38, 76, 146, 279, 538}};
        pack_basis_T<<<(768 * 544 + 255) / 256, 256, 0, stream>>>(basisdec, BcdT, bdd, 512, 768, 538, 544);
        pack_wT<<<(20 * 256 * 512 + 255) / 256, 256, 0, stream>>>(Wd_enc, WdencT, 20, 512, 256, 512);
        pack_wT<<<(20 * 512 * 256 + 255) / 256, 256, 0, stream>>>(Wd_dec, WddecT, 20, 256, 512, 256);
        pack_wT<<<(256 * 256 + 255) / 256, 256, 0, stream>>>(W_mu, WmuT, 1, 256, 256, 256);
        pack_wT<<<(256 * 256 + 255) / 256, 256, 0, stream>>>(W_lv, WlvT, 1, 256, 256, 256);
        cast_bf16_kernel<<<(N * 768 / 4 + 255) / 256, 256, 0, stream>>>(x, xbf, N * 768 / 4);
    }

    // 1) SpMM via device-built CSR (bf16 gather)
    hipMemsetAsync(csr_cnt, 0, N * sizeof(int), stream);
    hipMemsetAsync(cenc, 0, (size_t)N * 800 * sizeof(unsigned short), stream);
    hist_kernel<<<(E + 255) / 256, 256, 0, stream>>>(arows, csr_cnt, E);
    scan_kernel<<<1, 1024, 0, stream>>>(csr_cnt, csr_offs, csr_cur, N, E);
    scatter_kernel<<<(E + 255) / 256, 256, 0, stream>>>(arows, acols, avals, csr_cur, csr_col, csr_val, E);
    spmm_csr<<<N / 4, 256, 0, stream>>>(xbf, csr_offs, csr_col, csr_val, xa);

    // 2) wavedec enc: 768->387->197->102->54 ; cenc cols [cA4(0)|cD4(54)|cD3(108)|cD2(210)|cD1(407)]
    dwt_kernel<false, false><<<N, 128, 768 * 4, stream>>>(xa, 768, 768, a1, 387, cenc + 407, 800, 387);
    dwt_kernel<false, false><<<N, 128, 387 * 4, stream>>>(a1, 387, 387, a2, 197, cenc + 210, 800, 197);
    dwt_kernel<false, false><<<N, 128, 197 * 4, stream>>>(a2, 197, 197, a3, 102, cenc + 108, 800, 102);
    dwt_kernel<false, true><<<N, 128, 102 * 4, stream>>>(a3, 102, 102, cenc + 0, 800, cenc + 54, 800, 54);

    // 3) h = cenc @ BceT^T  [16384,512], K=800
    gemm_mfma<0><<<dim3(512 / 128, N / 128), 256, 0, stream>>>(cenc, BceT, nullptr, hF, N, 512, 800, 800, 800, 512);

    // 4) layernorm -> bf16
    layernorm_bf16<<<N, 256, 0, stream>>>(hF, hbf, ln_g, ln_b);

    // 5) enc: 5 branch-groups of 4 (hF dead -> Penc), combine -> encb
    dendritic_part<<<dim3(256 / 64, N / 128, 5), 256, 0, stream>>>(hbf, WdencT, bd_enc, Penc, N, 256, 512, 20, 5);
    combine_max<<<(int)(((size_t)N * 256 / 4 + 255) / 256), 256, 0, stream>>>(Penc, encb, (size_t)N * 256, 5);

    // 6) mu / logvar (f32 out to d_out), K=256
    gemm_mfma<0><<<dim3(256 / 128, N / 128), 256, 0, stream>>>(encb, WmuT, b_mu, out_mu, N, 256, 256, 256, 256, 256);
    gemm_mfma<0><<<dim3(256 / 128, N / 128), 256, 0, stream>>>(encb, WlvT, b_lv, out_lv, N, 256, 256, 256, 256, 256);

    // 7) z -> bf16
    z_kernel<<<(N * 256 / 4 + 255) / 256, 256, 0, stream>>>(out_mu, out_lv, epsin, zb, N * 256 / 4);

    // 8) dec: 3 branch-groups of 7/7/6 (Penc dead -> Pdec), combine -> decb
    dendritic_part<<<dim3(512 / 64, N / 128, 3), 256, 0, stream>>>(zb, WddecT, bd_dec, Pdec, N, 512, 256, 20, 3);
    combine_max<<<(int)(((size_t)N * 512 / 4 + 255) / 256), 256, 0, stream>>>(Pdec, decb, (size_t)N * 512, 3);

    // 9) memset cdec pad, then wavedec dec: 512->259->133->70->38 ; cols [0|38|76|146|279]
    hipMemsetAsync(cdec, 0, (size_t)N * 544 * sizeof(unsigned short), stream);
    dwt_kernel<true, false><<<N, 128, 512 * 4, stream>>>(decb, 512, 512, b1, 259, cdec + 279, 544, 259);
    dwt_kernel<false, false><<<N, 128, 259 * 4, stream>>>(b1, 259, 259, b2, 133, cdec + 146, 544, 133);
    dwt_kernel<false, false><<<N, 128, 133 * 4, stream>>>(b2, 133, 133, b3, 70, cdec + 76, 544, 70);
    dwt_kernel<false, true><<<N, 128, 70 * 4, stream>>>(b3, 70, 70, cdec + 0, 544, cdec + 38, 544, 38);

    // 10) recon = cdec @ BcdT^T [16384,768], K=544
    gemm_mfma<0><<<dim3(768 / 128, N / 128), 256, 0, stream>>>(cdec, BcdT, nullptr, out_recon, N, 768, 544, 544, 544, 768);

    (void)ws_size; (void)out_size; (void)n_in;
}

// Round 9
// 710.985 us; speedup vs baseline: 1.3485x; 1.0760x over previous
//
#include <hip/hip_runtime.h>

typedef __attribute__((ext_vector_type(8))) short short8v;
typedef __attribute__((ext_vector_type(8))) unsigned short ushort8v;
typedef __attribute__((ext_vector_type(4))) float float4v;

__device__ __constant__ float c_LO[8] = {
    -0.010597401784997278f, 0.032883011666982945f, 0.030841381835986965f,
    -0.18703481171888114f, -0.02798376941698385f, 0.6308807679295904f,
    0.7148465705525415f, 0.23037781330885523f};
__device__ __constant__ float c_HI[8] = {
    -0.23037781330885523f, 0.7148465705525415f, -0.6308807679295904f,
    -0.02798376941698385f, 0.18703481171888114f, 0.030841381835986965f,
    -0.032883011666982945f, -0.010597401784997278f};

__device__ __forceinline__ unsigned short f2bf(float f) {
    unsigned u = __builtin_bit_cast(unsigned, f);
    unsigned r = u + 0x7fffu + ((u >> 16) & 1u);
    return (unsigned short)(r >> 16);
}
__device__ __forceinline__ float bf2f(unsigned short u) {
    return __builtin_bit_cast(float, (unsigned)u << 16);
}

// tanh-form GELU: one exp2 + rcp
__device__ __forceinline__ float gelu_fast(float x) {
    float x3 = x * x * x;
    float y = fmaf(0.044715f, x3, x) * 0.7978845608028654f;
    float t = fminf(fmaxf(y * 2.8853900817779268f, -30.f), 30.f);
    float e = exp2f(t);
    return x * e * __builtin_amdgcn_rcpf(e + 1.0f);
}

__device__ __forceinline__ void gload_lds16(const void* g, void* l) {
    __builtin_amdgcn_global_load_lds(g, l, 16, 0, 0);
}

// ---------------- x -> bf16 cast ----------------
__global__ void cast_bf16_kernel(const float* __restrict__ in, unsigned short* __restrict__ out, int n4) {
    int i = blockIdx.x * blockDim.x + threadIdx.x;
    if (i >= n4) return;
    float4 v = ((const float4*)in)[i];
    ushort4 o;
    o.x = f2bf(v.x); o.y = f2bf(v.y); o.z = f2bf(v.z); o.w = f2bf(v.w);
    ((ushort4*)out)[i] = o;
}

// ---------------- CSR build: histogram ----------------
__global__ void hist_kernel(const int* __restrict__ rows, int* __restrict__ cnt, int E) {
    int i = blockIdx.x * blockDim.x + threadIdx.x;
    if (i < E) atomicAdd(&cnt[rows[i]], 1);
}

// ---------------- CSR build: single-block scan ----------------
__global__ __launch_bounds__(1024) void scan_kernel(const int* __restrict__ cnt, int* __restrict__ offs,
                                                    int* __restrict__ cursor, int Nrows, int E) {
    __shared__ int part[1024];
    int tid = threadIdx.x;
    const int per = Nrows / 1024;  // 16
    int base = tid * per;
    int local[16];
    int s = 0;
    for (int i = 0; i < per; ++i) { local[i] = s; s += cnt[base + i]; }
    part[tid] = s;
    __syncthreads();
    for (int off = 1; off < 1024; off <<= 1) {
        int v = part[tid];
        int w = (tid >= off) ? part[tid - off] : 0;
        __syncthreads();
        part[tid] = v + w;
        __syncthreads();
    }
    int pre = (tid == 0) ? 0 : part[tid - 1];
    for (int i = 0; i < per; ++i) {
        int o = pre + local[i];
        offs[base + i] = o;
        cursor[base + i] = o;
    }
    if (tid == 0) offs[Nrows] = E;
}

// ---------------- CSR build: scatter ----------------
__global__ void scatter_kernel(const int* __restrict__ rows, const int* __restrict__ cols,
                               const float* __restrict__ vals, int* __restrict__ cursor,
                               int* __restrict__ ccol, float* __restrict__ cval, int E) {
    int i = blockIdx.x * blockDim.x + threadIdx.x;
    if (i >= E) return;
    int r = rows[i];
    int p = atomicAdd(&cursor[r], 1);
    ccol[p] = cols[i];
    cval[p] = vals[i];
}

// ---------------- SpMM CSR: one wave per row, bf16 gather ----------------
__global__ __launch_bounds__(256) void spmm_csr(const unsigned short* __restrict__ xb, const int* __restrict__ offs,
                                                const int* __restrict__ ccol, const float* __restrict__ cval,
                                                float* __restrict__ xa) {
    int r = blockIdx.x * 4 + (threadIdx.x >> 6);
    int lane = threadIdx.x & 63;
    int s = offs[r], e = offs[r + 1];
    float acc[12] = {};
    for (int j = s; j < e; ++j) {
        int c = ccol[j];
        float v = cval[j];
        const unsigned short* xr = xb + (size_t)c * 768;
#pragma unroll
        for (int seg = 0; seg < 3; ++seg) {
            ushort4 u = *(const ushort4*)(xr + seg * 256 + lane * 4);
            acc[seg * 4 + 0] = fmaf(v, bf2f(u.x), acc[seg * 4 + 0]);
            acc[seg * 4 + 1] = fmaf(v, bf2f(u.y), acc[seg * 4 + 1]);
            acc[seg * 4 + 2] = fmaf(v, bf2f(u.z), acc[seg * 4 + 2]);
            acc[seg * 4 + 3] = fmaf(v, bf2f(u.w), acc[seg * 4 + 3]);
        }
    }
    float* o = xa + (size_t)r * 768;
#pragma unroll
    for (int seg = 0; seg < 3; ++seg) {
        float4 w = make_float4(acc[seg * 4], acc[seg * 4 + 1], acc[seg * 4 + 2], acc[seg * 4 + 3]);
        *(float4*)(o + seg * 256 + lane * 4) = w;
    }
}

// ---------------- one DWT level (pywt symmetric) ----------------
template <bool IN_BF16, bool A_BF16>
__global__ void dwt_kernel(const void* __restrict__ in, int n, int in_stride,
                           void* __restrict__ outA, int a_stride,
                           unsigned short* __restrict__ outD, int d_stride, int m) {
    extern __shared__ float srow[];
    int row = blockIdx.x;
    if (IN_BF16) {
        const unsigned short* ip = (const unsigned short*)in + (size_t)row * in_stride;
        for (int i = threadIdx.x; i < n; i += blockDim.x) srow[i] = bf2f(ip[i]);
    } else {
        const float* ip = (const float*)in + (size_t)row * in_stride;
        for (int i = threadIdx.x; i < n; i += blockDim.x) srow[i] = ip[i];
    }
    __syncthreads();
    for (int j = threadIdx.x; j < m; j += blockDim.x) {
        float a = 0.f, d = 0.f;
#pragma unroll
        for (int i = 0; i < 8; ++i) {
            int p = 2 * j + 7 - i;
            int q = (p < 6) ? (5 - p) : ((p < n + 6) ? (p - 6) : (2 * n + 5 - p));
            float xv = srow[q];
            a = fmaf(c_LO[i], xv, a);
            d = fmaf(c_HI[i], xv, d);
        }
        if (A_BF16)
            ((unsigned short*)outA)[(size_t)row * a_stride + j] = f2bf(a);
        else
            ((float*)outA)[(size_t)row * a_stride + j] = a;
        outD[(size_t)row * d_stride + j] = f2bf(d);
    }
}

// ---------------- pack basis stack -> transposed bf16 [N][Kpad] ----------------
struct Bounds { int b[6]; };

__global__ void pack_basis_T(const float* __restrict__ basis, unsigned short* __restrict__ BT,
                             Bounds bd, int brows, int N, int K, int Kpad) {
    int idx = blockIdx.x * blockDim.x + threadIdx.x;
    if (idx >= N * Kpad) return;
    int n = idx / Kpad, k = idx - n * Kpad;
    float v = 0.f;
    if (k < K) {
        int s = 0;
#pragma unroll
        for (int t = 1; t < 5; ++t)
            if (k >= bd.b[t]) s = t;
        int lr = k - bd.b[s];
        v = basis[((size_t)s * brows + lr) * N + n];
    }
    BT[idx] = f2bf(v);
}

// ---------------- pack weights [NB][K][N] -> transposed bf16 [NB][N][Kpad] ----------------
__global__ void pack_wT(const float* __restrict__ W, unsigned short* __restrict__ WT,
                        int NB, int K, int N, int Kpad) {
    int idx = blockIdx.x * blockDim.x + threadIdx.x;
    int tot = NB * N * Kpad;
    if (idx >= tot) return;
    int b = idx / (N * Kpad);
    int r = idx - b * (N * Kpad);
    int n = r / Kpad, k = r - n * Kpad;
    float v = (k < K) ? W[((size_t)b * K + k) * N + n] : 0.f;
    WT[idx] = f2bf(v);
}

// ---------------- bf16 MFMA GEMM (proven) ----------------
template <int OUT_BF16>
__global__ __launch_bounds__(256) void gemm_mfma(const unsigned short* __restrict__ A,
                                                 const unsigned short* __restrict__ BT,
                                                 const float* __restrict__ bias,
                                                 void* __restrict__ Cv,
                                                 int M, int N, int K, int lda, int ldb, int ldc) {
    __shared__ __align__(16) unsigned short As[128 * 32];
    __shared__ __align__(16) unsigned short Bs[128 * 32];
    const int tid = threadIdx.x;
    const int wave = tid >> 6, lane = tid & 63;
    const int m0 = blockIdx.y * 128, n0 = blockIdx.x * 128;
    const int wr = wave >> 1, wc = wave & 1;
    const int frow = lane & 15, fq = lane >> 4;

    const int off0 = tid * 16;
    const int r0 = off0 >> 6, c0 = off0 & 63;
    const int r1 = (off0 + 4096) >> 6, c1 = (off0 + 4096) & 63;
    const char* Ab = (const char*)A;
    const char* Bb = (const char*)BT;
    size_t gA0 = (size_t)(m0 + r0) * lda * 2 + c0;
    size_t gA1 = (size_t)(m0 + r1) * lda * 2 + c1;
    size_t gB0 = (size_t)(n0 + r0) * ldb * 2 + c0;
    size_t gB1 = (size_t)(n0 + r1) * ldb * 2 + c1;
    char* lA0 = (char*)As + wave * 1024;
    char* lB0 = (char*)Bs + wave * 1024;

    const int aoff = (wr * 64 + frow) * 32 + fq * 8;
    const int boff = (wc * 64 + frow) * 32 + fq * 8;

    float4v acc[4][4] = {};
    for (int k0 = 0; k0 < K; k0 += 32) {
        size_t kb2 = (size_t)k0 * 2;
        gload_lds16(Ab + gA0 + kb2, lA0);
        gload_lds16(Ab + gA1 + kb2, lA0 + 4096);
        gload_lds16(Bb + gB0 + kb2, lB0);
        gload_lds16(Bb + gB1 + kb2, lB0 + 4096);
        __syncthreads();
        short8v av[4], bv[4];
#pragma unroll
        for (int i = 0; i < 4; ++i) av[i] = *(const short8v*)(As + aoff + i * 512);
#pragma unroll
        for (int i = 0; i < 4; ++i) bv[i] = *(const short8v*)(Bs + boff + i * 512);
#pragma unroll
        for (int mi = 0; mi < 4; ++mi)
#pragma unroll
            for (int ni = 0; ni < 4; ++ni)
                acc[mi][ni] = __builtin_amdgcn_mfma_f32_16x16x32_bf16(av[mi], bv[ni], acc[mi][ni], 0, 0, 0);
        __syncthreads();
    }
#pragma unroll
    for (int ni = 0; ni < 4; ++ni) {
        int col = n0 + wc * 64 + ni * 16 + frow;
        float bval = bias ? bias[col] : 0.f;
#pragma unroll
        for (int mi = 0; mi < 4; ++mi) {
#pragma unroll
            for (int i = 0; i < 4; ++i) {
                int row = m0 + wr * 64 + mi * 16 + fq * 4 + i;
                float v = acc[mi][ni][i] + bval;
                if (OUT_BF16)
                    ((unsigned short*)Cv)[(size_t)row * ldc + col] = f2bf(v);
                else
                    ((float*)Cv)[(size_t)row * ldc + col] = v;
            }
        }
    }
}

// ---- dendritic partial v5: v4 + XCD-aware m-major swizzle (1D grid, nwg%8==0). ----
// Block tile 128x64, wave tile 64x32, BK=64, >=3 waves/SIMD.
// Logical order m-major: each XCD owns a contiguous run of m-tiles -> A L2-resident.
__global__ __launch_bounds__(256, 3) void dendritic_part(const unsigned short* __restrict__ A,
                                                         const unsigned short* __restrict__ WT,
                                                         const float* __restrict__ bias,
                                                         unsigned short* __restrict__ Pout,
                                                         int M, int Nc, int K, int nb, int ngrp, int nx) {
    __shared__ __align__(16) unsigned short As[128 * 64];  // 16 KB
    __shared__ __align__(16) unsigned short Bs[64 * 64];   // 8 KB
    const int tid = threadIdx.x;
    const int wave = tid >> 6;
    const int lane = tid & 63;

    // XCD swizzle: dispatch bid round-robins XCDs; give XCD (bid&7) the
    // contiguous logical chunk. logical decomposed m-major.
    const int nwg = gridDim.x;
    const int logical = (blockIdx.x & 7) * (nwg >> 3) + (blockIdx.x >> 3);
    const int span = nx * ngrp;
    const int mblk = logical / span;
    const int rem = logical - mblk * span;
    const int gz = rem / nx;
    const int nblk = rem - gz * nx;
    const int n0 = nblk * 64, m0 = mblk * 128;

    const int q = nb / ngrp, rmd = nb - q * ngrp;
    const int kb0 = gz * q + (gz < rmd ? gz : rmd);
    const int kbn = q + (gz < rmd ? 1 : 0);
    unsigned short* P = Pout + (size_t)gz * M * Nc;
    const int wr = wave >> 1, wc = wave & 1;
    const int frow = lane & 15, fq = lane >> 4;

    // staging: chunk ch -> LDS linear byte ch*16 (row=ch>>3, slot=ch&7);
    // global col pre-swizzled: slot_src = slot ^ (row&7)  (involution; read applies same XOR)
    int srA[4], scA[4];
#pragma unroll
    for (int i = 0; i < 4; ++i) {
        int ch = i * 256 + tid;
        srA[i] = ch >> 3;
        scA[i] = ((ch & 7) ^ (srA[i] & 7)) * 16;
    }
    int srB[2], scB[2];
#pragma unroll
    for (int i = 0; i < 2; ++i) {
        int ch = i * 256 + tid;
        srB[i] = ch >> 3;
        scB[i] = ((ch & 7) ^ (srB[i] & 7)) * 16;
    }
    const char* Ab = (const char*)A;
    const size_t K2 = (size_t)K * 2;
    const size_t branchBytes = (size_t)Nc * K2;
    char* lA = (char*)As + wave * 1024;
    char* lB = (char*)Bs + wave * 1024;

    float4v best[4][2];
#pragma unroll
    for (int mi = 0; mi < 4; ++mi)
#pragma unroll
        for (int ni = 0; ni < 2; ++ni) best[mi][ni] = (float4v)(-1e30f);

    for (int kb = kb0; kb < kb0 + kbn; ++kb) {
        const char* Bb = (const char*)WT + (size_t)kb * branchBytes;
        float4v acc[4][2];
#pragma unroll
        for (int ni = 0; ni < 2; ++ni) {
            float bval = bias[(size_t)kb * Nc + n0 + wc * 32 + ni * 16 + frow];
#pragma unroll
            for (int mi = 0; mi < 4; ++mi) acc[mi][ni] = (float4v)(bval);
        }
        for (int k0 = 0; k0 < K; k0 += 64) {
            const size_t kby = (size_t)k0 * 2;
#pragma unroll
            for (int i = 0; i < 4; ++i)
                gload_lds16(Ab + (size_t)(m0 + srA[i]) * K2 + kby + scA[i], lA + i * 4096);
#pragma unroll
            for (int i = 0; i < 2; ++i)
                gload_lds16(Bb + (size_t)(n0 + srB[i]) * K2 + kby + scB[i], lB + i * 4096);
            __syncthreads();
#pragma unroll
            for (int kk = 0; kk < 2; ++kk) {
                short8v av[4], bv[2];
                const int slot = kk * 4 + fq;
#pragma unroll
                for (int mi = 0; mi < 4; ++mi) {
                    int ra = wr * 64 + mi * 16 + frow;
                    av[mi] = *(const short8v*)((const char*)As + ra * 128 + ((slot ^ (ra & 7)) * 16));
                }
#pragma unroll
                for (int ni = 0; ni < 2; ++ni) {
                    int rb = wc * 32 + ni * 16 + frow;
                    bv[ni] = *(const short8v*)((const char*)Bs + rb * 128 + ((slot ^ (rb & 7)) * 16));
                }
#pragma unroll
                for (int mi = 0; mi < 4; ++mi)
#pragma unroll
                    for (int ni = 0; ni < 2; ++ni)
                        acc[mi][ni] = __builtin_amdgcn_mfma_f32_16x16x32_bf16(av[mi], bv[ni], acc[mi][ni], 0, 0, 0);
            }
            __syncthreads();
        }
#pragma unroll
        for (int ni = 0; ni < 2; ++ni)
#pragma unroll
            for (int mi = 0; mi < 4; ++mi)
#pragma unroll
                for (int i = 0; i < 4; ++i)
                    best[mi][ni][i] = fmaxf(best[mi][ni][i], gelu_fast(acc[mi][ni][i]));
    }

#pragma unroll
    for (int ni = 0; ni < 2; ++ni) {
        int col = n0 + wc * 32 + ni * 16 + frow;
#pragma unroll
        for (int mi = 0; mi < 4; ++mi) {
#pragma unroll
            for (int i = 0; i < 4; ++i) {
                int row = m0 + wr * 64 + mi * 16 + fq * 4 + i;
                P[(size_t)row * Nc + col] = f2bf(best[mi][ni][i]);
            }
        }
    }
}

// ---------------- combine: out[i] = max_s P[s][i] (bf16, 4/thread) ----------------
__global__ void combine_max(const unsigned short* __restrict__ P, unsigned short* __restrict__ out,
                            size_t tileElems, int S) {
    size_t i = ((size_t)blockIdx.x * blockDim.x + threadIdx.x) * 4;
    if (i >= tileElems) return;
    ushort4 best = *(const ushort4*)(P + i);
    for (int s = 1; s < S; ++s) {
        ushort4 c = *(const ushort4*)(P + (size_t)s * tileElems + i);
        if (bf2f(c.x) > bf2f(best.x)) best.x = c.x;
        if (bf2f(c.y) > bf2f(best.y)) best.y = c.y;
        if (bf2f(c.z) > bf2f(best.z)) best.z = c.z;
        if (bf2f(c.w) > bf2f(best.w)) best.w = c.w;
    }
    *(ushort4*)(out + i) = best;
}

// ---------------- LayerNorm over H=512: f32 in -> bf16 out ----------------
__global__ __launch_bounds__(256) void layernorm_bf16(const float* __restrict__ h,
                                                      unsigned short* __restrict__ o,
                                                      const float* __restrict__ g,
                                                      const float* __restrict__ b) {
    int row = blockIdx.x;
    const float* p = h + (size_t)row * 512;
    int tid = threadIdx.x;
    float v0 = p[tid], v1 = p[tid + 256];
    float s = v0 + v1, sq = v0 * v0 + v1 * v1;
#pragma unroll
    for (int off = 32; off >= 1; off >>= 1) {
        s += __shfl_xor(s, off);
        sq += __shfl_xor(sq, off);
    }
    __shared__ float ls[4], lq[4];
    int wid = tid >> 6, lane = tid & 63;
    if (lane == 0) { ls[wid] = s; lq[wid] = sq; }
    __syncthreads();
    float ts = ls[0] + ls[1] + ls[2] + ls[3];
    float tq = lq[0] + lq[1] + lq[2] + lq[3];
    float mean = ts / 512.f;
    float var = tq / 512.f - mean * mean;
    float inv = rsqrtf(var + 1e-5f);
    unsigned short* op = o + (size_t)row * 512;
    op[tid] = f2bf((v0 - mean) * inv * g[tid] + b[tid]);
    op[tid + 256] = f2bf((v1 - mean) * inv * g[tid + 256] + b[tid + 256]);
}

// ---------------- z = mu + eps * exp(0.5*logvar)  -> bf16 ----------------
__global__ void z_kernel(const float* __restrict__ mu, const float* __restrict__ lv,
                         const float* __restrict__ eps, unsigned short* __restrict__ z, int n4) {
    int i = blockIdx.x * blockDim.x + threadIdx.x;
    if (i >= n4) return;
    float4 m = ((const float4*)mu)[i];
    float4 l = ((const float4*)lv)[i];
    float4 e = ((const float4*)eps)[i];
    ushort4 o;
    o.x = f2bf(m.x + e.x * expf(0.5f * l.x));
    o.y = f2bf(m.y + e.y * expf(0.5f * l.y));
    o.z = f2bf(m.z + e.z * expf(0.5f * l.z));
    o.w = f2bf(m.w + e.w * expf(0.5f * l.w));
    ((ushort4*)z)[i] = o;
}

extern "C" void kernel_launch(void* const* d_in, const int* in_sizes, int n_in,
                              void* d_out, int out_size, void* d_ws, size_t ws_size,
                              hipStream_t stream) {
    const float* x        = (const float*)d_in[0];
    const int*   arows    = (const int*)d_in[1];
    const int*   acols    = (const int*)d_in[2];
    const float* avals    = (const float*)d_in[3];
    const float* basisenc = (const float*)d_in[4];
    const float* ln_g     = (const float*)d_in[5];
    const float* ln_b     = (const float*)d_in[6];
    const float* Wd_enc   = (const float*)d_in[7];
    const float* bd_enc   = (const float*)d_in[8];
    const float* W_mu     = (const float*)d_in[9];
    const float* b_mu     = (const float*)d_in[10];
    const float* W_lv     = (const float*)d_in[11];
    const float* b_lv     = (const float*)d_in[12];
    const float* Wd_dec   = (const float*)d_in[13];
    const float* bd_dec   = (const float*)d_in[14];
    const float* basisdec = (const float*)d_in[15];
    const float* epsin    = (const float*)d_in[16];

    const int N = 16384;
    const int E = in_sizes[1];

    float* ws = (float*)d_ws;
    const size_t A0 = 0;                               // f32 N*768: xa -> hF -> Penc(5xN*256 u16) -> Pdec(3xN*512 u16) -> b1
    const size_t B0 = A0 + (size_t)N * 768;            // u16 N*800: cenc -> [cdec | zb]
    const size_t C0 = B0 + (size_t)N * 400;            // f32 N*387: xbf -> a1 -> [hbf | encb] -> decb
    const size_t D0 = C0 + (size_t)N * 387;            // f32 N*197: a2 -> b2
    const size_t E0 = D0 + (size_t)N * 197;            // f32 N*102: a3 -> b3
    const size_t F0 = E0 + (size_t)N * 102;            // u16 weights
    const size_t G0 = F0 + 3100672;                    // CSR

    float* xa  = ws + A0;
    float* hF  = ws + A0;
    unsigned short* Penc = (unsigned short*)(ws + A0);  // 5 x N*256 u16
    unsigned short* Pdec = (unsigned short*)(ws + A0);  // 3 x N*512 u16 (exact fit)
    float* b1  = ws + A0;
    unsigned short* cenc = (unsigned short*)(ws + B0);
    unsigned short* cdec = (unsigned short*)(ws + B0);
    unsigned short* zb   = cdec + (size_t)N * 544;
    unsigned short* xbf  = (unsigned short*)(ws + C0);
    float* a1 = ws + C0;
    unsigned short* hbf  = (unsigned short*)(ws + C0);
    unsigned short* encb = hbf + (size_t)N * 512;
    unsigned short* decb = (unsigned short*)(ws + C0);
    float* a2 = ws + D0;
    float* b2 = ws + D0;
    float* a3 = ws + E0;
    float* b3 = ws + E0;
    unsigned short* wF = (unsigned short*)(ws + F0);
    unsigned short* BceT   = wF;                       // 512*800
    unsigned short* BcdT   = BceT + 512 * 800;         // 768*544
    unsigned short* WdencT = BcdT + 768 * 544;         // 20*256*512
    unsigned short* WddecT = WdencT + 20 * 256 * 512;  // 20*512*256
    unsigned short* WmuT   = WddecT + 20 * 512 * 256;  // 256*256
    unsigned short* WlvT   = WmuT + 256 * 256;
    int*   csr_cnt  = (int*)(ws + G0);
    int*   csr_offs = csr_cnt + N;
    int*   csr_cur  = csr_offs + N + 1;
    int*   csr_col  = csr_cur + N;
    float* csr_val  = (float*)(csr_col + E);

    float* out_recon = (float*)d_out;
    float* out_mu    = out_recon + (size_t)N * 768;
    float* out_lv    = out_mu + (size_t)N * 256;

    // --- packs + cast (independent) ---
    {
        Bounds be = {{0, 54, 108, 210, 407, 794}};
        pack_basis_T<<<(512 * 800 + 255) / 256, 256, 0, stream>>>(basisenc, BceT, be, 768, 512, 794, 800);
        Bounds bdd = {{0, 38, 76, 146, 279, 538}};
        pack_basis_T<<<(768 * 544 + 255) / 256, 256, 0, stream>>>(basisdec, BcdT, bdd, 512, 768, 538, 544);
        pack_wT<<<(20 * 256 * 512 + 255) / 256, 256, 0, stream>>>(Wd_enc, WdencT, 20, 512, 256, 512);
        pack_wT<<<(20 * 512 * 256 + 255) / 256, 256, 0, stream>>>(Wd_dec, WddecT, 20, 256, 512, 256);
        pack_wT<<<(256 * 256 + 255) / 256, 256, 0, stream>>>(W_mu, WmuT, 1, 256, 256, 256);
        pack_wT<<<(256 * 256 + 255) / 256, 256, 0, stream>>>(W_lv, WlvT, 1, 256, 256, 256);
        cast_bf16_kernel<<<(N * 768 / 4 + 255) / 256, 256, 0, stream>>>(x, xbf, N * 768 / 4);
    }

    // 1) SpMM via device-built CSR (bf16 gather)
    hipMemsetAsync(csr_cnt, 0, N * sizeof(int), stream);
    hipMemsetAsync(cenc, 0, (size_t)N * 800 * sizeof(unsigned short), stream);
    hist_kernel<<<(E + 255) / 256, 256, 0, stream>>>(arows, csr_cnt, E);
    scan_kernel<<<1, 1024, 0, stream>>>(csr_cnt, csr_offs, csr_cur, N, E);
    scatter_kernel<<<(E + 255) / 256, 256, 0, stream>>>(arows, acols, avals, csr_cur, csr_col, csr_val, E);
    spmm_csr<<<N / 4, 256, 0, stream>>>(xbf, csr_offs, csr_col, csr_val, xa);

    // 2) wavedec enc: 768->387->197->102->54 ; cenc cols [cA4(0)|cD4(54)|cD3(108)|cD2(210)|cD1(407)]
    dwt_kernel<false, false><<<N, 128, 768 * 4, stream>>>(xa, 768, 768, a1, 387, cenc + 407, 800, 387);
    dwt_kernel<false, false><<<N, 128, 387 * 4, stream>>>(a1, 387, 387, a2, 197, cenc + 210, 800, 197);
    dwt_kernel<false, false><<<N, 128, 197 * 4, stream>>>(a2, 197, 197, a3, 102, cenc + 108, 800, 102);
    dwt_kernel<false, true><<<N, 128, 102 * 4, stream>>>(a3, 102, 102, cenc + 0, 800, cenc + 54, 800, 54);

    // 3) h = cenc @ BceT^T  [16384,512], K=800
    gemm_mfma<0><<<dim3(512 / 128, N / 128), 256, 0, stream>>>(cenc, BceT, nullptr, hF, N, 512, 800, 800, 800, 512);

    // 4) layernorm -> bf16
    layernorm_bf16<<<N, 256, 0, stream>>>(hF, hbf, ln_g, ln_b);

    // 5) enc: 5 branch-groups of 4 (hF dead -> Penc), combine -> encb.  nwg = 4*128*5 = 2560 (%8==0)
    dendritic_part<<<4 * (N / 128) * 5, 256, 0, stream>>>(hbf, WdencT, bd_enc, Penc, N, 256, 512, 20, 5, 4);
    combine_max<<<(int)(((size_t)N * 256 / 4 + 255) / 256), 256, 0, stream>>>(Penc, encb, (size_t)N * 256, 5);

    // 6) mu / logvar (f32 out to d_out), K=256
    gemm_mfma<0><<<dim3(256 / 128, N / 128), 256, 0, stream>>>(encb, WmuT, b_mu, out_mu, N, 256, 256, 256, 256, 256);
    gemm_mfma<0><<<dim3(256 / 128, N / 128), 256, 0, stream>>>(encb, WlvT, b_lv, out_lv, N, 256, 256, 256, 256, 256);

    // 7) z -> bf16
    z_kernel<<<(N * 256 / 4 + 255) / 256, 256, 0, stream>>>(out_mu, out_lv, epsin, zb, N * 256 / 4);

    // 8) dec: 3 branch-groups of 7/7/6 (Penc dead -> Pdec), combine -> decb.  nwg = 8*128*3 = 3072 (%8==0)
    dendritic_part<<<8 * (N / 128) * 3, 256, 0, stream>>>(zb, WddecT, bd_dec, Pdec, N, 512, 256, 20, 3, 8);
    combine_max<<<(int)(((size_t)N * 512 / 4 + 255) / 256), 256, 0, stream>>>(Pdec, decb, (size_t)N * 512, 3);

    // 9) memset cdec pad, then wavedec dec: 512->259->133->70->38 ; cols [0|38|76|146|279]
    hipMemsetAsync(cdec, 0, (size_t)N * 544 * sizeof(unsigned short), stream);
    dwt_kernel<true, false><<<N, 128, 512 * 4, stream>>>(decb, 512, 512, b1, 259, cdec + 279, 544, 259);
    dwt_kernel<false, false><<<N, 128, 259 * 4, stream>>>(b1, 259, 259, b2, 133, cdec + 146, 544, 133);
    dwt_kernel<false, false><<<N, 128, 133 * 4, stream>>>(b2, 133, 133, b3, 70, cdec + 76, 544, 70);
    dwt_kernel<false, true><<<N, 128, 70 * 4, stream>>>(b3, 70, 70, cdec + 0, 544, cdec + 38, 544, 38);

    // 10) recon = cdec @ BcdT^T [16384,768], K=544
    gemm_mfma<0><<<dim3(768 / 128, N / 128), 256, 0, stream>>>(cdec, BcdT, nullptr, out_recon, N, 768, 544, 544, 544, 768);

    (void)ws_size; (void)out_size; (void)n_in;
}

// Round 10
// 688.896 us; speedup vs baseline: 1.3918x; 1.0321x over previous
//
#include <hip/hip_runtime.h>

typedef __attribute__((ext_vector_type(8))) short short8v;
typedef __attribute__((ext_vector_type(8))) unsigned short ushort8v;
typedef __attribute__((ext_vector_type(4))) float float4v;

__device__ __constant__ float c_LO[8] = {
    -0.010597401784997278f, 0.032883011666982945f, 0.030841381835986965f,
    -0.18703481171888114f, -0.02798376941698385f, 0.6308807679295904f,
    0.7148465705525415f, 0.23037781330885523f};
__device__ __constant__ float c_HI[8] = {
    -0.23037781330885523f, 0.7148465705525415f, -0.6308807679295904f,
    -0.02798376941698385f, 0.18703481171888114f, 0.030841381835986965f,
    -0.032883011666982945f, -0.010597401784997278f};

__device__ __forceinline__ unsigned short f2bf(float f) {
    unsigned u = __builtin_bit_cast(unsigned, f);
    unsigned r = u + 0x7fffu + ((u >> 16) & 1u);
    return (unsigned short)(r >> 16);
}
__device__ __forceinline__ float bf2f(unsigned short u) {
    return __builtin_bit_cast(float, (unsigned)u << 16);
}

// tanh-form GELU: one exp2 + rcp
__device__ __forceinline__ float gelu_fast(float x) {
    float x3 = x * x * x;
    float y = fmaf(0.044715f, x3, x) * 0.7978845608028654f;
    float t = fminf(fmaxf(y * 2.8853900817779268f, -30.f), 30.f);
    float e = exp2f(t);
    return x * e * __builtin_amdgcn_rcpf(e + 1.0f);
}

__device__ __forceinline__ void gload_lds16(const void* g, void* l) {
    __builtin_amdgcn_global_load_lds(g, l, 16, 0, 0);
}

// ---------------- x -> bf16 cast ----------------
__global__ void cast_bf16_kernel(const float* __restrict__ in, unsigned short* __restrict__ out, int n4) {
    int i = blockIdx.x * blockDim.x + threadIdx.x;
    if (i >= n4) return;
    float4 v = ((const float4*)in)[i];
    ushort4 o;
    o.x = f2bf(v.x); o.y = f2bf(v.y); o.z = f2bf(v.z); o.w = f2bf(v.w);
    ((ushort4*)out)[i] = o;
}

// ---------------- CSR build: histogram ----------------
__global__ void hist_kernel(const int* __restrict__ rows, int* __restrict__ cnt, int E) {
    int i = blockIdx.x * blockDim.x + threadIdx.x;
    if (i < E) atomicAdd(&cnt[rows[i]], 1);
}

// ---------------- CSR build: single-block scan ----------------
__global__ __launch_bounds__(1024) void scan_kernel(const int* __restrict__ cnt, int* __restrict__ offs,
                                                    int* __restrict__ cursor, int Nrows, int E) {
    __shared__ int part[1024];
    int tid = threadIdx.x;
    const int per = Nrows / 1024;  // 16
    int base = tid * per;
    int local[16];
    int s = 0;
    for (int i = 0; i < per; ++i) { local[i] = s; s += cnt[base + i]; }
    part[tid] = s;
    __syncthreads();
    for (int off = 1; off < 1024; off <<= 1) {
        int v = part[tid];
        int w = (tid >= off) ? part[tid - off] : 0;
        __syncthreads();
        part[tid] = v + w;
        __syncthreads();
    }
    int pre = (tid == 0) ? 0 : part[tid - 1];
    for (int i = 0; i < per; ++i) {
        int o = pre + local[i];
        offs[base + i] = o;
        cursor[base + i] = o;
    }
    if (tid == 0) offs[Nrows] = E;
}

// ---------------- CSR build: scatter ----------------
__global__ void scatter_kernel(const int* __restrict__ rows, const int* __restrict__ cols,
                               const float* __restrict__ vals, int* __restrict__ cursor,
                               int* __restrict__ ccol, float* __restrict__ cval, int E) {
    int i = blockIdx.x * blockDim.x + threadIdx.x;
    if (i >= E) return;
    int r = rows[i];
    int p = atomicAdd(&cursor[r], 1);
    ccol[p] = cols[i];
    cval[p] = vals[i];
}

// ---------------- SpMM CSR: one wave per row, bf16 gather ----------------
__global__ __launch_bounds__(256) void spmm_csr(const unsigned short* __restrict__ xb, const int* __restrict__ offs,
                                                const int* __restrict__ ccol, const float* __restrict__ cval,
                                                float* __restrict__ xa) {
    int r = blockIdx.x * 4 + (threadIdx.x >> 6);
    int lane = threadIdx.x & 63;
    int s = offs[r], e = offs[r + 1];
    float acc[12] = {};
    for (int j = s; j < e; ++j) {
        int c = ccol[j];
        float v = cval[j];
        const unsigned short* xr = xb + (size_t)c * 768;
#pragma unroll
        for (int seg = 0; seg < 3; ++seg) {
            ushort4 u = *(const ushort4*)(xr + seg * 256 + lane * 4);
            acc[seg * 4 + 0] = fmaf(v, bf2f(u.x), acc[seg * 4 + 0]);
            acc[seg * 4 + 1] = fmaf(v, bf2f(u.y), acc[seg * 4 + 1]);
            acc[seg * 4 + 2] = fmaf(v, bf2f(u.z), acc[seg * 4 + 2]);
            acc[seg * 4 + 3] = fmaf(v, bf2f(u.w), acc[seg * 4 + 3]);
        }
    }
    float* o = xa + (size_t)r * 768;
#pragma unroll
    for (int seg = 0; seg < 3; ++seg) {
        float4 w = make_float4(acc[seg * 4], acc[seg * 4 + 1], acc[seg * 4 + 2], acc[seg * 4 + 3]);
        *(float4*)(o + seg * 256 + lane * 4) = w;
    }
}

// ---------------- one DWT level (pywt symmetric) ----------------
template <bool IN_BF16, bool A_BF16>
__global__ void dwt_kernel(const void* __restrict__ in, int n, int in_stride,
                           void* __restrict__ outA, int a_stride,
                           unsigned short* __restrict__ outD, int d_stride, int m) {
    extern __shared__ float srow[];
    int row = blockIdx.x;
    if (IN_BF16) {
        const unsigned short* ip = (const unsigned short*)in + (size_t)row * in_stride;
        for (int i = threadIdx.x; i < n; i += blockDim.x) srow[i] = bf2f(ip[i]);
    } else {
        const float* ip = (const float*)in + (size_t)row * in_stride;
        for (int i = threadIdx.x; i < n; i += blockDim.x) srow[i] = ip[i];
    }
    __syncthreads();
    for (int j = threadIdx.x; j < m; j += blockDim.x) {
        float a = 0.f, d = 0.f;
#pragma unroll
        for (int i = 0; i < 8; ++i) {
            int p = 2 * j + 7 - i;
            int q = (p < 6) ? (5 - p) : ((p < n + 6) ? (p - 6) : (2 * n + 5 - p));
            float xv = srow[q];
            a = fmaf(c_LO[i], xv, a);
            d = fmaf(c_HI[i], xv, d);
        }
        if (A_BF16)
            ((unsigned short*)outA)[(size_t)row * a_stride + j] = f2bf(a);
        else
            ((float*)outA)[(size_t)row * a_stride + j] = a;
        outD[(size_t)row * d_stride + j] = f2bf(d);
    }
}

// ---------------- pack basis stack -> transposed bf16 [N][Kpad] ----------------
struct Bounds { int b[6]; };

__global__ void pack_basis_T(const float* __restrict__ basis, unsigned short* __restrict__ BT,
                             Bounds bd, int brows, int N, int K, int Kpad) {
    int idx = blockIdx.x * blockDim.x + threadIdx.x;
    if (idx >= N * Kpad) return;
    int n = idx / Kpad, k = idx - n * Kpad;
    float v = 0.f;
    if (k < K) {
        int s = 0;
#pragma unroll
        for (int t = 1; t < 5; ++t)
            if (k >= bd.b[t]) s = t;
        int lr = k - bd.b[s];
        v = basis[((size_t)s * brows + lr) * N + n];
    }
    BT[idx] = f2bf(v);
}

// ---------------- pack weights [NB][K][N] -> transposed bf16 [NB][N][Kpad] ----------------
__global__ void pack_wT(const float* __restrict__ W, unsigned short* __restrict__ WT,
                        int NB, int K, int N, int Kpad) {
    int idx = blockIdx.x * blockDim.x + threadIdx.x;
    int tot = NB * N * Kpad;
    if (idx >= tot) return;
    int b = idx / (N * Kpad);
    int r = idx - b * (N * Kpad);
    int n = r / Kpad, k = r - n * Kpad;
    float v = (k < K) ? W[((size_t)b * K + k) * N + n] : 0.f;
    WT[idx] = f2bf(v);
}

// ---------------- bf16 MFMA GEMM (proven) ----------------
template <int OUT_BF16>
__global__ __launch_bounds__(256) void gemm_mfma(const unsigned short* __restrict__ A,
                                                 const unsigned short* __restrict__ BT,
                                                 const float* __restrict__ bias,
                                                 void* __restrict__ Cv,
                                                 int M, int N, int K, int lda, int ldb, int ldc) {
    __shared__ __align__(16) unsigned short As[128 * 32];
    __shared__ __align__(16) unsigned short Bs[128 * 32];
    const int tid = threadIdx.x;
    const int wave = tid >> 6, lane = tid & 63;
    const int m0 = blockIdx.y * 128, n0 = blockIdx.x * 128;
    const int wr = wave >> 1, wc = wave & 1;
    const int frow = lane & 15, fq = lane >> 4;

    const int off0 = tid * 16;
    const int r0 = off0 >> 6, c0 = off0 & 63;
    const int r1 = (off0 + 4096) >> 6, c1 = (off0 + 4096) & 63;
    const char* Ab = (const char*)A;
    const char* Bb = (const char*)BT;
    size_t gA0 = (size_t)(m0 + r0) * lda * 2 + c0;
    size_t gA1 = (size_t)(m0 + r1) * lda * 2 + c1;
    size_t gB0 = (size_t)(n0 + r0) * ldb * 2 + c0;
    size_t gB1 = (size_t)(n0 + r1) * ldb * 2 + c1;
    char* lA0 = (char*)As + wave * 1024;
    char* lB0 = (char*)Bs + wave * 1024;

    const int aoff = (wr * 64 + frow) * 32 + fq * 8;
    const int boff = (wc * 64 + frow) * 32 + fq * 8;

    float4v acc[4][4] = {};
    for (int k0 = 0; k0 < K; k0 += 32) {
        size_t kb2 = (size_t)k0 * 2;
        gload_lds16(Ab + gA0 + kb2, lA0);
        gload_lds16(Ab + gA1 + kb2, lA0 + 4096);
        gload_lds16(Bb + gB0 + kb2, lB0);
        gload_lds16(Bb + gB1 + kb2, lB0 + 4096);
        __syncthreads();
        short8v av[4], bv[4];
#pragma unroll
        for (int i = 0; i < 4; ++i) av[i] = *(const short8v*)(As + aoff + i * 512);
#pragma unroll
        for (int i = 0; i < 4; ++i) bv[i] = *(const short8v*)(Bs + boff + i * 512);
#pragma unroll
        for (int mi = 0; mi < 4; ++mi)
#pragma unroll
            for (int ni = 0; ni < 4; ++ni)
                acc[mi][ni] = __builtin_amdgcn_mfma_f32_16x16x32_bf16(av[mi], bv[ni], acc[mi][ni], 0, 0, 0);
        __syncthreads();
    }
#pragma unroll
    for (int ni = 0; ni < 4; ++ni) {
        int col = n0 + wc * 64 + ni * 16 + frow;
        float bval = bias ? bias[col] : 0.f;
#pragma unroll
        for (int mi = 0; mi < 4; ++mi) {
#pragma unroll
            for (int i = 0; i < 4; ++i) {
                int row = m0 + wr * 64 + mi * 16 + fq * 4 + i;
                float v = acc[mi][ni][i] + bval;
                if (OUT_BF16)
                    ((unsigned short*)Cv)[(size_t)row * ldc + col] = f2bf(v);
                else
                    ((float*)Cv)[(size_t)row * ldc + col] = v;
            }
        }
    }
}

// ---- dendritic partial v6: v5 + unimodal GELU trick. ----
// max_k gelu(h_k) == max(gelu(min_k h_k), gelu(max_k h_k))  [gelu is a unimodal valley]
// -> track only running hmin/hmax per element (2 ops/branch), gelu twice in epilogue.
__global__ __launch_bounds__(256, 3) void dendritic_part(const unsigned short* __restrict__ A,
                                                         const unsigned short* __restrict__ WT,
                                                         const float* __restrict__ bias,
                                                         unsigned short* __restrict__ Pout,
                                                         int M, int Nc, int K, int nb, int ngrp, int nx) {
    __shared__ __align__(16) unsigned short As[128 * 64];  // 16 KB
    __shared__ __align__(16) unsigned short Bs[64 * 64];   // 8 KB
    const int tid = threadIdx.x;
    const int wave = tid >> 6;
    const int lane = tid & 63;

    // XCD swizzle: give XCD (bid&7) a contiguous logical chunk; logical is m-major.
    const int nwg = gridDim.x;
    const int logical = (blockIdx.x & 7) * (nwg >> 3) + (blockIdx.x >> 3);
    const int span = nx * ngrp;
    const int mblk = logical / span;
    const int rem = logical - mblk * span;
    const int gz = rem / nx;
    const int nblk = rem - gz * nx;
    const int n0 = nblk * 64, m0 = mblk * 128;

    const int q = nb / ngrp, rmd = nb - q * ngrp;
    const int kb0 = gz * q + (gz < rmd ? gz : rmd);
    const int kbn = q + (gz < rmd ? 1 : 0);
    unsigned short* P = Pout + (size_t)gz * M * Nc;
    const int wr = wave >> 1, wc = wave & 1;
    const int frow = lane & 15, fq = lane >> 4;

    int srA[4], scA[4];
#pragma unroll
    for (int i = 0; i < 4; ++i) {
        int ch = i * 256 + tid;
        srA[i] = ch >> 3;
        scA[i] = ((ch & 7) ^ (srA[i] & 7)) * 16;
    }
    int srB[2], scB[2];
#pragma unroll
    for (int i = 0; i < 2; ++i) {
        int ch = i * 256 + tid;
        srB[i] = ch >> 3;
        scB[i] = ((ch & 7) ^ (srB[i] & 7)) * 16;
    }
    const char* Ab = (const char*)A;
    const size_t K2 = (size_t)K * 2;
    const size_t branchBytes = (size_t)Nc * K2;
    char* lA = (char*)As + wave * 1024;
    char* lB = (char*)Bs + wave * 1024;

    float4v hmn[4][2], hmx[4][2];
#pragma unroll
    for (int mi = 0; mi < 4; ++mi)
#pragma unroll
        for (int ni = 0; ni < 2; ++ni) { hmn[mi][ni] = (float4v)(1e30f); hmx[mi][ni] = (float4v)(-1e30f); }

    for (int kb = kb0; kb < kb0 + kbn; ++kb) {
        const char* Bb = (const char*)WT + (size_t)kb * branchBytes;
        float4v acc[4][2];
#pragma unroll
        for (int ni = 0; ni < 2; ++ni) {
            float bval = bias[(size_t)kb * Nc + n0 + wc * 32 + ni * 16 + frow];
#pragma unroll
            for (int mi = 0; mi < 4; ++mi) acc[mi][ni] = (float4v)(bval);
        }
        for (int k0 = 0; k0 < K; k0 += 64) {
            const size_t kby = (size_t)k0 * 2;
#pragma unroll
            for (int i = 0; i < 4; ++i)
                gload_lds16(Ab + (size_t)(m0 + srA[i]) * K2 + kby + scA[i], lA + i * 4096);
#pragma unroll
            for (int i = 0; i < 2; ++i)
                gload_lds16(Bb + (size_t)(n0 + srB[i]) * K2 + kby + scB[i], lB + i * 4096);
            __syncthreads();
#pragma unroll
            for (int kk = 0; kk < 2; ++kk) {
                short8v av[4], bv[2];
                const int slot = kk * 4 + fq;
#pragma unroll
                for (int mi = 0; mi < 4; ++mi) {
                    int ra = wr * 64 + mi * 16 + frow;
                    av[mi] = *(const short8v*)((const char*)As + ra * 128 + ((slot ^ (ra & 7)) * 16));
                }
#pragma unroll
                for (int ni = 0; ni < 2; ++ni) {
                    int rb = wc * 32 + ni * 16 + frow;
                    bv[ni] = *(const short8v*)((const char*)Bs + rb * 128 + ((slot ^ (rb & 7)) * 16));
                }
#pragma unroll
                for (int mi = 0; mi < 4; ++mi)
#pragma unroll
                    for (int ni = 0; ni < 2; ++ni)
                        acc[mi][ni] = __builtin_amdgcn_mfma_f32_16x16x32_bf16(av[mi], bv[ni], acc[mi][ni], 0, 0, 0);
            }
            __syncthreads();
        }
#pragma unroll
        for (int ni = 0; ni < 2; ++ni)
#pragma unroll
            for (int mi = 0; mi < 4; ++mi)
#pragma unroll
                for (int i = 0; i < 4; ++i) {
                    hmn[mi][ni][i] = fminf(hmn[mi][ni][i], acc[mi][ni][i]);
                    hmx[mi][ni][i] = fmaxf(hmx[mi][ni][i], acc[mi][ni][i]);
                }
    }

#pragma unroll
    for (int ni = 0; ni < 2; ++ni) {
        int col = n0 + wc * 32 + ni * 16 + frow;
#pragma unroll
        for (int mi = 0; mi < 4; ++mi) {
#pragma unroll
            for (int i = 0; i < 4; ++i) {
                int row = m0 + wr * 64 + mi * 16 + fq * 4 + i;
                float g = fmaxf(gelu_fast(hmn[mi][ni][i]), gelu_fast(hmx[mi][ni][i]));
                P[(size_t)row * Nc + col] = f2bf(g);
            }
        }
    }
}

// ---------------- combine: out[i] = max_s P[s][i] (bf16, 4/thread) ----------------
__global__ void combine_max(const unsigned short* __restrict__ P, unsigned short* __restrict__ out,
                            size_t tileElems, int S) {
    size_t i = ((size_t)blockIdx.x * blockDim.x + threadIdx.x) * 4;
    if (i >= tileElems) return;
    ushort4 best = *(const ushort4*)(P + i);
    for (int s = 1; s < S; ++s) {
        ushort4 c = *(const ushort4*)(P + (size_t)s * tileElems + i);
        if (bf2f(c.x) > bf2f(best.x)) best.x = c.x;
        if (bf2f(c.y) > bf2f(best.y)) best.y = c.y;
        if (bf2f(c.z) > bf2f(best.z)) best.z = c.z;
        if (bf2f(c.w) > bf2f(best.w)) best.w = c.w;
    }
    *(ushort4*)(out + i) = best;
}

// ---------------- LayerNorm over H=512: f32 in -> bf16 out ----------------
__global__ __launch_bounds__(256) void layernorm_bf16(const float* __restrict__ h,
                                                      unsigned short* __restrict__ o,
                                                      const float* __restrict__ g,
                                                      const float* __restrict__ b) {
    int row = blockIdx.x;
    const float* p = h + (size_t)row * 512;
    int tid = threadIdx.x;
    float v0 = p[tid], v1 = p[tid + 256];
    float s = v0 + v1, sq = v0 * v0 + v1 * v1;
#pragma unroll
    for (int off = 32; off >= 1; off >>= 1) {
        s += __shfl_xor(s, off);
        sq += __shfl_xor(sq, off);
    }
    __shared__ float ls[4], lq[4];
    int wid = tid >> 6, lane = tid & 63;
    if (lane == 0) { ls[wid] = s; lq[wid] = sq; }
    __syncthreads();
    float ts = ls[0] + ls[1] + ls[2] + ls[3];
    float tq = lq[0] + lq[1] + lq[2] + lq[3];
    float mean = ts / 512.f;
    float var = tq / 512.f - mean * mean;
    float inv = rsqrtf(var + 1e-5f);
    unsigned short* op = o + (size_t)row * 512;
    op[tid] = f2bf((v0 - mean) * inv * g[tid] + b[tid]);
    op[tid + 256] = f2bf((v1 - mean) * inv * g[tid + 256] + b[tid + 256]);
}

// ---------------- z = mu + eps * exp(0.5*logvar)  -> bf16 ----------------
__global__ void z_kernel(const float* __restrict__ mu, const float* __restrict__ lv,
                         const float* __restrict__ eps, unsigned short* __restrict__ z, int n4) {
    int i = blockIdx.x * blockDim.x + threadIdx.x;
    if (i >= n4) return;
    float4 m = ((const float4*)mu)[i];
    float4 l = ((const float4*)lv)[i];
    float4 e = ((const float4*)eps)[i];
    ushort4 o;
    o.x = f2bf(m.x + e.x * expf(0.5f * l.x));
    o.y = f2bf(m.y + e.y * expf(0.5f * l.y));
    o.z = f2bf(m.z + e.z * expf(0.5f * l.z));
    o.w = f2bf(m.w + e.w * expf(0.5f * l.w));
    ((ushort4*)z)[i] = o;
}

extern "C" void kernel_launch(void* const* d_in, const int* in_sizes, int n_in,
                              void* d_out, int out_size, void* d_ws, size_t ws_size,
                              hipStream_t stream) {
    const float* x        = (const float*)d_in[0];
    const int*   arows    = (const int*)d_in[1];
    const int*   acols    = (const int*)d_in[2];
    const float* avals    = (const float*)d_in[3];
    const float* basisenc = (const float*)d_in[4];
    const float* ln_g     = (const float*)d_in[5];
    const float* ln_b     = (const float*)d_in[6];
    const float* Wd_enc   = (const float*)d_in[7];
    const float* bd_enc   = (const float*)d_in[8];
    const float* W_mu     = (const float*)d_in[9];
    const float* b_mu     = (const float*)d_in[10];
    const float* W_lv     = (const float*)d_in[11];
    const float* b_lv     = (const float*)d_in[12];
    const float* Wd_dec   = (const float*)d_in[13];
    const float* bd_dec   = (const float*)d_in[14];
    const float* basisdec = (const float*)d_in[15];
    const float* epsin    = (const float*)d_in[16];

    const int N = 16384;
    const int E = in_sizes[1];

    float* ws = (float*)d_ws;
    const size_t A0 = 0;                               // f32 N*768: xa -> hF -> Penc(5xN*256 u16) -> Pdec(3xN*512 u16) -> b1
    const size_t B0 = A0 + (size_t)N * 768;            // u16 N*800: cenc -> [cdec | zb]
    const size_t C0 = B0 + (size_t)N * 400;            // f32 N*387: xbf -> a1 -> [hbf | encb] -> decb
    const size_t D0 = C0 + (size_t)N * 387;            // f32 N*197: a2 -> b2
    const size_t E0 = D0 + (size_t)N * 197;            // f32 N*102: a3 -> b3
    const size_t F0 = E0 + (size_t)N * 102;            // u16 weights
    const size_t G0 = F0 + 3100672;                    // CSR

    float* xa  = ws + A0;
    float* hF  = ws + A0;
    unsigned short* Penc = (unsigned short*)(ws + A0);  // 5 x N*256 u16
    unsigned short* Pdec = (unsigned short*)(ws + A0);  // 3 x N*512 u16 (exact fit)
    float* b1  = ws + A0;
    unsigned short* cenc = (unsigned short*)(ws + B0);
    unsigned short* cdec = (unsigned short*)(ws + B0);
    unsigned short* zb   = cdec + (size_t)N * 544;
    unsigned short* xbf  = (unsigned short*)(ws + C0);
    float* a1 = ws + C0;
    unsigned short* hbf  = (unsigned short*)(ws + C0);
    unsigned short* encb = hbf + (size_t)N * 512;
    unsigned short* decb = (unsigned short*)(ws + C0);
    float* a2 = ws + D0;
    float* b2 = ws + D0;
    float* a3 = ws + E0;
    float* b3 = ws + E0;
    unsigned short* wF = (unsigned short*)(ws + F0);
    unsigned short* BceT   = wF;                       // 512*800
    unsigned short* BcdT   = BceT + 512 * 800;         // 768*544
    unsigned short* WdencT = BcdT + 768 * 544;         // 20*256*512
    unsigned short* WddecT = WdencT + 20 * 256 * 512;  // 20*512*256
    unsigned short* WmuT   = WddecT + 20 * 512 * 256;  // 256*256
    unsigned short* WlvT   = WmuT + 256 * 256;
    int*   csr_cnt  = (int*)(ws + G0);
    int*   csr_offs = csr_cnt + N;
    int*   csr_cur  = csr_offs + N + 1;
    int*   csr_col  = csr_cur + N;
    float* csr_val  = (float*)(csr_col + E);

    float* out_recon = (float*)d_out;
    float* out_mu    = out_recon + (size_t)N * 768;
    float* out_lv    = out_mu + (size_t)N * 256;

    // --- packs + cast (independent) ---
    {
        Bounds be = {{0, 54, 108, 210, 407, 794}};
        pack_basis_T<<<(512 * 800 + 255) / 256, 256, 0, stream>>>(basisenc, BceT, be, 768, 512, 794, 800);
        Bounds bdd = {{0, 38, 76, 146, 279, 538}};
        pack_basis_T<<<(768 * 544 + 255) / 256, 256, 0, stream>>>(basisdec, BcdT, bdd, 512, 768, 538, 544);
        pack_wT<<<(20 * 256 * 512 + 255) / 256, 256, 0, stream>>>(Wd_enc, WdencT, 20, 512, 256, 512);
        pack_wT<<<(20 * 512 * 256 + 255) / 256, 256, 0, stream>>>(Wd_dec, WddecT, 20, 256, 512, 256);
        pack_wT<<<(256 * 256 + 255) / 256, 256, 0, stream>>>(W_mu, WmuT, 1, 256, 256, 256);
        pack_wT<<<(256 * 256 + 255) / 256, 256, 0, stream>>>(W_lv, WlvT, 1, 256, 256, 256);
        cast_bf16_kernel<<<(N * 768 / 4 + 255) / 256, 256, 0, stream>>>(x, xbf, N * 768 / 4);
    }

    // 1) SpMM via device-built CSR (bf16 gather)
    hipMemsetAsync(csr_cnt, 0, N * sizeof(int), stream);
    hipMemsetAsync(cenc, 0, (size_t)N * 800 * sizeof(unsigned short), stream);
    hist_kernel<<<(E + 255) / 256, 256, 0, stream>>>(arows, csr_cnt, E);
    scan_kernel<<<1, 1024, 0, stream>>>(csr_cnt, csr_offs, csr_cur, N, E);
    scatter_kernel<<<(E + 255) / 256, 256, 0, stream>>>(arows, acols, avals, csr_cur, csr_col, csr_val, E);
    spmm_csr<<<N / 4, 256, 0, stream>>>(xbf, csr_offs, csr_col, csr_val, xa);

    // 2) wavedec enc: 768->387->197->102->54 ; cenc cols [cA4(0)|cD4(54)|cD3(108)|cD2(210)|cD1(407)]
    dwt_kernel<false, false><<<N, 128, 768 * 4, stream>>>(xa, 768, 768, a1, 387, cenc + 407, 800, 387);
    dwt_kernel<false, false><<<N, 128, 387 * 4, stream>>>(a1, 387, 387, a2, 197, cenc + 210, 800, 197);
    dwt_kernel<false, false><<<N, 128, 197 * 4, stream>>>(a2, 197, 197, a3, 102, cenc + 108, 800, 102);
    dwt_kernel<false, true><<<N, 128, 102 * 4, stream>>>(a3, 102, 102, cenc + 0, 800, cenc + 54, 800, 54);

    // 3) h = cenc @ BceT^T  [16384,512], K=800
    gemm_mfma<0><<<dim3(512 / 128, N / 128), 256, 0, stream>>>(cenc, BceT, nullptr, hF, N, 512, 800, 800, 800, 512);

    // 4) layernorm -> bf16
    layernorm_bf16<<<N, 256, 0, stream>>>(hF, hbf, ln_g, ln_b);

    // 5) enc: 5 branch-groups of 4 (hF dead -> Penc), combine -> encb.  nwg = 4*128*5 = 2560 (%8==0)
    dendritic_part<<<4 * (N / 128) * 5, 256, 0, stream>>>(hbf, WdencT, bd_enc, Penc, N, 256, 512, 20, 5, 4);
    combine_max<<<(int)(((size_t)N * 256 / 4 + 255) / 256), 256, 0, stream>>>(Penc, encb, (size_t)N * 256, 5);

    // 6) mu / logvar (f32 out to d_out), K=256
    gemm_mfma<0><<<dim3(256 / 128, N / 128), 256, 0, stream>>>(encb, WmuT, b_mu, out_mu, N, 256, 256, 256, 256, 256);
    gemm_mfma<0><<<dim3(256 / 128, N / 128), 256, 0, stream>>>(encb, WlvT, b_lv, out_lv, N, 256, 256, 256, 256, 256);

    // 7) z -> bf16
    z_kernel<<<(N * 256 / 4 + 255) / 256, 256, 0, stream>>>(out_mu, out_lv, epsin, zb, N * 256 / 4);

    // 8) dec: 3 branch-groups of 7/7/6 (Penc dead -> Pdec), combine -> decb.  nwg = 8*128*3 = 3072 (%8==0)
    dendritic_part<<<8 * (N / 128) * 3, 256, 0, stream>>>(zb, WddecT, bd_dec, Pdec, N, 512, 256, 20, 3, 8);
    combine_max<<<(int)(((size_t)N * 512 / 4 + 255) / 256), 256, 0, stream>>>(Pdec, decb, (size_t)N * 512, 3);

    // 9) memset cdec pad, then wavedec dec: 512->259->133->70->38 ; cols [0|38|76|146|279]
    hipMemsetAsync(cdec, 0, (size_t)N * 544 * sizeof(unsigned short), stream);
    dwt_kernel<true, false><<<N, 128, 512 * 4, stream>>>(decb, 512, 512, b1, 259, cdec + 279, 544, 259);
    dwt_kernel<false, false><<<N, 128, 259 * 4, stream>>>(b1, 259, 259, b2, 133, cdec + 146, 544, 133);
    dwt_kernel<false, false><<<N, 128, 133 * 4, stream>>>(b2, 133, 133, b3, 70, cdec + 76, 544, 70);
    dwt_kernel<false, true><<<N, 128, 70 * 4, stream>>>(b3, 70, 70, cdec + 0, 544, cdec + 38, 544, 38);

    // 10) recon = cdec @ BcdT^T [16384,768], K=544
    gemm_mfma<0><<<dim3(768 / 128, N / 128), 256, 0, stream>>>(cdec, BcdT, nullptr, out_recon, N, 768, 544, 544, 544, 768);

    (void)ws_size; (void)out_size; (void)n_in;
}

// Round 11
// 620.081 us; speedup vs baseline: 1.5462x; 1.1110x over previous
//
#include <hip/hip_runtime.h>

typedef __attribute__((ext_vector_type(8))) short short8v;
typedef __attribute__((ext_vector_type(8))) unsigned short ushort8v;
typedef __attribute__((ext_vector_type(4))) float float4v;

__device__ __constant__ float c_LO[8] = {
    -0.010597401784997278f, 0.032883011666982945f, 0.030841381835986965f,
    -0.18703481171888114f, -0.02798376941698385f, 0.6308807679295904f,
    0.7148465705525415f, 0.23037781330885523f};
__device__ __constant__ float c_HI[8] = {
    -0.23037781330885523f, 0.7148465705525415f, -0.6308807679295904f,
    -0.02798376941698385f, 0.18703481171888114f, 0.030841381835986965f,
    -0.032883011666982945f, -0.010597401784997278f};

__device__ __forceinline__ unsigned short f2bf(float f) {
    unsigned u = __builtin_bit_cast(unsigned, f);
    unsigned r = u + 0x7fffu + ((u >> 16) & 1u);
    return (unsigned short)(r >> 16);
}
__device__ __forceinline__ float bf2f(unsigned short u) {
    return __builtin_bit_cast(float, (unsigned)u << 16);
}

// tanh-form GELU: one exp2 + rcp
__device__ __forceinline__ float gelu_fast(float x) {
    float x3 = x * x * x;
    float y = fmaf(0.044715f, x3, x) * 0.7978845608028654f;
    float t = fminf(fmaxf(y * 2.8853900817779268f, -30.f), 30.f);
    float e = exp2f(t);
    return x * e * __builtin_amdgcn_rcpf(e + 1.0f);
}

__device__ __forceinline__ void gload_lds16(const void* g, void* l) {
    __builtin_amdgcn_global_load_lds(g, l, 16, 0, 0);
}

// ---------------- x -> bf16 cast ----------------
__global__ void cast_bf16_kernel(const float* __restrict__ in, unsigned short* __restrict__ out, int n4) {
    int i = blockIdx.x * blockDim.x + threadIdx.x;
    if (i >= n4) return;
    float4 v = ((const float4*)in)[i];
    ushort4 o;
    o.x = f2bf(v.x); o.y = f2bf(v.y); o.z = f2bf(v.z); o.w = f2bf(v.w);
    ((ushort4*)out)[i] = o;
}

// ---------------- CSR build: histogram ----------------
__global__ void hist_kernel(const int* __restrict__ rows, int* __restrict__ cnt, int E) {
    int i = blockIdx.x * blockDim.x + threadIdx.x;
    if (i < E) atomicAdd(&cnt[rows[i]], 1);
}

// ---------------- CSR build: single-block scan ----------------
__global__ __launch_bounds__(1024) void scan_kernel(const int* __restrict__ cnt, int* __restrict__ offs,
                                                    int* __restrict__ cursor, int Nrows, int E) {
    __shared__ int part[1024];
    int tid = threadIdx.x;
    const int per = Nrows / 1024;  // 16
    int base = tid * per;
    int local[16];
    int s = 0;
    for (int i = 0; i < per; ++i) { local[i] = s; s += cnt[base + i]; }
    part[tid] = s;
    __syncthreads();
    for (int off = 1; off < 1024; off <<= 1) {
        int v = part[tid];
        int w = (tid >= off) ? part[tid - off] : 0;
        __syncthreads();
        part[tid] = v + w;
        __syncthreads();
    }
    int pre = (tid == 0) ? 0 : part[tid - 1];
    for (int i = 0; i < per; ++i) {
        int o = pre + local[i];
        offs[base + i] = o;
        cursor[base + i] = o;
    }
    if (tid == 0) offs[Nrows] = E;
}

// ---------------- CSR build: scatter ----------------
__global__ void scatter_kernel(const int* __restrict__ rows, const int* __restrict__ cols,
                               const float* __restrict__ vals, int* __restrict__ cursor,
                               int* __restrict__ ccol, float* __restrict__ cval, int E) {
    int i = blockIdx.x * blockDim.x + threadIdx.x;
    if (i >= E) return;
    int r = rows[i];
    int p = atomicAdd(&cursor[r], 1);
    ccol[p] = cols[i];
    cval[p] = vals[i];
}

// ---------------- SpMM CSR: one wave per row, bf16 gather ----------------
__global__ __launch_bounds__(256) void spmm_csr(const unsigned short* __restrict__ xb, const int* __restrict__ offs,
                                                const int* __restrict__ ccol, const float* __restrict__ cval,
                                                float* __restrict__ xa) {
    int r = blockIdx.x * 4 + (threadIdx.x >> 6);
    int lane = threadIdx.x & 63;
    int s = offs[r], e = offs[r + 1];
    float acc[12] = {};
    for (int j = s; j < e; ++j) {
        int c = ccol[j];
        float v = cval[j];
        const unsigned short* xr = xb + (size_t)c * 768;
#pragma unroll
        for (int seg = 0; seg < 3; ++seg) {
            ushort4 u = *(const ushort4*)(xr + seg * 256 + lane * 4);
            acc[seg * 4 + 0] = fmaf(v, bf2f(u.x), acc[seg * 4 + 0]);
            acc[seg * 4 + 1] = fmaf(v, bf2f(u.y), acc[seg * 4 + 1]);
            acc[seg * 4 + 2] = fmaf(v, bf2f(u.z), acc[seg * 4 + 2]);
            acc[seg * 4 + 3] = fmaf(v, bf2f(u.w), acc[seg * 4 + 3]);
        }
    }
    float* o = xa + (size_t)r * 768;
#pragma unroll
    for (int seg = 0; seg < 3; ++seg) {
        float4 w = make_float4(acc[seg * 4], acc[seg * 4 + 1], acc[seg * 4 + 2], acc[seg * 4 + 3]);
        *(float4*)(o + seg * 256 + lane * 4) = w;
    }
}

// ---------------- one DWT level (pywt symmetric) ----------------
template <bool IN_BF16, bool A_BF16>
__global__ void dwt_kernel(const void* __restrict__ in, int n, int in_stride,
                           void* __restrict__ outA, int a_stride,
                           unsigned short* __restrict__ outD, int d_stride, int m) {
    extern __shared__ float srow[];
    int row = blockIdx.x;
    if (IN_BF16) {
        const unsigned short* ip = (const unsigned short*)in + (size_t)row * in_stride;
        for (int i = threadIdx.x; i < n; i += blockDim.x) srow[i] = bf2f(ip[i]);
    } else {
        const float* ip = (const float*)in + (size_t)row * in_stride;
        for (int i = threadIdx.x; i < n; i += blockDim.x) srow[i] = ip[i];
    }
    __syncthreads();
    for (int j = threadIdx.x; j < m; j += blockDim.x) {
        float a = 0.f, d = 0.f;
#pragma unroll
        for (int i = 0; i < 8; ++i) {
            int p = 2 * j + 7 - i;
            int q = (p < 6) ? (5 - p) : ((p < n + 6) ? (p - 6) : (2 * n + 5 - p));
            float xv = srow[q];
            a = fmaf(c_LO[i], xv, a);
            d = fmaf(c_HI[i], xv, d);
        }
        if (A_BF16)
            ((unsigned short*)outA)[(size_t)row * a_stride + j] = f2bf(a);
        else
            ((float*)outA)[(size_t)row * a_stride + j] = a;
        outD[(size_t)row * d_stride + j] = f2bf(d);
    }
}

// ---------------- pack basis stack -> transposed bf16 [N][Kpad] ----------------
struct Bounds { int b[6]; };

__global__ void pack_basis_T(const float* __restrict__ basis, unsigned short* __restrict__ BT,
                             Bounds bd, int brows, int N, int K, int Kpad) {
    int idx = blockIdx.x * blockDim.x + threadIdx.x;
    if (idx >= N * Kpad) return;
    int n = idx / Kpad, k = idx - n * Kpad;
    float v = 0.f;
    if (k < K) {
        int s = 0;
#pragma unroll
        for (int t = 1; t < 5; ++t)
            if (k >= bd.b[t]) s = t;
        int lr = k - bd.b[s];
        v = basis[((size_t)s * brows + lr) * N + n];
    }
    BT[idx] = f2bf(v);
}

// ---------------- pack weights [NB][K][N] -> transposed bf16 [NB][N][Kpad] ----------------
__global__ void pack_wT(const float* __restrict__ W, unsigned short* __restrict__ WT,
                        int NB, int K, int N, int Kpad) {
    int idx = blockIdx.x * blockDim.x + threadIdx.x;
    int tot = NB * N * Kpad;
    if (idx >= tot) return;
    int b = idx / (N * Kpad);
    int r = idx - b * (N * Kpad);
    int n = r / Kpad, k = r - n * Kpad;
    float v = (k < K) ? W[((size_t)b * K + k) * N + n] : 0.f;
    WT[idx] = f2bf(v);
}

// ---------------- bf16 MFMA GEMM (proven) ----------------
template <int OUT_BF16>
__global__ __launch_bounds__(256) void gemm_mfma(const unsigned short* __restrict__ A,
                                                 const unsigned short* __restrict__ BT,
                                                 const float* __restrict__ bias,
                                                 void* __restrict__ Cv,
                                                 int M, int N, int K, int lda, int ldb, int ldc) {
    __shared__ __align__(16) unsigned short As[128 * 32];
    __shared__ __align__(16) unsigned short Bs[128 * 32];
    const int tid = threadIdx.x;
    const int wave = tid >> 6, lane = tid & 63;
    const int m0 = blockIdx.y * 128, n0 = blockIdx.x * 128;
    const int wr = wave >> 1, wc = wave & 1;
    const int frow = lane & 15, fq = lane >> 4;

    const int off0 = tid * 16;
    const int r0 = off0 >> 6, c0 = off0 & 63;
    const int r1 = (off0 + 4096) >> 6, c1 = (off0 + 4096) & 63;
    const char* Ab = (const char*)A;
    const char* Bb = (const char*)BT;
    size_t gA0 = (size_t)(m0 + r0) * lda * 2 + c0;
    size_t gA1 = (size_t)(m0 + r1) * lda * 2 + c1;
    size_t gB0 = (size_t)(n0 + r0) * ldb * 2 + c0;
    size_t gB1 = (size_t)(n0 + r1) * ldb * 2 + c1;
    char* lA0 = (char*)As + wave * 1024;
    char* lB0 = (char*)Bs + wave * 1024;

    const int aoff = (wr * 64 + frow) * 32 + fq * 8;
    const int boff = (wc * 64 + frow) * 32 + fq * 8;

    float4v acc[4][4] = {};
    for (int k0 = 0; k0 < K; k0 += 32) {
        size_t kb2 = (size_t)k0 * 2;
        gload_lds16(Ab + gA0 + kb2, lA0);
        gload_lds16(Ab + gA1 + kb2, lA0 + 4096);
        gload_lds16(Bb + gB0 + kb2, lB0);
        gload_lds16(Bb + gB1 + kb2, lB0 + 4096);
        __syncthreads();
        short8v av[4], bv[4];
#pragma unroll
        for (int i = 0; i < 4; ++i) av[i] = *(const short8v*)(As + aoff + i * 512);
#pragma unroll
        for (int i = 0; i < 4; ++i) bv[i] = *(const short8v*)(Bs + boff + i * 512);
#pragma unroll
        for (int mi = 0; mi < 4; ++mi)
#pragma unroll
            for (int ni = 0; ni < 4; ++ni)
                acc[mi][ni] = __builtin_amdgcn_mfma_f32_16x16x32_bf16(av[mi], bv[ni], acc[mi][ni], 0, 0, 0);
        __syncthreads();
    }
#pragma unroll
    for (int ni = 0; ni < 4; ++ni) {
        int col = n0 + wc * 64 + ni * 16 + frow;
        float bval = bias ? bias[col] : 0.f;
#pragma unroll
        for (int mi = 0; mi < 4; ++mi) {
#pragma unroll
            for (int i = 0; i < 4; ++i) {
                int row = m0 + wr * 64 + mi * 16 + fq * 4 + i;
                float v = acc[mi][ni][i] + bval;
                if (OUT_BF16)
                    ((unsigned short*)Cv)[(size_t)row * ldc + col] = f2bf(v);
                else
                    ((float*)Cv)[(size_t)row * ldc + col] = v;
            }
        }
    }
}

// ---- dendritic partial v7: dual-branch per pass (shared A-fragments). ----
// Per kk: read av[4] once + bv0[2] + bv1[2] -> 16 MFMA. LDS reads/MFMA 0.75 -> 0.5.
// Unimodal GELU: track hmin/hmax only; gelu twice in epilogue.
__global__ __launch_bounds__(256, 2) void dendritic_part(const unsigned short* __restrict__ A,
                                                         const unsigned short* __restrict__ WT,
                                                         const float* __restrict__ bias,
                                                         unsigned short* __restrict__ Pout,
                                                         int M, int Nc, int K, int nb, int ngrp, int nx) {
    __shared__ __align__(16) unsigned short As[128 * 64];     // 16 KB
    __shared__ __align__(16) unsigned short Bs[2][64 * 64];   // 2 x 8 KB
    const int tid = threadIdx.x;
    const int wave = tid >> 6;
    const int lane = tid & 63;

    // XCD swizzle: give XCD (bid&7) a contiguous logical chunk; logical is m-major.
    const int nwg = gridDim.x;
    const int logical = (blockIdx.x & 7) * (nwg >> 3) + (blockIdx.x >> 3);
    const int span = nx * ngrp;
    const int mblk = logical / span;
    const int rem = logical - mblk * span;
    const int gz = rem / nx;
    const int nblk = rem - gz * nx;
    const int n0 = nblk * 64, m0 = mblk * 128;

    const int q = nb / ngrp, rmd = nb - q * ngrp;
    const int kb0 = gz * q + (gz < rmd ? gz : rmd);
    const int kbn = q + (gz < rmd ? 1 : 0);
    unsigned short* P = Pout + (size_t)gz * M * Nc;
    const int wr = wave >> 1, wc = wave & 1;
    const int frow = lane & 15, fq = lane >> 4;

    // staging: chunk ch -> LDS linear byte ch*16 (row=ch>>3, slot=ch&7);
    // global source col pre-swizzled (involution; read applies same XOR)
    int srA[4], scA[4];
#pragma unroll
    for (int i = 0; i < 4; ++i) {
        int ch = i * 256 + tid;
        srA[i] = ch >> 3;
        scA[i] = ((ch & 7) ^ (srA[i] & 7)) * 16;
    }
    int srB[2], scB[2];
#pragma unroll
    for (int i = 0; i < 2; ++i) {
        int ch = i * 256 + tid;
        srB[i] = ch >> 3;
        scB[i] = ((ch & 7) ^ (srB[i] & 7)) * 16;
    }
    const char* Ab = (const char*)A;
    const size_t K2 = (size_t)K * 2;
    const size_t branchBytes = (size_t)Nc * K2;
    char* lA  = (char*)As + wave * 1024;
    char* lB0 = (char*)&Bs[0][0] + wave * 1024;
    char* lB1 = (char*)&Bs[1][0] + wave * 1024;

    float4v hmn[4][2], hmx[4][2];
#pragma unroll
    for (int mi = 0; mi < 4; ++mi)
#pragma unroll
        for (int ni = 0; ni < 2; ++ni) { hmn[mi][ni] = (float4v)(1e30f); hmx[mi][ni] = (float4v)(-1e30f); }

    const int npair = (kbn + 1) >> 1;
    for (int p = 0; p < npair; ++p) {
        const int b0 = kb0 + 2 * p;
        const int b1 = (2 * p + 1 < kbn) ? (b0 + 1) : b0;  // clamp (idempotent under min/max)
        const char* Bb0 = (const char*)WT + (size_t)b0 * branchBytes;
        const char* Bb1 = (const char*)WT + (size_t)b1 * branchBytes;
        float4v ac0[4][2], ac1[4][2];
#pragma unroll
        for (int ni = 0; ni < 2; ++ni) {
            int col = n0 + wc * 32 + ni * 16 + frow;
            float bv0 = bias[(size_t)b0 * Nc + col];
            float bv1 = bias[(size_t)b1 * Nc + col];
#pragma unroll
            for (int mi = 0; mi < 4; ++mi) { ac0[mi][ni] = (float4v)(bv0); ac1[mi][ni] = (float4v)(bv1); }
        }
        for (int k0 = 0; k0 < K; k0 += 64) {
            const size_t kby = (size_t)k0 * 2;
#pragma unroll
            for (int i = 0; i < 4; ++i)
                gload_lds16(Ab + (size_t)(m0 + srA[i]) * K2 + kby + scA[i], lA + i * 4096);
#pragma unroll
            for (int i = 0; i < 2; ++i)
                gload_lds16(Bb0 + (size_t)(n0 + srB[i]) * K2 + kby + scB[i], lB0 + i * 4096);
#pragma unroll
            for (int i = 0; i < 2; ++i)
                gload_lds16(Bb1 + (size_t)(n0 + srB[i]) * K2 + kby + scB[i], lB1 + i * 4096);
            __syncthreads();
#pragma unroll
            for (int kk = 0; kk < 2; ++kk) {
                short8v av[4], bv0[2], bv1[2];
                const int slot = kk * 4 + fq;
#pragma unroll
                for (int mi = 0; mi < 4; ++mi) {
                    int ra = wr * 64 + mi * 16 + frow;
                    av[mi] = *(const short8v*)((const char*)As + ra * 128 + ((slot ^ (ra & 7)) * 16));
                }
#pragma unroll
                for (int ni = 0; ni < 2; ++ni) {
                    int rb = wc * 32 + ni * 16 + frow;
                    int rboff = rb * 128 + ((slot ^ (rb & 7)) * 16);
                    bv0[ni] = *(const short8v*)((const char*)&Bs[0][0] + rboff);
                    bv1[ni] = *(const short8v*)((const char*)&Bs[1][0] + rboff);
                }
#pragma unroll
                for (int mi = 0; mi < 4; ++mi)
#pragma unroll
                    for (int ni = 0; ni < 2; ++ni) {
                        ac0[mi][ni] = __builtin_amdgcn_mfma_f32_16x16x32_bf16(av[mi], bv0[ni], ac0[mi][ni], 0, 0, 0);
                        ac1[mi][ni] = __builtin_amdgcn_mfma_f32_16x16x32_bf16(av[mi], bv1[ni], ac1[mi][ni], 0, 0, 0);
                    }
            }
            __syncthreads();
        }
#pragma unroll
        for (int ni = 0; ni < 2; ++ni)
#pragma unroll
            for (int mi = 0; mi < 4; ++mi)
#pragma unroll
                for (int i = 0; i < 4; ++i) {
                    float mn = fminf(ac0[mi][ni][i], ac1[mi][ni][i]);
                    float mx = fmaxf(ac0[mi][ni][i], ac1[mi][ni][i]);
                    hmn[mi][ni][i] = fminf(hmn[mi][ni][i], mn);
                    hmx[mi][ni][i] = fmaxf(hmx[mi][ni][i], mx);
                }
    }

#pragma unroll
    for (int ni = 0; ni < 2; ++ni) {
        int col = n0 + wc * 32 + ni * 16 + frow;
#pragma unroll
        for (int mi = 0; mi < 4; ++mi) {
#pragma unroll
            for (int i = 0; i < 4; ++i) {
                int row = m0 + wr * 64 + mi * 16 + fq * 4 + i;
                float g = fmaxf(gelu_fast(hmn[mi][ni][i]), gelu_fast(hmx[mi][ni][i]));
                P[(size_t)row * Nc + col] = f2bf(g);
            }
        }
    }
}

// ---------------- combine: out[i] = max_s P[s][i] (bf16, 4/thread) ----------------
__global__ void combine_max(const unsigned short* __restrict__ P, unsigned short* __restrict__ out,
                            size_t tileElems, int S) {
    size_t i = ((size_t)blockIdx.x * blockDim.x + threadIdx.x) * 4;
    if (i >= tileElems) return;
    ushort4 best = *(const ushort4*)(P + i);
    for (int s = 1; s < S; ++s) {
        ushort4 c = *(const ushort4*)(P + (size_t)s * tileElems + i);
        if (bf2f(c.x) > bf2f(best.x)) best.x = c.x;
        if (bf2f(c.y) > bf2f(best.y)) best.y = c.y;
        if (bf2f(c.z) > bf2f(best.z)) best.z = c.z;
        if (bf2f(c.w) > bf2f(best.w)) best.w = c.w;
    }
    *(ushort4*)(out + i) = best;
}

// ---------------- LayerNorm over H=512: f32 in -> bf16 out ----------------
__global__ __launch_bounds__(256) void layernorm_bf16(const float* __restrict__ h,
                                                      unsigned short* __restrict__ o,
                                                      const float* __restrict__ g,
                                                      const float* __restrict__ b) {
    int row = blockIdx.x;
    const float* p = h + (size_t)row * 512;
    int tid = threadIdx.x;
    float v0 = p[tid], v1 = p[tid + 256];
    float s = v0 + v1, sq = v0 * v0 + v1 * v1;
#pragma unroll
    for (int off = 32; off >= 1; off >>= 1) {
        s += __shfl_xor(s, off);
        sq += __shfl_xor(sq, off);
    }
    __shared__ float ls[4], lq[4];
    int wid = tid >> 6, lane = tid & 63;
    if (lane == 0) { ls[wid] = s; lq[wid] = sq; }
    __syncthreads();
    float ts = ls[0] + ls[1] + ls[2] + ls[3];
    float tq = lq[0] + lq[1] + lq[2] + lq[3];
    float mean = ts / 512.f;
    float var = tq / 512.f - mean * mean;
    float inv = rsqrtf(var + 1e-5f);
    unsigned short* op = o + (size_t)row * 512;
    op[tid] = f2bf((v0 - mean) * inv * g[tid] + b[tid]);
    op[tid + 256] = f2bf((v1 - mean) * inv * g[tid + 256] + b[tid + 256]);
}

// ---------------- z = mu + eps * exp(0.5*logvar)  -> bf16 ----------------
__global__ void z_kernel(const float* __restrict__ mu, const float* __restrict__ lv,
                         const float* __restrict__ eps, unsigned short* __restrict__ z, int n4) {
    int i = blockIdx.x * blockDim.x + threadIdx.x;
    if (i >= n4) return;
    float4 m = ((const float4*)mu)[i];
    float4 l = ((const float4*)lv)[i];
    float4 e = ((const float4*)eps)[i];
    ushort4 o;
    o.x = f2bf(m.x + e.x * expf(0.5f * l.x));
    o.y = f2bf(m.y + e.y * expf(0.5f * l.y));
    o.z = f2bf(m.z + e.z * expf(0.5f * l.z));
    o.w = f2bf(m.w + e.w * expf(0.5f * l.w));
    ((ushort4*)z)[i] = o;
}

extern "C" void kernel_launch(void* const* d_in, const int* in_sizes, int n_in,
                              void* d_out, int out_size, void* d_ws, size_t ws_size,
                              hipStream_t stream) {
    const float* x        = (const float*)d_in[0];
    const int*   arows    = (const int*)d_in[1];
    const int*   acols    = (const int*)d_in[2];
    const float* avals    = (const float*)d_in[3];
    const float* basisenc = (const float*)d_in[4];
    const float* ln_g     = (const float*)d_in[5];
    const float* ln_b     = (const float*)d_in[6];
    const float* Wd_enc   = (const float*)d_in[7];
    const float* bd_enc   = (const float*)d_in[8];
    const float* W_mu     = (const float*)d_in[9];
    const float* b_mu     = (const float*)d_in[10];
    const float* W_lv     = (const float*)d_in[11];
    const float* b_lv     = (const float*)d_in[12];
    const float* Wd_dec   = (const float*)d_in[13];
    const float* bd_dec   = (const float*)d_in[14];
    const float* basisdec = (const float*)d_in[15];
    const float* epsin    = (const float*)d_in[16];

    const int N = 16384;
    const int E = in_sizes[1];

    float* ws = (float*)d_ws;
    const size_t A0 = 0;                               // f32 N*768: xa -> hF -> Penc(2xN*256 u16) -> Pdec(2xN*512 u16) -> b1
    const size_t B0 = A0 + (size_t)N * 768;            // u16 N*800: cenc -> [cdec | zb]
    const size_t C0 = B0 + (size_t)N * 400;            // f32 N*387: xbf -> a1 -> [hbf | encb] -> decb
    const size_t D0 = C0 + (size_t)N * 387;            // f32 N*197: a2 -> b2
    const size_t E0 = D0 + (size_t)N * 197;            // f32 N*102: a3 -> b3
    const size_t F0 = E0 + (size_t)N * 102;            // u16 weights
    const size_t G0 = F0 + 3100672;                    // CSR

    float* xa  = ws + A0;
    float* hF  = ws + A0;
    unsigned short* Penc = (unsigned short*)(ws + A0);  // 2 x N*256 u16
    unsigned short* Pdec = (unsigned short*)(ws + A0);  // 2 x N*512 u16
    float* b1  = ws + A0;
    unsigned short* cenc = (unsigned short*)(ws + B0);
    unsigned short* cdec = (unsigned short*)(ws + B0);
    unsigned short* zb   = cdec + (size_t)N * 544;
    unsigned short* xbf  = (unsigned short*)(ws + C0);
    float* a1 = ws + C0;
    unsigned short* hbf  = (unsigned short*)(ws + C0);
    unsigned short* encb = hbf + (size_t)N * 512;
    unsigned short* decb = (unsigned short*)(ws + C0);
    float* a2 = ws + D0;
    float* b2 = ws + D0;
    float* a3 = ws + E0;
    float* b3 = ws + E0;
    unsigned short* wF = (unsigned short*)(ws + F0);
    unsigned short* BceT   = wF;                       // 512*800
    unsigned short* BcdT   = BceT + 512 * 800;         // 768*544
    unsigned short* WdencT = BcdT + 768 * 544;         // 20*256*512
    unsigned short* WddecT = WdencT + 20 * 256 * 512;  // 20*512*256
    unsigned short* WmuT   = WddecT + 20 * 512 * 256;  // 256*256
    unsigned short* WlvT   = WmuT + 256 * 256;
    int*   csr_cnt  = (int*)(ws + G0);
    int*   csr_offs = csr_cnt + N;
    int*   csr_cur  = csr_offs + N + 1;
    int*   csr_col  = csr_cur + N;
    float* csr_val  = (float*)(csr_col + E);

    float* out_recon = (float*)d_out;
    float* out_mu    = out_recon + (size_t)N * 768;
    float* out_lv    = out_mu + (size_t)N * 256;

    // --- packs + cast (independent) ---
    {
        Bounds be = {{0, 54, 108, 210, 407, 794}};
        pack_basis_T<<<(512 * 800 + 255) / 256, 256, 0, stream>>>(basisenc, BceT, be, 768, 512, 794, 800);
        Bounds bdd = {{0, 38, 76, 146, 279, 538}};
        pack_basis_T<<<(768 * 544 + 255) / 256, 256, 0, stream>>>(basisdec, BcdT, bdd, 512, 768, 538, 544);
        pack_wT<<<(20 * 256 * 512 + 255) / 256, 256, 0, stream>>>(Wd_enc, WdencT, 20, 512, 256, 512);
        pack_wT<<<(20 * 512 * 256 + 255) / 256, 256, 0, stream>>>(Wd_dec, WddecT, 20, 256, 512, 256);
        pack_wT<<<(256 * 256 + 255) / 256, 256, 0, stream>>>(W_mu, WmuT, 1, 256, 256, 256);
        pack_wT<<<(256 * 256 + 255) / 256, 256, 0, stream>>>(W_lv, WlvT, 1, 256, 256, 256);
        cast_bf16_kernel<<<(N * 768 / 4 + 255) / 256, 256, 0, stream>>>(x, xbf, N * 768 / 4);
    }

    // 1) SpMM via device-built CSR (bf16 gather)
    hipMemsetAsync(csr_cnt, 0, N * sizeof(int), stream);
    hipMemsetAsync(cenc, 0, (size_t)N * 800 * sizeof(unsigned short), stream);
    hist_kernel<<<(E + 255) / 256, 256, 0, stream>>>(arows, csr_cnt, E);
    scan_kernel<<<1, 1024, 0, stream>>>(csr_cnt, csr_offs, csr_cur, N, E);
    scatter_kernel<<<(E + 255) / 256, 256, 0, stream>>>(arows, acols, avals, csr_cur, csr_col, csr_val, E);
    spmm_csr<<<N / 4, 256, 0, stream>>>(xbf, csr_offs, csr_col, csr_val, xa);

    // 2) wavedec enc: 768->387->197->102->54 ; cenc cols [cA4(0)|cD4(54)|cD3(108)|cD2(210)|cD1(407)]
    dwt_kernel<false, false><<<N, 128, 768 * 4, stream>>>(xa, 768, 768, a1, 387, cenc + 407, 800, 387);
    dwt_kernel<false, false><<<N, 128, 387 * 4, stream>>>(a1, 387, 387, a2, 197, cenc + 210, 800, 197);
    dwt_kernel<false, false><<<N, 128, 197 * 4, stream>>>(a2, 197, 197, a3, 102, cenc + 108, 800, 102);
    dwt_kernel<false, true><<<N, 128, 102 * 4, stream>>>(a3, 102, 102, cenc + 0, 800, cenc + 54, 800, 54);

    // 3) h = cenc @ BceT^T  [16384,512], K=800
    gemm_mfma<0><<<dim3(512 / 128, N / 128), 256, 0, stream>>>(cenc, BceT, nullptr, hF, N, 512, 800, 800, 800, 512);

    // 4) layernorm -> bf16
    layernorm_bf16<<<N, 256, 0, stream>>>(hF, hbf, ln_g, ln_b);

    // 5) enc: 2 branch-groups of 10, dual-branch passes (hF dead -> Penc), combine -> encb.
    //    nwg = 4*128*2 = 1024 (%8==0)
    dendritic_part<<<4 * (N / 128) * 2, 256, 0, stream>>>(hbf, WdencT, bd_enc, Penc, N, 256, 512, 20, 2, 4);
    combine_max<<<(int)(((size_t)N * 256 / 4 + 255) / 256), 256, 0, stream>>>(Penc, encb, (size_t)N * 256, 2);

    // 6) mu / logvar (f32 out to d_out), K=256
    gemm_mfma<0><<<dim3(256 / 128, N / 128), 256, 0, stream>>>(encb, WmuT, b_mu, out_mu, N, 256, 256, 256, 256, 256);
    gemm_mfma<0><<<dim3(256 / 128, N / 128), 256, 0, stream>>>(encb, WlvT, b_lv, out_lv, N, 256, 256, 256, 256, 256);

    // 7) z -> bf16
    z_kernel<<<(N * 256 / 4 + 255) / 256, 256, 0, stream>>>(out_mu, out_lv, epsin, zb, N * 256 / 4);

    // 8) dec: 2 branch-groups of 10, dual-branch passes (Penc dead -> Pdec), combine -> decb.
    //    nwg = 8*128*2 = 2048 (%8==0)
    dendritic_part<<<8 * (N / 128) * 2, 256, 0, stream>>>(zb, WddecT, bd_dec, Pdec, N, 512, 256, 20, 2, 8);
    combine_max<<<(int)(((size_t)N * 512 / 4 + 255) / 256), 256, 0, stream>>>(Pdec, decb, (size_t)N * 512, 2);

    // 9) memset cdec pad, then wavedec dec: 512->259->133->70->38 ; cols [0|38|76|146|279]
    hipMemsetAsync(cdec, 0, (size_t)N * 544 * sizeof(unsigned short), stream);
    dwt_kernel<true, false><<<N, 128, 512 * 4, stream>>>(decb, 512, 512, b1, 259, cdec + 279, 544, 259);
    dwt_kernel<false, false><<<N, 128, 259 * 4, stream>>>(b1, 259, 259, b2, 133, cdec + 146, 544, 133);
    dwt_kernel<false, false><<<N, 128, 133 * 4, stream>>>(b2, 133, 133, b3, 70, cdec + 76, 544, 70);
    dwt_kernel<false, true><<<N, 128, 70 * 4, stream>>>(b3, 70, 70, cdec + 0, 544, cdec + 38, 544, 38);

    // 10) recon = cdec @ BcdT^T [16384,768], K=544
    gemm_mfma<0><<<dim3(768 / 128, N / 128), 256, 0, stream>>>(cdec, BcdT, nullptr, out_recon, N, 768, 544, 544, 544, 768);

    (void)ws_size; (void)out_size; (void)n_in;
}

// Round 12
// 520.680 us; speedup vs baseline: 1.8414x; 1.1909x over previous
//
#include <hip/hip_runtime.h>

typedef __attribute__((ext_vector_type(8))) short short8v;
typedef __attribute__((ext_vector_type(8))) unsigned short ushort8v;
typedef __attribute__((ext_vector_type(4))) float float4v;

__device__ __constant__ float c_LO[8] = {
    -0.010597401784997278f, 0.032883011666982945f, 0.030841381835986965f,
    -0.18703481171888114f, -0.02798376941698385f, 0.6308807679295904f,
    0.7148465705525415f, 0.23037781330885523f};
__device__ __constant__ float c_HI[8] = {
    -0.23037781330885523f, 0.7148465705525415f, -0.6308807679295904f,
    -0.02798376941698385f, 0.18703481171888114f, 0.030841381835986965f,
    -0.032883011666982945f, -0.010597401784997278f};

__device__ __forceinline__ unsigned short f2bf(float f) {
    unsigned u = __builtin_bit_cast(unsigned, f);
    unsigned r = u + 0x7fffu + ((u >> 16) & 1u);
    return (unsigned short)(r >> 16);
}
__device__ __forceinline__ float bf2f(unsigned short u) {
    return __builtin_bit_cast(float, (unsigned)u << 16);
}

// tanh-form GELU: one exp2 + rcp
__device__ __forceinline__ float gelu_fast(float x) {
    float x3 = x * x * x;
    float y = fmaf(0.044715f, x3, x) * 0.7978845608028654f;
    float t = fminf(fmaxf(y * 2.8853900817779268f, -30.f), 30.f);
    float e = exp2f(t);
    return x * e * __builtin_amdgcn_rcpf(e + 1.0f);
}

__device__ __forceinline__ void gload_lds16(const void* g, void* l) {
    __builtin_amdgcn_global_load_lds(g, l, 16, 0, 0);
}

// ---- one DWT level: LDS f32 in -> LDS f32 cA + global bf16 cD (pywt symmetric) ----
__device__ __forceinline__ void dwt_lvl(const float* __restrict__ in, int n, float* __restrict__ outA,
                                        unsigned short* __restrict__ outD, int m, int lane) {
    for (int j = lane; j < m; j += 64) {
        float a = 0.f, d = 0.f;
#pragma unroll
        for (int i = 0; i < 8; ++i) {
            int p = 2 * j + 7 - i;
            int q = (p < 6) ? (5 - p) : ((p < n + 6) ? (p - 6) : (2 * n + 5 - p));
            float xv = in[q];
            a = fmaf(c_LO[i], xv, a);
            d = fmaf(c_HI[i], xv, d);
        }
        outA[j] = a;
        outD[j] = f2bf(d);
    }
}
// final level: both outputs global bf16
__device__ __forceinline__ void dwt_lvl_final(const float* __restrict__ in, int n, unsigned short* __restrict__ outA,
                                              unsigned short* __restrict__ outD, int m, int lane) {
    for (int j = lane; j < m; j += 64) {
        float a = 0.f, d = 0.f;
#pragma unroll
        for (int i = 0; i < 8; ++i) {
            int p = 2 * j + 7 - i;
            int q = (p < 6) ? (5 - p) : ((p < n + 6) ? (p - 6) : (2 * n + 5 - p));
            float xv = in[q];
            a = fmaf(c_LO[i], xv, a);
            d = fmaf(c_HI[i], xv, d);
        }
        outA[j] = f2bf(a);
        outD[j] = f2bf(d);
    }
}

// ---------------- x -> bf16 cast ----------------
__global__ void cast_bf16_kernel(const float* __restrict__ in, unsigned short* __restrict__ out, int n4) {
    int i = blockIdx.x * blockDim.x + threadIdx.x;
    if (i >= n4) return;
    float4 v = ((const float4*)in)[i];
    ushort4 o;
    o.x = f2bf(v.x); o.y = f2bf(v.y); o.z = f2bf(v.z); o.w = f2bf(v.w);
    ((ushort4*)out)[i] = o;
}

// ---------------- CSR build: histogram ----------------
__global__ void hist_kernel(const int* __restrict__ rows, int* __restrict__ cnt, int E) {
    int i = blockIdx.x * blockDim.x + threadIdx.x;
    if (i < E) atomicAdd(&cnt[rows[i]], 1);
}

// ---------------- CSR build: single-block scan ----------------
__global__ __launch_bounds__(1024) void scan_kernel(const int* __restrict__ cnt, int* __restrict__ offs,
                                                    int* __restrict__ cursor, int Nrows, int E) {
    __shared__ int part[1024];
    int tid = threadIdx.x;
    const int per = Nrows / 1024;  // 16
    int base = tid * per;
    int local[16];
    int s = 0;
    for (int i = 0; i < per; ++i) { local[i] = s; s += cnt[base + i]; }
    part[tid] = s;
    __syncthreads();
    for (int off = 1; off < 1024; off <<= 1) {
        int v = part[tid];
        int w = (tid >= off) ? part[tid - off] : 0;
        __syncthreads();
        part[tid] = v + w;
        __syncthreads();
    }
    int pre = (tid == 0) ? 0 : part[tid - 1];
    for (int i = 0; i < per; ++i) {
        int o = pre + local[i];
        offs[base + i] = o;
        cursor[base + i] = o;
    }
    if (tid == 0) offs[Nrows] = E;
}

// ---------------- CSR build: scatter ----------------
__global__ void scatter_kernel(const int* __restrict__ rows, const int* __restrict__ cols,
                               const float* __restrict__ vals, int* __restrict__ cursor,
                               int* __restrict__ ccol, float* __restrict__ cval, int E) {
    int i = blockIdx.x * blockDim.x + threadIdx.x;
    if (i >= E) return;
    int r = rows[i];
    int p = atomicAdd(&cursor[r], 1);
    ccol[p] = cols[i];
    cval[p] = vals[i];
}

// ---- FUSED: SpMM (CSR, bf16 gather) + 4-level wavedec -> cenc bf16 [N,800] ----
// one wave per row; DWT ping-pongs in LDS; pad cols written inline.
__global__ __launch_bounds__(256) void spmm_wavedec_enc(const unsigned short* __restrict__ xb,
                                                        const int* __restrict__ offs,
                                                        const int* __restrict__ ccol,
                                                        const float* __restrict__ cval,
                                                        unsigned short* __restrict__ cenc) {
    __shared__ float buf0[4][768];
    __shared__ float buf1[4][400];
    const int widx = threadIdx.x >> 6, lane = threadIdx.x & 63;
    const int r = blockIdx.x * 4 + widx;
    float* b0 = buf0[widx];
    float* b1 = buf1[widx];

    // gather
    int s = offs[r], e = offs[r + 1];
    float acc[12] = {};
    for (int j = s; j < e; ++j) {
        int c = ccol[j];
        float v = cval[j];
        const unsigned short* xr = xb + (size_t)c * 768;
#pragma unroll
        for (int seg = 0; seg < 3; ++seg) {
            ushort4 u = *(const ushort4*)(xr + seg * 256 + lane * 4);
            acc[seg * 4 + 0] = fmaf(v, bf2f(u.x), acc[seg * 4 + 0]);
            acc[seg * 4 + 1] = fmaf(v, bf2f(u.y), acc[seg * 4 + 1]);
            acc[seg * 4 + 2] = fmaf(v, bf2f(u.z), acc[seg * 4 + 2]);
            acc[seg * 4 + 3] = fmaf(v, bf2f(u.w), acc[seg * 4 + 3]);
        }
    }
#pragma unroll
    for (int seg = 0; seg < 3; ++seg) {
        b0[seg * 256 + lane * 4 + 0] = acc[seg * 4 + 0];
        b0[seg * 256 + lane * 4 + 1] = acc[seg * 4 + 1];
        b0[seg * 256 + lane * 4 + 2] = acc[seg * 4 + 2];
        b0[seg * 256 + lane * 4 + 3] = acc[seg * 4 + 3];
    }
    __syncthreads();

    unsigned short* cr = cenc + (size_t)r * 800;
    // cols: cA4(0,54) | cD4(54,54) | cD3(108,102) | cD2(210,197) | cD1(407,387) | pad(794,6)
    dwt_lvl(b0, 768, b1, cr + 407, 387, lane);
    __syncthreads();
    dwt_lvl(b1, 387, b0, cr + 210, 197, lane);
    __syncthreads();
    dwt_lvl(b0, 197, b1, cr + 108, 102, lane);
    __syncthreads();
    dwt_lvl_final(b1, 102, cr + 0, cr + 54, 54, lane);
    if (lane < 6) cr[794 + lane] = 0;
}

// ---- FUSED: 4-level wavedec of dec (bf16 in) -> cdec bf16 [N,544] ----
__global__ __launch_bounds__(256) void wavedec_dec(const unsigned short* __restrict__ decb,
                                                   unsigned short* __restrict__ cdec) {
    __shared__ float buf0[4][512];
    __shared__ float buf1[4][272];
    const int widx = threadIdx.x >> 6, lane = threadIdx.x & 63;
    const int r = blockIdx.x * 4 + widx;
    float* b0 = buf0[widx];
    float* b1 = buf1[widx];
    const unsigned short* ip = decb + (size_t)r * 512;
    for (int i = lane; i < 512; i += 64) b0[i] = bf2f(ip[i]);
    __syncthreads();
    unsigned short* cr = cdec + (size_t)r * 544;
    // cols: cA4(0,38) | cD4(38,38) | cD3(76,70) | cD2(146,133) | cD1(279,259) | pad(538,6)
    dwt_lvl(b0, 512, b1, cr + 279, 259, lane);
    __syncthreads();
    dwt_lvl(b1, 259, b0, cr + 146, 133, lane);
    __syncthreads();
    dwt_lvl(b0, 133, b1, cr + 76, 70, lane);
    __syncthreads();
    dwt_lvl_final(b1, 70, cr + 0, cr + 38, 38, lane);
    if (lane < 6) cr[538 + lane] = 0;
}

// ---------------- pack basis stack -> transposed bf16 [N][Kpad] ----------------
struct Bounds { int b[6]; };

__global__ void pack_basis_T(const float* __restrict__ basis, unsigned short* __restrict__ BT,
                             Bounds bd, int brows, int N, int K, int Kpad) {
    int idx = blockIdx.x * blockDim.x + threadIdx.x;
    if (idx >= N * Kpad) return;
    int n = idx / Kpad, k = idx - n * Kpad;
    float v = 0.f;
    if (k < K) {
        int s = 0;
#pragma unroll
        for (int t = 1; t < 5; ++t)
            if (k >= bd.b[t]) s = t;
        int lr = k - bd.b[s];
        v = basis[((size_t)s * brows + lr) * N + n];
    }
    BT[idx] = f2bf(v);
}

// ---------------- pack weights [NB][K][N] -> transposed bf16 [NB][N][Kpad] ----------------
__global__ void pack_wT(const float* __restrict__ W, unsigned short* __restrict__ WT,
                        int NB, int K, int N, int Kpad) {
    int idx = blockIdx.x * blockDim.x + threadIdx.x;
    int tot = NB * N * Kpad;
    if (idx >= tot) return;
    int b = idx / (N * Kpad);
    int r = idx - b * (N * Kpad);
    int n = r / Kpad, k = r - n * Kpad;
    float v = (k < K) ? W[((size_t)b * K + k) * N + n] : 0.f;
    WT[idx] = f2bf(v);
}

// ---------------- bf16 MFMA GEMM (proven) ----------------
template <int OUT_BF16>
__global__ __launch_bounds__(256) void gemm_mfma(const unsigned short* __restrict__ A,
                                                 const unsigned short* __restrict__ BT,
                                                 const float* __restrict__ bias,
                                                 void* __restrict__ Cv,
                                                 int M, int N, int K, int lda, int ldb, int ldc) {
    __shared__ __align__(16) unsigned short As[128 * 32];
    __shared__ __align__(16) unsigned short Bs[128 * 32];
    const int tid = threadIdx.x;
    const int wave = tid >> 6, lane = tid & 63;
    const int m0 = blockIdx.y * 128, n0 = blockIdx.x * 128;
    const int wr = wave >> 1, wc = wave & 1;
    const int frow = lane & 15, fq = lane >> 4;

    const int off0 = tid * 16;
    const int r0 = off0 >> 6, c0 = off0 & 63;
    const int r1 = (off0 + 4096) >> 6, c1 = (off0 + 4096) & 63;
    const char* Ab = (const char*)A;
    const char* Bb = (const char*)BT;
    size_t gA0 = (size_t)(m0 + r0) * lda * 2 + c0;
    size_t gA1 = (size_t)(m0 + r1) * lda * 2 + c1;
    size_t gB0 = (size_t)(n0 + r0) * ldb * 2 + c0;
    size_t gB1 = (size_t)(n0 + r1) * ldb * 2 + c1;
    char* lA0 = (char*)As + wave * 1024;
    char* lB0 = (char*)Bs + wave * 1024;

    const int aoff = (wr * 64 + frow) * 32 + fq * 8;
    const int boff = (wc * 64 + frow) * 32 + fq * 8;

    float4v acc[4][4] = {};
    for (int k0 = 0; k0 < K; k0 += 32) {
        size_t kb2 = (size_t)k0 * 2;
        gload_lds16(Ab + gA0 + kb2, lA0);
        gload_lds16(Ab + gA1 + kb2, lA0 + 4096);
        gload_lds16(Bb + gB0 + kb2, lB0);
        gload_lds16(Bb + gB1 + kb2, lB0 + 4096);
        __syncthreads();
        short8v av[4], bv[4];
#pragma unroll
        for (int i = 0; i < 4; ++i) av[i] = *(const short8v*)(As + aoff + i * 512);
#pragma unroll
        for (int i = 0; i < 4; ++i) bv[i] = *(const short8v*)(Bs + boff + i * 512);
#pragma unroll
        for (int mi = 0; mi < 4; ++mi)
#pragma unroll
            for (int ni = 0; ni < 4; ++ni)
                acc[mi][ni] = __builtin_amdgcn_mfma_f32_16x16x32_bf16(av[mi], bv[ni], acc[mi][ni], 0, 0, 0);
        __syncthreads();
    }
#pragma unroll
    for (int ni = 0; ni < 4; ++ni) {
        int col = n0 + wc * 64 + ni * 16 + frow;
        float bval = bias ? bias[col] : 0.f;
#pragma unroll
        for (int mi = 0; mi < 4; ++mi) {
#pragma unroll
            for (int i = 0; i < 4; ++i) {
                int row = m0 + wr * 64 + mi * 16 + fq * 4 + i;
                float v = acc[mi][ni][i] + bval;
                if (OUT_BF16)
                    ((unsigned short*)Cv)[(size_t)row * ldc + col] = f2bf(v);
                else
                    ((float*)Cv)[(size_t)row * ldc + col] = v;
            }
        }
    }
}

// ---- dendritic partial v7: dual-branch per pass (shared A-fragments). ----
__global__ __launch_bounds__(256, 2) void dendritic_part(const unsigned short* __restrict__ A,
                                                         const unsigned short* __restrict__ WT,
                                                         const float* __restrict__ bias,
                                                         unsigned short* __restrict__ Pout,
                                                         int M, int Nc, int K, int nb, int ngrp, int nx) {
    __shared__ __align__(16) unsigned short As[128 * 64];     // 16 KB
    __shared__ __align__(16) unsigned short Bs[2][64 * 64];   // 2 x 8 KB
    const int tid = threadIdx.x;
    const int wave = tid >> 6;
    const int lane = tid & 63;

    const int nwg = gridDim.x;
    const int logical = (blockIdx.x & 7) * (nwg >> 3) + (blockIdx.x >> 3);
    const int span = nx * ngrp;
    const int mblk = logical / span;
    const int rem = logical - mblk * span;
    const int gz = rem / nx;
    const int nblk = rem - gz * nx;
    const int n0 = nblk * 64, m0 = mblk * 128;

    const int q = nb / ngrp, rmd = nb - q * ngrp;
    const int kb0 = gz * q + (gz < rmd ? gz : rmd);
    const int kbn = q + (gz < rmd ? 1 : 0);
    unsigned short* P = Pout + (size_t)gz * M * Nc;
    const int wr = wave >> 1, wc = wave & 1;
    const int frow = lane & 15, fq = lane >> 4;

    int srA[4], scA[4];
#pragma unroll
    for (int i = 0; i < 4; ++i) {
        int ch = i * 256 + tid;
        srA[i] = ch >> 3;
        scA[i] = ((ch & 7) ^ (srA[i] & 7)) * 16;
    }
    int srB[2], scB[2];
#pragma unroll
    for (int i = 0; i < 2; ++i) {
        int ch = i * 256 + tid;
        srB[i] = ch >> 3;
        scB[i] = ((ch & 7) ^ (srB[i] & 7)) * 16;
    }
    const char* Ab = (const char*)A;
    const size_t K2 = (size_t)K * 2;
    const size_t branchBytes = (size_t)Nc * K2;
    char* lA  = (char*)As + wave * 1024;
    char* lB0 = (char*)&Bs[0][0] + wave * 1024;
    char* lB1 = (char*)&Bs[1][0] + wave * 1024;

    float4v hmn[4][2], hmx[4][2];
#pragma unroll
    for (int mi = 0; mi < 4; ++mi)
#pragma unroll
        for (int ni = 0; ni < 2; ++ni) { hmn[mi][ni] = (float4v)(1e30f); hmx[mi][ni] = (float4v)(-1e30f); }

    const int npair = (kbn + 1) >> 1;
    for (int p = 0; p < npair; ++p) {
        const int b0 = kb0 + 2 * p;
        const int b1 = (2 * p + 1 < kbn) ? (b0 + 1) : b0;  // clamp (idempotent under min/max)
        const char* Bb0 = (const char*)WT + (size_t)b0 * branchBytes;
        const char* Bb1 = (const char*)WT + (size_t)b1 * branchBytes;
        float4v ac0[4][2], ac1[4][2];
#pragma unroll
        for (int ni = 0; ni < 2; ++ni) {
            int col = n0 + wc * 32 + ni * 16 + frow;
            float bv0 = bias[(size_t)b0 * Nc + col];
            float bv1 = bias[(size_t)b1 * Nc + col];
#pragma unroll
            for (int mi = 0; mi < 4; ++mi) { ac0[mi][ni] = (float4v)(bv0); ac1[mi][ni] = (float4v)(bv1); }
        }
        for (int k0 = 0; k0 < K; k0 += 64) {
            const size_t kby = (size_t)k0 * 2;
#pragma unroll
            for (int i = 0; i < 4; ++i)
                gload_lds16(Ab + (size_t)(m0 + srA[i]) * K2 + kby + scA[i], lA + i * 4096);
#pragma unroll
            for (int i = 0; i < 2; ++i)
                gload_lds16(Bb0 + (size_t)(n0 + srB[i]) * K2 + kby + scB[i], lB0 + i * 4096);
#pragma unroll
            for (int i = 0; i < 2; ++i)
                gload_lds16(Bb1 + (size_t)(n0 + srB[i]) * K2 + kby + scB[i], lB1 + i * 4096);
            __syncthreads();
#pragma unroll
            for (int kk = 0; kk < 2; ++kk) {
                short8v av[4], bv0[2], bv1[2];
                const int slot = kk * 4 + fq;
#pragma unroll
                for (int mi = 0; mi < 4; ++mi) {
                    int ra = wr * 64 + mi * 16 + frow;
                    av[mi] = *(const short8v*)((const char*)As + ra * 128 + ((slot ^ (ra & 7)) * 16));
                }
#pragma unroll
                for (int ni = 0; ni < 2; ++ni) {
                    int rb = wc * 32 + ni * 16 + frow;
                    int rboff = rb * 128 + ((slot ^ (rb & 7)) * 16);
                    bv0[ni] = *(const short8v*)((const char*)&Bs[0][0] + rboff);
                    bv1[ni] = *(const short8v*)((const char*)&Bs[1][0] + rboff);
                }
#pragma unroll
                for (int mi = 0; mi < 4; ++mi)
#pragma unroll
                    for (int ni = 0; ni < 2; ++ni) {
                        ac0[mi][ni] = __builtin_amdgcn_mfma_f32_16x16x32_bf16(av[mi], bv0[ni], ac0[mi][ni], 0, 0, 0);
                        ac1[mi][ni] = __builtin_amdgcn_mfma_f32_16x16x32_bf16(av[mi], bv1[ni], ac1[mi][ni], 0, 0, 0);
                    }
            }
            __syncthreads();
        }
#pragma unroll
        for (int ni = 0; ni < 2; ++ni)
#pragma unroll
            for (int mi = 0; mi < 4; ++mi)
#pragma unroll
                for (int i = 0; i < 4; ++i) {
                    float mn = fminf(ac0[mi][ni][i], ac1[mi][ni][i]);
                    float mx = fmaxf(ac0[mi][ni][i], ac1[mi][ni][i]);
                    hmn[mi][ni][i] = fminf(hmn[mi][ni][i], mn);
                    hmx[mi][ni][i] = fmaxf(hmx[mi][ni][i], mx);
                }
    }

#pragma unroll
    for (int ni = 0; ni < 2; ++ni) {
        int col = n0 + wc * 32 + ni * 16 + frow;
#pragma unroll
        for (int mi = 0; mi < 4; ++mi) {
#pragma unroll
            for (int i = 0; i < 4; ++i) {
                int row = m0 + wr * 64 + mi * 16 + fq * 4 + i;
                float g = fmaxf(gelu_fast(hmn[mi][ni][i]), gelu_fast(hmx[mi][ni][i]));
                P[(size_t)row * Nc + col] = f2bf(g);
            }
        }
    }
}

// ---------------- combine: out[i] = max_s P[s][i] (bf16, 4/thread) ----------------
__global__ void combine_max(const unsigned short* __restrict__ P, unsigned short* __restrict__ out,
                            size_t tileElems, int S) {
    size_t i = ((size_t)blockIdx.x * blockDim.x + threadIdx.x) * 4;
    if (i >= tileElems) return;
    ushort4 best = *(const ushort4*)(P + i);
    for (int s = 1; s < S; ++s) {
        ushort4 c = *(const ushort4*)(P + (size_t)s * tileElems + i);
        if (bf2f(c.x) > bf2f(best.x)) best.x = c.x;
        if (bf2f(c.y) > bf2f(best.y)) best.y = c.y;
        if (bf2f(c.z) > bf2f(best.z)) best.z = c.z;
        if (bf2f(c.w) > bf2f(best.w)) best.w = c.w;
    }
    *(ushort4*)(out + i) = best;
}

// ---------------- LayerNorm over H=512: f32 in -> bf16 out ----------------
__global__ __launch_bounds__(256) void layernorm_bf16(const float* __restrict__ h,
                                                      unsigned short* __restrict__ o,
                                                      const float* __restrict__ g,
                                                      const float* __restrict__ b) {
    int row = blockIdx.x;
    const float* p = h + (size_t)row * 512;
    int tid = threadIdx.x;
    float v0 = p[tid], v1 = p[tid + 256];
    float s = v0 + v1, sq = v0 * v0 + v1 * v1;
#pragma unroll
    for (int off = 32; off >= 1; off >>= 1) {
        s += __shfl_xor(s, off);
        sq += __shfl_xor(sq, off);
    }
    __shared__ float ls[4], lq[4];
    int wid = tid >> 6, lane = tid & 63;
    if (lane == 0) { ls[wid] = s; lq[wid] = sq; }
    __syncthreads();
    float ts = ls[0] + ls[1] + ls[2] + ls[3];
    float tq = lq[0] + lq[1] + lq[2] + lq[3];
    float mean = ts / 512.f;
    float var = tq / 512.f - mean * mean;
    float inv = rsqrtf(var + 1e-5f);
    unsigned short* op = o + (size_t)row * 512;
    op[tid] = f2bf((v0 - mean) * inv * g[tid] + b[tid]);
    op[tid + 256] = f2bf((v1 - mean) * inv * g[tid + 256] + b[tid + 256]);
}

// ---------------- z = mu + eps * exp(0.5*logvar)  -> bf16 ----------------
__global__ void z_kernel(const float* __restrict__ mu, const float* __restrict__ lv,
                         const float* __restrict__ eps, unsigned short* __restrict__ z, int n4) {
    int i = blockIdx.x * blockDim.x + threadIdx.x;
    if (i >= n4) return;
    float4 m = ((const float4*)mu)[i];
    float4 l = ((const float4*)lv)[i];
    float4 e = ((const float4*)eps)[i];
    ushort4 o;
    o.x = f2bf(m.x + e.x * expf(0.5f * l.x));
    o.y = f2bf(m.y + e.y * expf(0.5f * l.y));
    o.z = f2bf(m.z + e.z * expf(0.5f * l.z));
    o.w = f2bf(m.w + e.w * expf(0.5f * l.w));
    ((ushort4*)z)[i] = o;
}

extern "C" void kernel_launch(void* const* d_in, const int* in_sizes, int n_in,
                              void* d_out, int out_size, void* d_ws, size_t ws_size,
                              hipStream_t stream) {
    const float* x        = (const float*)d_in[0];
    const int*   arows    = (const int*)d_in[1];
    const int*   acols    = (const int*)d_in[2];
    const float* avals    = (const float*)d_in[3];
    const float* basisenc = (const float*)d_in[4];
    const float* ln_g     = (const float*)d_in[5];
    const float* ln_b     = (const float*)d_in[6];
    const float* Wd_enc   = (const float*)d_in[7];
    const float* bd_enc   = (const float*)d_in[8];
    const float* W_mu     = (const float*)d_in[9];
    const float* b_mu     = (const float*)d_in[10];
    const float* W_lv     = (const float*)d_in[11];
    const float* b_lv     = (const float*)d_in[12];
    const float* Wd_dec   = (const float*)d_in[13];
    const float* bd_dec   = (const float*)d_in[14];
    const float* basisdec = (const float*)d_in[15];
    const float* epsin    = (const float*)d_in[16];

    const int N = 16384;
    const int E = in_sizes[1];

    float* ws = (float*)d_ws;
    const size_t A0 = 0;                               // f32 N*768: hF -> Penc/Pdec
    const size_t B0 = A0 + (size_t)N * 768;            // u16 N*800: cenc -> [cdec | zb]
    const size_t C0 = B0 + (size_t)N * 400;            // f32 N*387: xbf -> [hbf | encb] -> decb
    const size_t D0 = C0 + (size_t)N * 387;
    const size_t E0 = D0 + (size_t)N * 197;
    const size_t F0 = E0 + (size_t)N * 102;            // u16 weights
    const size_t G0 = F0 + 3100672;                    // CSR

    float* hF  = ws + A0;
    unsigned short* Penc = (unsigned short*)(ws + A0);  // 2 x N*256 u16
    unsigned short* Pdec = (unsigned short*)(ws + A0);  // 2 x N*512 u16
    unsigned short* cenc = (unsigned short*)(ws + B0);
    unsigned short* cdec = (unsigned short*)(ws + B0);
    unsigned short* zb   = cdec + (size_t)N * 544;
    unsigned short* xbf  = (unsigned short*)(ws + C0);
    unsigned short* hbf  = (unsigned short*)(ws + C0);
    unsigned short* encb = hbf + (size_t)N * 512;
    unsigned short* decb = (unsigned short*)(ws + C0);
    unsigned short* wF = (unsigned short*)(ws + F0);
    unsigned short* BceT   = wF;                       // 512*800
    unsigned short* BcdT   = BceT + 512 * 800;         // 768*544
    unsigned short* WdencT = BcdT + 768 * 544;         // 20*256*512
    unsigned short* WddecT = WdencT + 20 * 256 * 512;  // 20*512*256
    unsigned short* WmuT   = WddecT + 20 * 512 * 256;  // 256*256
    unsigned short* WlvT   = WmuT + 256 * 256;
    int*   csr_cnt  = (int*)(ws + G0);
    int*   csr_offs = csr_cnt + N;
    int*   csr_cur  = csr_offs + N + 1;
    int*   csr_col  = csr_cur + N;
    float* csr_val  = (float*)(csr_col + E);

    float* out_recon = (float*)d_out;
    float* out_mu    = out_recon + (size_t)N * 768;
    float* out_lv    = out_mu + (size_t)N * 256;

    // --- packs + cast (independent) ---
    {
        Bounds be = {{0, 54, 108, 210, 407, 794}};
        pack_basis_T<<<(512 * 800 + 255) / 256, 256, 0, stream>>>(basisenc, BceT, be, 768, 512, 794, 800);
        Bounds bdd = {{0, 38, 76, 146, 279, 538}};
        pack_basis_T<<<(768 * 544 + 255) / 256, 256, 0, stream>>>(basisdec, BcdT, bdd, 512, 768, 538, 544);
        pack_wT<<<(20 * 256 * 512 + 255) / 256, 256, 0, stream>>>(Wd_enc, WdencT, 20, 512, 256, 512);
        pack_wT<<<(20 * 512 * 256 + 255) / 256, 256, 0, stream>>>(Wd_dec, WddecT, 20, 256, 512, 256);
        pack_wT<<<(256 * 256 + 255) / 256, 256, 0, stream>>>(W_mu, WmuT, 1, 256, 256, 256);
        pack_wT<<<(256 * 256 + 255) / 256, 256, 0, stream>>>(W_lv, WlvT, 1, 256, 256, 256);
        cast_bf16_kernel<<<(N * 768 / 4 + 255) / 256, 256, 0, stream>>>(x, xbf, N * 768 / 4);
    }

    // 1) CSR build + fused SpMM+wavedec-enc -> cenc (incl. pad)
    hipMemsetAsync(csr_cnt, 0, N * sizeof(int), stream);
    hist_kernel<<<(E + 255) / 256, 256, 0, stream>>>(arows, csr_cnt, E);
    scan_kernel<<<1, 1024, 0, stream>>>(csr_cnt, csr_offs, csr_cur, N, E);
    scatter_kernel<<<(E + 255) / 256, 256, 0, stream>>>(arows, acols, avals, csr_cur, csr_col, csr_val, E);
    spmm_wavedec_enc<<<N / 4, 256, 0, stream>>>(xbf, csr_offs, csr_col, csr_val, cenc);

    // 2) h = cenc @ BceT^T  [16384,512], K=800
    gemm_mfma<0><<<dim3(512 / 128, N / 128), 256, 0, stream>>>(cenc, BceT, nullptr, hF, N, 512, 800, 800, 800, 512);

    // 3) layernorm -> bf16
    layernorm_bf16<<<N, 256, 0, stream>>>(hF, hbf, ln_g, ln_b);

    // 4) enc: 2 branch-groups of 10, dual-branch passes, combine -> encb.  nwg = 1024
    dendritic_part<<<4 * (N / 128) * 2, 256, 0, stream>>>(hbf, WdencT, bd_enc, Penc, N, 256, 512, 20, 2, 4);
    combine_max<<<(int)(((size_t)N * 256 / 4 + 255) / 256), 256, 0, stream>>>(Penc, encb, (size_t)N * 256, 2);

    // 5) mu / logvar (f32 out to d_out), K=256
    gemm_mfma<0><<<dim3(256 / 128, N / 128), 256, 0, stream>>>(encb, WmuT, b_mu, out_mu, N, 256, 256, 256, 256, 256);
    gemm_mfma<0><<<dim3(256 / 128, N / 128), 256, 0, stream>>>(encb, WlvT, b_lv, out_lv, N, 256, 256, 256, 256, 256);

    // 6) z -> bf16
    z_kernel<<<(N * 256 / 4 + 255) / 256, 256, 0, stream>>>(out_mu, out_lv, epsin, zb, N * 256 / 4);

    // 7) dec: 2 branch-groups of 10, dual-branch passes, combine -> decb.  nwg = 2048
    dendritic_part<<<8 * (N / 128) * 2, 256, 0, stream>>>(zb, WddecT, bd_dec, Pdec, N, 512, 256, 20, 2, 8);
    combine_max<<<(int)(((size_t)N * 512 / 4 + 255) / 256), 256, 0, stream>>>(Pdec, decb, (size_t)N * 512, 2);

    // 8) fused wavedec-dec -> cdec (incl. pad)
    wavedec_dec<<<N / 4, 256, 0, stream>>>(decb, cdec);

    // 9) recon = cdec @ BcdT^T [16384,768], K=544
    gemm_mfma<0><<<dim3(768 / 128, N / 128), 256, 0, stream>>>(cdec, BcdT, nullptr, out_recon, N, 768, 544, 544, 544, 768);

    (void)ws_size; (void)out_size; (void)n_in;
}

// Round 13
// 475.773 us; speedup vs baseline: 2.0152x; 1.0944x over previous
//
#include <hip/hip_runtime.h>

typedef __attribute__((ext_vector_type(8))) short short8v;
typedef __attribute__((ext_vector_type(8))) unsigned short ushort8v;
typedef __attribute__((ext_vector_type(4))) float float4v;

__device__ __constant__ float c_LO[8] = {
    -0.010597401784997278f, 0.032883011666982945f, 0.030841381835986965f,
    -0.18703481171888114f, -0.02798376941698385f, 0.6308807679295904f,
    0.7148465705525415f, 0.23037781330885523f};
__device__ __constant__ float c_HI[8] = {
    -0.23037781330885523f, 0.7148465705525415f, -0.6308807679295904f,
    -0.02798376941698385f, 0.18703481171888114f, 0.030841381835986965f,
    -0.032883011666982945f, -0.010597401784997278f};

__device__ __forceinline__ unsigned short f2bf(float f) {
    unsigned u = __builtin_bit_cast(unsigned, f);
    unsigned r = u + 0x7fffu + ((u >> 16) & 1u);
    return (unsigned short)(r >> 16);
}
__device__ __forceinline__ float bf2f(unsigned short u) {
    return __builtin_bit_cast(float, (unsigned)u << 16);
}

// tanh-form GELU: one exp2 + rcp
__device__ __forceinline__ float gelu_fast(float x) {
    float x3 = x * x * x;
    float y = fmaf(0.044715f, x3, x) * 0.7978845608028654f;
    float t = fminf(fmaxf(y * 2.8853900817779268f, -30.f), 30.f);
    float e = exp2f(t);
    return x * e * __builtin_amdgcn_rcpf(e + 1.0f);
}

__device__ __forceinline__ void gload_lds16(const void* g, void* l) {
    __builtin_amdgcn_global_load_lds(g, l, 16, 0, 0);
}

// ---- one DWT level: LDS f32 in -> LDS f32 cA + global bf16 cD (pywt symmetric) ----
__device__ __forceinline__ void dwt_lvl(const float* __restrict__ in, int n, float* __restrict__ outA,
                                        unsigned short* __restrict__ outD, int m, int lane) {
    for (int j = lane; j < m; j += 64) {
        float a = 0.f, d = 0.f;
#pragma unroll
        for (int i = 0; i < 8; ++i) {
            int p = 2 * j + 7 - i;
            int q = (p < 6) ? (5 - p) : ((p < n + 6) ? (p - 6) : (2 * n + 5 - p));
            float xv = in[q];
            a = fmaf(c_LO[i], xv, a);
            d = fmaf(c_HI[i], xv, d);
        }
        outA[j] = a;
        outD[j] = f2bf(d);
    }
}
__device__ __forceinline__ void dwt_lvl_final(const float* __restrict__ in, int n, unsigned short* __restrict__ outA,
                                              unsigned short* __restrict__ outD, int m, int lane) {
    for (int j = lane; j < m; j += 64) {
        float a = 0.f, d = 0.f;
#pragma unroll
        for (int i = 0; i < 8; ++i) {
            int p = 2 * j + 7 - i;
            int q = (p < 6) ? (5 - p) : ((p < n + 6) ? (p - 6) : (2 * n + 5 - p));
            float xv = in[q];
            a = fmaf(c_LO[i], xv, a);
            d = fmaf(c_HI[i], xv, d);
        }
        outA[j] = f2bf(a);
        outD[j] = f2bf(d);
    }
}

// ---------------- x -> bf16 cast ----------------
__global__ void cast_bf16_kernel(const float* __restrict__ in, unsigned short* __restrict__ out, int n4) {
    int i = blockIdx.x * blockDim.x + threadIdx.x;
    if (i >= n4) return;
    float4 v = ((const float4*)in)[i];
    ushort4 o;
    o.x = f2bf(v.x); o.y = f2bf(v.y); o.z = f2bf(v.z); o.w = f2bf(v.w);
    ((ushort4*)out)[i] = o;
}

// ---------------- CSR build ----------------
__global__ void hist_kernel(const int* __restrict__ rows, int* __restrict__ cnt, int E) {
    int i = blockIdx.x * blockDim.x + threadIdx.x;
    if (i < E) atomicAdd(&cnt[rows[i]], 1);
}

__global__ __launch_bounds__(1024) void scan_kernel(const int* __restrict__ cnt, int* __restrict__ offs,
                                                    int* __restrict__ cursor, int Nrows, int E) {
    __shared__ int part[1024];
    int tid = threadIdx.x;
    const int per = Nrows / 1024;  // 16
    int base = tid * per;
    int local[16];
    int s = 0;
    for (int i = 0; i < per; ++i) { local[i] = s; s += cnt[base + i]; }
    part[tid] = s;
    __syncthreads();
    for (int off = 1; off < 1024; off <<= 1) {
        int v = part[tid];
        int w = (tid >= off) ? part[tid - off] : 0;
        __syncthreads();
        part[tid] = v + w;
        __syncthreads();
    }
    int pre = (tid == 0) ? 0 : part[tid - 1];
    for (int i = 0; i < per; ++i) {
        int o = pre + local[i];
        offs[base + i] = o;
        cursor[base + i] = o;
    }
    if (tid == 0) offs[Nrows] = E;
}

__global__ void scatter_kernel(const int* __restrict__ rows, const int* __restrict__ cols,
                               const float* __restrict__ vals, int* __restrict__ cursor,
                               int* __restrict__ ccol, float* __restrict__ cval, int E) {
    int i = blockIdx.x * blockDim.x + threadIdx.x;
    if (i >= E) return;
    int r = rows[i];
    int p = atomicAdd(&cursor[r], 1);
    ccol[p] = cols[i];
    cval[p] = vals[i];
}

// ---- FUSED: SpMM (CSR, bf16 gather) + 4-level wavedec -> cenc bf16 [N,800] ----
__global__ __launch_bounds__(256) void spmm_wavedec_enc(const unsigned short* __restrict__ xb,
                                                        const int* __restrict__ offs,
                                                        const int* __restrict__ ccol,
                                                        const float* __restrict__ cval,
                                                        unsigned short* __restrict__ cenc) {
    __shared__ float buf0[4][768];
    __shared__ float buf1[4][400];
    const int widx = threadIdx.x >> 6, lane = threadIdx.x & 63;
    const int r = blockIdx.x * 4 + widx;
    float* b0 = buf0[widx];
    float* b1 = buf1[widx];

    int s = offs[r], e = offs[r + 1];
    float acc[12] = {};
    for (int j = s; j < e; ++j) {
        int c = ccol[j];
        float v = cval[j];
        const unsigned short* xr = xb + (size_t)c * 768;
#pragma unroll
        for (int seg = 0; seg < 3; ++seg) {
            ushort4 u = *(const ushort4*)(xr + seg * 256 + lane * 4);
            acc[seg * 4 + 0] = fmaf(v, bf2f(u.x), acc[seg * 4 + 0]);
            acc[seg * 4 + 1] = fmaf(v, bf2f(u.y), acc[seg * 4 + 1]);
            acc[seg * 4 + 2] = fmaf(v, bf2f(u.z), acc[seg * 4 + 2]);
            acc[seg * 4 + 3] = fmaf(v, bf2f(u.w), acc[seg * 4 + 3]);
        }
    }
#pragma unroll
    for (int seg = 0; seg < 3; ++seg) {
        b0[seg * 256 + lane * 4 + 0] = acc[seg * 4 + 0];
        b0[seg * 256 + lane * 4 + 1] = acc[seg * 4 + 1];
        b0[seg * 256 + lane * 4 + 2] = acc[seg * 4 + 2];
        b0[seg * 256 + lane * 4 + 3] = acc[seg * 4 + 3];
    }
    __syncthreads();

    unsigned short* cr = cenc + (size_t)r * 800;
    dwt_lvl(b0, 768, b1, cr + 407, 387, lane);
    __syncthreads();
    dwt_lvl(b1, 387, b0, cr + 210, 197, lane);
    __syncthreads();
    dwt_lvl(b0, 197, b1, cr + 108, 102, lane);
    __syncthreads();
    dwt_lvl_final(b1, 102, cr + 0, cr + 54, 54, lane);
    if (lane < 6) cr[794 + lane] = 0;
}

// ---- FUSED: 4-level wavedec of dec (bf16 in) -> cdec bf16 [N,544] ----
__global__ __launch_bounds__(256) void wavedec_dec(const unsigned short* __restrict__ decb,
                                                   unsigned short* __restrict__ cdec) {
    __shared__ float buf0[4][512];
    __shared__ float buf1[4][272];
    const int widx = threadIdx.x >> 6, lane = threadIdx.x & 63;
    const int r = blockIdx.x * 4 + widx;
    float* b0 = buf0[widx];
    float* b1 = buf1[widx];
    const unsigned short* ip = decb + (size_t)r * 512;
    for (int i = lane; i < 512; i += 64) b0[i] = bf2f(ip[i]);
    __syncthreads();
    unsigned short* cr = cdec + (size_t)r * 544;
    dwt_lvl(b0, 512, b1, cr + 279, 259, lane);
    __syncthreads();
    dwt_lvl(b1, 259, b0, cr + 146, 133, lane);
    __syncthreads();
    dwt_lvl(b0, 133, b1, cr + 76, 70, lane);
    __syncthreads();
    dwt_lvl_final(b1, 70, cr + 0, cr + 38, 38, lane);
    if (lane < 6) cr[538 + lane] = 0;
}

// ---------------- pack basis stack -> transposed bf16 [N][Kpad] ----------------
struct Bounds { int b[6]; };

__global__ void pack_basis_T(const float* __restrict__ basis, unsigned short* __restrict__ BT,
                             Bounds bd, int brows, int N, int K, int Kpad) {
    int idx = blockIdx.x * blockDim.x + threadIdx.x;
    if (idx >= N * Kpad) return;
    int n = idx / Kpad, k = idx - n * Kpad;
    float v = 0.f;
    if (k < K) {
        int s = 0;
#pragma unroll
        for (int t = 1; t < 5; ++t)
            if (k >= bd.b[t]) s = t;
        int lr = k - bd.b[s];
        v = basis[((size_t)s * brows + lr) * N + n];
    }
    BT[idx] = f2bf(v);
}

__global__ void pack_wT(const float* __restrict__ W, unsigned short* __restrict__ WT,
                        int NB, int K, int N, int Kpad) {
    int idx = blockIdx.x * blockDim.x + threadIdx.x;
    int tot = NB * N * Kpad;
    if (idx >= tot) return;
    int b = idx / (N * Kpad);
    int r = idx - b * (N * Kpad);
    int n = r / Kpad, k = r - n * Kpad;
    float v = (k < K) ? W[((size_t)b * K + k) * N + n] : 0.f;
    WT[idx] = f2bf(v);
}

// ---------------- bf16 MFMA GEMM, 1D grid + m-major XCD swizzle ----------------
// MODE 0: f32 out (Cv, ldc). MODE 2: mu/lv split — cols<256 -> (float*)Cv (+bias), else (float*)Cv2 (+bias2).
template <int MODE>
__global__ __launch_bounds__(256) void gemm_mfma(const unsigned short* __restrict__ A,
                                                 const unsigned short* __restrict__ BT,
                                                 const float* __restrict__ bias,
                                                 const float* __restrict__ bias2,
                                                 void* __restrict__ Cv, void* __restrict__ Cv2,
                                                 int M, int N, int K, int lda, int ldb, int ldc, int nx) {
    __shared__ __align__(16) unsigned short As[128 * 32];
    __shared__ __align__(16) unsigned short Bs[128 * 32];
    const int tid = threadIdx.x;
    const int wave = tid >> 6, lane = tid & 63;
    // XCD swizzle (nwg % 8 == 0), logical m-major (n fastest)
    const int nwg = gridDim.x;
    const int logical = (blockIdx.x & 7) * (nwg >> 3) + (blockIdx.x >> 3);
    const int mblk = logical / nx, nblk = logical - mblk * nx;
    const int m0 = mblk * 128, n0 = nblk * 128;
    const int wr = wave >> 1, wc = wave & 1;
    const int frow = lane & 15, fq = lane >> 4;

    const int off0 = tid * 16;
    const int r0 = off0 >> 6, c0 = off0 & 63;
    const int r1 = (off0 + 4096) >> 6, c1 = (off0 + 4096) & 63;
    const char* Ab = (const char*)A;
    const char* Bb = (const char*)BT;
    size_t gA0 = (size_t)(m0 + r0) * lda * 2 + c0;
    size_t gA1 = (size_t)(m0 + r1) * lda * 2 + c1;
    size_t gB0 = (size_t)(n0 + r0) * ldb * 2 + c0;
    size_t gB1 = (size_t)(n0 + r1) * ldb * 2 + c1;
    char* lA0 = (char*)As + wave * 1024;
    char* lB0 = (char*)Bs + wave * 1024;

    const int aoff = (wr * 64 + frow) * 32 + fq * 8;
    const int boff = (wc * 64 + frow) * 32 + fq * 8;

    float4v acc[4][4] = {};
    for (int k0 = 0; k0 < K; k0 += 32) {
        size_t kb2 = (size_t)k0 * 2;
        gload_lds16(Ab + gA0 + kb2, lA0);
        gload_lds16(Ab + gA1 + kb2, lA0 + 4096);
        gload_lds16(Bb + gB0 + kb2, lB0);
        gload_lds16(Bb + gB1 + kb2, lB0 + 4096);
        __syncthreads();
        short8v av[4], bv[4];
#pragma unroll
        for (int i = 0; i < 4; ++i) av[i] = *(const short8v*)(As + aoff + i * 512);
#pragma unroll
        for (int i = 0; i < 4; ++i) bv[i] = *(const short8v*)(Bs + boff + i * 512);
#pragma unroll
        for (int mi = 0; mi < 4; ++mi)
#pragma unroll
            for (int ni = 0; ni < 4; ++ni)
                acc[mi][ni] = __builtin_amdgcn_mfma_f32_16x16x32_bf16(av[mi], bv[ni], acc[mi][ni], 0, 0, 0);
        __syncthreads();
    }
#pragma unroll
    for (int ni = 0; ni < 4; ++ni) {
        int col = n0 + wc * 64 + ni * 16 + frow;
        float bval;
        float* dst;
        int coll;
        if (MODE == 2) {
            bool isMu = col < 256;
            coll = col & 255;
            bval = isMu ? bias[coll] : bias2[coll];
            dst = (float*)(isMu ? Cv : Cv2);
        } else {
            coll = col;
            bval = bias ? bias[col] : 0.f;
            dst = (float*)Cv;
        }
#pragma unroll
        for (int mi = 0; mi < 4; ++mi) {
#pragma unroll
            for (int i = 0; i < 4; ++i) {
                int row = m0 + wr * 64 + mi * 16 + fq * 4 + i;
                float v = acc[mi][ni][i] + bval;
                if (MODE == 2)
                    dst[(size_t)row * 256 + coll] = v;
                else
                    dst[(size_t)row * ldc + coll] = v;
            }
        }
    }
}

// ---- dendritic v8: dual-branch, all 20 branches per block, direct bf16 output ----
__global__ __launch_bounds__(256, 2) void dendritic_full(const unsigned short* __restrict__ A,
                                                         const unsigned short* __restrict__ WT,
                                                         const float* __restrict__ bias,
                                                         unsigned short* __restrict__ out,
                                                         int M, int Nc, int K, int nb, int nx) {
    __shared__ __align__(16) unsigned short As[128 * 64];     // 16 KB
    __shared__ __align__(16) unsigned short Bs[2][64 * 64];   // 2 x 8 KB
    const int tid = threadIdx.x;
    const int wave = tid >> 6;
    const int lane = tid & 63;

    // XCD swizzle; logical m-major
    const int nwg = gridDim.x;
    const int logical = (blockIdx.x & 7) * (nwg >> 3) + (blockIdx.x >> 3);
    const int mblk = logical / nx;
    const int nblk = logical - mblk * nx;
    const int n0 = nblk * 64, m0 = mblk * 128;

    const int wr = wave >> 1, wc = wave & 1;
    const int frow = lane & 15, fq = lane >> 4;

    int srA[4], scA[4];
#pragma unroll
    for (int i = 0; i < 4; ++i) {
        int ch = i * 256 + tid;
        srA[i] = ch >> 3;
        scA[i] = ((ch & 7) ^ (srA[i] & 7)) * 16;
    }
    int srB[2], scB[2];
#pragma unroll
    for (int i = 0; i < 2; ++i) {
        int ch = i * 256 + tid;
        srB[i] = ch >> 3;
        scB[i] = ((ch & 7) ^ (srB[i] & 7)) * 16;
    }
    const char* Ab = (const char*)A;
    const size_t K2 = (size_t)K * 2;
    const size_t branchBytes = (size_t)Nc * K2;
    char* lA  = (char*)As + wave * 1024;
    char* lB0 = (char*)&Bs[0][0] + wave * 1024;
    char* lB1 = (char*)&Bs[1][0] + wave * 1024;

    float4v hmn[4][2], hmx[4][2];
#pragma unroll
    for (int mi = 0; mi < 4; ++mi)
#pragma unroll
        for (int ni = 0; ni < 2; ++ni) { hmn[mi][ni] = (float4v)(1e30f); hmx[mi][ni] = (float4v)(-1e30f); }

    const int npair = nb >> 1;  // nb even (20)
    for (int p = 0; p < npair; ++p) {
        const int b0 = 2 * p, b1 = 2 * p + 1;
        const char* Bb0 = (const char*)WT + (size_t)b0 * branchBytes;
        const char* Bb1 = (const char*)WT + (size_t)b1 * branchBytes;
        float4v ac0[4][2], ac1[4][2];
#pragma unroll
        for (int ni = 0; ni < 2; ++ni) {
            int col = n0 + wc * 32 + ni * 16 + frow;
            float bv0 = bias[(size_t)b0 * Nc + col];
            float bv1 = bias[(size_t)b1 * Nc + col];
#pragma unroll
            for (int mi = 0; mi < 4; ++mi) { ac0[mi][ni] = (float4v)(bv0); ac1[mi][ni] = (float4v)(bv1); }
        }
        for (int k0 = 0; k0 < K; k0 += 64) {
            const size_t kby = (size_t)k0 * 2;
#pragma unroll
            for (int i = 0; i < 4; ++i)
                gload_lds16(Ab + (size_t)(m0 + srA[i]) * K2 + kby + scA[i], lA + i * 4096);
#pragma unroll
            for (int i = 0; i < 2; ++i)
                gload_lds16(Bb0 + (size_t)(n0 + srB[i]) * K2 + kby + scB[i], lB0 + i * 4096);
#pragma unroll
            for (int i = 0; i < 2; ++i)
                gload_lds16(Bb1 + (size_t)(n0 + srB[i]) * K2 + kby + scB[i], lB1 + i * 4096);
            __syncthreads();
#pragma unroll
            for (int kk = 0; kk < 2; ++kk) {
                short8v av[4], bv0[2], bv1[2];
                const int slot = kk * 4 + fq;
#pragma unroll
                for (int mi = 0; mi < 4; ++mi) {
                    int ra = wr * 64 + mi * 16 + frow;
                    av[mi] = *(const short8v*)((const char*)As + ra * 128 + ((slot ^ (ra & 7)) * 16));
                }
#pragma unroll
                for (int ni = 0; ni < 2; ++ni) {
                    int rb = wc * 32 + ni * 16 + frow;
                    int rboff = rb * 128 + ((slot ^ (rb & 7)) * 16);
                    bv0[ni] = *(const short8v*)((const char*)&Bs[0][0] + rboff);
                    bv1[ni] = *(const short8v*)((const char*)&Bs[1][0] + rboff);
                }
#pragma unroll
                for (int mi = 0; mi < 4; ++mi)
#pragma unroll
                    for (int ni = 0; ni < 2; ++ni) {
                        ac0[mi][ni] = __builtin_amdgcn_mfma_f32_16x16x32_bf16(av[mi], bv0[ni], ac0[mi][ni], 0, 0, 0);
                        ac1[mi][ni] = __builtin_amdgcn_mfma_f32_16x16x32_bf16(av[mi], bv1[ni], ac1[mi][ni], 0, 0, 0);
                    }
            }
            __syncthreads();
        }
#pragma unroll
        for (int ni = 0; ni < 2; ++ni)
#pragma unroll
            for (int mi = 0; mi < 4; ++mi)
#pragma unroll
                for (int i = 0; i < 4; ++i) {
                    float mn = fminf(ac0[mi][ni][i], ac1[mi][ni][i]);
                    float mx = fmaxf(ac0[mi][ni][i], ac1[mi][ni][i]);
                    hmn[mi][ni][i] = fminf(hmn[mi][ni][i], mn);
                    hmx[mi][ni][i] = fmaxf(hmx[mi][ni][i], mx);
                }
    }

#pragma unroll
    for (int ni = 0; ni < 2; ++ni) {
        int col = n0 + wc * 32 + ni * 16 + frow;
#pragma unroll
        for (int mi = 0; mi < 4; ++mi) {
#pragma unroll
            for (int i = 0; i < 4; ++i) {
                int row = m0 + wr * 64 + mi * 16 + fq * 4 + i;
                float g = fmaxf(gelu_fast(hmn[mi][ni][i]), gelu_fast(hmx[mi][ni][i]));
                out[(size_t)row * Nc + col] = f2bf(g);
            }
        }
    }
}

// ---------------- LayerNorm over H=512: f32 in -> bf16 out ----------------
__global__ __launch_bounds__(256) void layernorm_bf16(const float* __restrict__ h,
                                                      unsigned short* __restrict__ o,
                                                      const float* __restrict__ g,
                                                      const float* __restrict__ b) {
    int row = blockIdx.x;
    const float* p = h + (size_t)row * 512;
    int tid = threadIdx.x;
    float v0 = p[tid], v1 = p[tid + 256];
    float s = v0 + v1, sq = v0 * v0 + v1 * v1;
#pragma unroll
    for (int off = 32; off >= 1; off >>= 1) {
        s += __shfl_xor(s, off);
        sq += __shfl_xor(sq, off);
    }
    __shared__ float ls[4], lq[4];
    int wid = tid >> 6, lane = tid & 63;
    if (lane == 0) { ls[wid] = s; lq[wid] = sq; }
    __syncthreads();
    float ts = ls[0] + ls[1] + ls[2] + ls[3];
    float tq = lq[0] + lq[1] + lq[2] + lq[3];
    float mean = ts / 512.f;
    float var = tq / 512.f - mean * mean;
    float inv = rsqrtf(var + 1e-5f);
    unsigned short* op = o + (size_t)row * 512;
    op[tid] = f2bf((v0 - mean) * inv * g[tid] + b[tid]);
    op[tid + 256] = f2bf((v1 - mean) * inv * g[tid + 256] + b[tid + 256]);
}

// ---------------- z = mu + eps * exp(0.5*logvar)  -> bf16 ----------------
__global__ void z_kernel(const float* __restrict__ mu, const float* __restrict__ lv,
                         const float* __restrict__ eps, unsigned short* __restrict__ z, int n4) {
    int i = blockIdx.x * blockDim.x + threadIdx.x;
    if (i >= n4) return;
    float4 m = ((const float4*)mu)[i];
    float4 l = ((const float4*)lv)[i];
    float4 e = ((const float4*)eps)[i];
    ushort4 o;
    o.x = f2bf(m.x + e.x * expf(0.5f * l.x));
    o.y = f2bf(m.y + e.y * expf(0.5f * l.y));
    o.z = f2bf(m.z + e.z * expf(0.5f * l.z));
    o.w = f2bf(m.w + e.w * expf(0.5f * l.w));
    ((ushort4*)z)[i] = o;
}

extern "C" void kernel_launch(void* const* d_in, const int* in_sizes, int n_in,
                              void* d_out, int out_size, void* d_ws, size_t ws_size,
                              hipStream_t stream) {
    const float* x        = (const float*)d_in[0];
    const int*   arows    = (const int*)d_in[1];
    const int*   acols    = (const int*)d_in[2];
    const float* avals    = (const float*)d_in[3];
    const float* basisenc = (const float*)d_in[4];
    const float* ln_g     = (const float*)d_in[5];
    const float* ln_b     = (const float*)d_in[6];
    const float* Wd_enc   = (const float*)d_in[7];
    const float* bd_enc   = (const float*)d_in[8];
    const float* W_mu     = (const float*)d_in[9];
    const float* b_mu     = (const float*)d_in[10];
    const float* W_lv     = (const float*)d_in[11];
    const float* b_lv     = (const float*)d_in[12];
    const float* Wd_dec   = (const float*)d_in[13];
    const float* bd_dec   = (const float*)d_in[14];
    const float* basisdec = (const float*)d_in[15];
    const float* epsin    = (const float*)d_in[16];

    const int N = 16384;
    const int E = in_sizes[1];

    float* ws = (float*)d_ws;
    const size_t A0 = 0;                               // f32 N*768: hF
    const size_t B0 = A0 + (size_t)N * 768;            // u16 N*800: cenc -> [cdec | zb]
    const size_t C0 = B0 + (size_t)N * 400;            // u16: xbf -> [hbf | encb] -> decb
    const size_t F0 = C0 + (size_t)N * 387;            // u16 weights
    const size_t G0 = F0 + 3100672;                    // CSR

    float* hF  = ws + A0;
    unsigned short* cenc = (unsigned short*)(ws + B0);
    unsigned short* cdec = (unsigned short*)(ws + B0);
    unsigned short* zb   = cdec + (size_t)N * 544;
    unsigned short* xbf  = (unsigned short*)(ws + C0);
    unsigned short* hbf  = (unsigned short*)(ws + C0);
    unsigned short* encb = hbf + (size_t)N * 512;
    unsigned short* decb = (unsigned short*)(ws + C0);
    unsigned short* wF = (unsigned short*)(ws + F0);
    unsigned short* BceT   = wF;                       // 512*800
    unsigned short* BcdT   = BceT + 512 * 800;         // 768*544
    unsigned short* WdencT = BcdT + 768 * 544;         // 20*256*512
    unsigned short* WddecT = WdencT + 20 * 256 * 512;  // 20*512*256
    unsigned short* WmuT   = WddecT + 20 * 512 * 256;  // 256*256
    unsigned short* WlvT   = WmuT + 256 * 256;         // contiguous -> [512,256]
    int*   csr_cnt  = (int*)(ws + G0);
    int*   csr_offs = csr_cnt + N;
    int*   csr_cur  = csr_offs + N + 1;
    int*   csr_col  = csr_cur + N;
    float* csr_val  = (float*)(csr_col + E);

    float* out_recon = (float*)d_out;
    float* out_mu    = out_recon + (size_t)N * 768;
    float* out_lv    = out_mu + (size_t)N * 256;

    // --- packs + cast (independent) ---
    {
        Bounds be = {{0, 54, 108, 210, 407, 794}};
        pack_basis_T<<<(512 * 800 + 255) / 256, 256, 0, stream>>>(basisenc, BceT, be, 768, 512, 794, 800);
        Bounds bdd = {{0, 38, 76, 146, 279, 538}};
        pack_basis_T<<<(768 * 544 + 255) / 256, 256, 0, stream>>>(basisdec, BcdT, bdd, 512, 768, 538, 544);
        pack_wT<<<(20 * 256 * 512 + 255) / 256, 256, 0, stream>>>(Wd_enc, WdencT, 20, 512, 256, 512);
        pack_wT<<<(20 * 512 * 256 + 255) / 256, 256, 0, stream>>>(Wd_dec, WddecT, 20, 256, 512, 256);
        pack_wT<<<(256 * 256 + 255) / 256, 256, 0, stream>>>(W_mu, WmuT, 1, 256, 256, 256);
        pack_wT<<<(256 * 256 + 255) / 256, 256, 0, stream>>>(W_lv, WlvT, 1, 256, 256, 256);
        cast_bf16_kernel<<<(N * 768 / 4 + 255) / 256, 256, 0, stream>>>(x, xbf, N * 768 / 4);
    }

    // 1) CSR build + fused SpMM+wavedec-enc -> cenc
    hipMemsetAsync(csr_cnt, 0, N * sizeof(int), stream);
    hist_kernel<<<(E + 255) / 256, 256, 0, stream>>>(arows, csr_cnt, E);
    scan_kernel<<<1, 1024, 0, stream>>>(csr_cnt, csr_offs, csr_cur, N, E);
    scatter_kernel<<<(E + 255) / 256, 256, 0, stream>>>(arows, acols, avals, csr_cur, csr_col, csr_val, E);
    spmm_wavedec_enc<<<N / 4, 256, 0, stream>>>(xbf, csr_offs, csr_col, csr_val, cenc);

    // 2) h = cenc @ BceT^T  [16384,512], K=800.  nwg = 4*128 = 512
    gemm_mfma<0><<<(512 / 128) * (N / 128), 256, 0, stream>>>(cenc, BceT, nullptr, nullptr, hF, nullptr,
                                                              N, 512, 800, 800, 800, 512, 512 / 128);

    // 3) layernorm -> bf16
    layernorm_bf16<<<N, 256, 0, stream>>>(hF, hbf, ln_g, ln_b);

    // 4) enc: all 20 branches per block, direct write -> encb.  nwg = 4*128 = 512
    dendritic_full<<<4 * (N / 128), 256, 0, stream>>>(hbf, WdencT, bd_enc, encb, N, 256, 512, 20, 4);

    // 5) mu & logvar fused: BT = [WmuT|WlvT] = [512,256], split epilogue.  nwg = 4*128 = 512
    gemm_mfma<2><<<(512 / 128) * (N / 128), 256, 0, stream>>>(encb, WmuT, b_mu, b_lv, out_mu, out_lv,
                                                              N, 512, 256, 256, 256, 256, 512 / 128);

    // 6) z -> bf16
    z_kernel<<<(N * 256 / 4 + 255) / 256, 256, 0, stream>>>(out_mu, out_lv, epsin, zb, N * 256 / 4);

    // 7) dec: all 20 branches per block, direct write -> decb.  nwg = 8*128 = 1024
    dendritic_full<<<8 * (N / 128), 256, 0, stream>>>(zb, WddecT, bd_dec, decb, N, 512, 256, 20, 8);

    // 8) fused wavedec-dec -> cdec
    wavedec_dec<<<N / 4, 256, 0, stream>>>(decb, cdec);

    // 9) recon = cdec @ BcdT^T [16384,768], K=544.  nwg = 6*128 = 768
    gemm_mfma<0><<<(768 / 128) * (N / 128), 256, 0, stream>>>(cdec, BcdT, nullptr, nullptr, out_recon, nullptr,
                                                              N, 768, 544, 544, 544, 768, 768 / 128);

    (void)ws_size; (void)out_size; (void)n_in;
}